// Round 1
// baseline (2231.548 us; speedup 1.0000x reference)
//
#include <hip/hip_runtime.h>
#include <cstddef>
#include <cstdint>

#define B_   4
#define L_   1024
#define D_   1024
#define H_   16
#define DH_  64
#define E_   8
#define R_   64
#define FF_  4096
#define NTOK (B_ * L_)   // 4096

__device__ __forceinline__ float gelu_f(float x) {
  // exact gelu: 0.5*x*(1+erf(x/sqrt(2)))
  return 0.5f * x * (1.0f + erff(x * 0.7071067811865476f));
}

// ---------------------------------------------------------------------------
// Generic fp32 GEMM: C[M,N] = epilogue(A[M,K] @ W[K,N] + bias[N] (+ Res))
// EPI: 0 = none, 1 = gelu, 2 = add residual
// 128x128 macro tile, BK=8, 256 threads, 8x8 micro-tile, reg-prefetch pipeline
// ---------------------------------------------------------------------------
template<int EPI>
__global__ __launch_bounds__(256)
void gemm_f32(const float* __restrict__ A, const float* __restrict__ W,
              const float* __restrict__ bias, const float* __restrict__ Res,
              float* __restrict__ C, int M, int N, int Kd) {
  __shared__ float As[8][128];   // [k][m] (transposed store)
  __shared__ float Ws[8][128];   // [k][n]

  const int t   = threadIdx.x;
  const int tx  = t & 15;        // 0..15 -> N direction
  const int ty  = t >> 4;        // 0..15 -> M direction
  const int row0 = blockIdx.y * 128;
  const int col0 = blockIdx.x * 128;

  // A tile loader: 128 rows x 8 cols; thread -> (row=t/2, col4=(t&1)*4)
  const int ar = t >> 1, ac = (t & 1) * 4;
  // W tile loader: 8 rows x 128 cols; thread -> (row=t/32, col4=(t&31)*4)
  const int wr = t >> 5, wc = (t & 31) * 4;

  const float* Aptr = A + (size_t)(row0 + ar) * Kd + ac;
  const float* Wptr = W + (size_t)wr * N + col0 + wc;

  float4 a4 = *(const float4*)Aptr;       // k0 = 0 panel
  float4 w4 = *(const float4*)Wptr;

  float acc[8][8];
  #pragma unroll
  for (int i = 0; i < 8; ++i)
    #pragma unroll
    for (int j = 0; j < 8; ++j) acc[i][j] = 0.0f;

  for (int k0 = 0; k0 < Kd; k0 += 8) {
    __syncthreads();
    As[ac + 0][ar] = a4.x;
    As[ac + 1][ar] = a4.y;
    As[ac + 2][ar] = a4.z;
    As[ac + 3][ar] = a4.w;
    *(float4*)&Ws[wr][wc] = w4;
    __syncthreads();

    if (k0 + 8 < Kd) {  // prefetch next panel into regs (overlaps with compute)
      a4 = *(const float4*)(Aptr + k0 + 8);
      w4 = *(const float4*)(Wptr + (size_t)(k0 + 8) * N);
    }

    #pragma unroll
    for (int kk = 0; kk < 8; ++kk) {
      float4 a0 = *(const float4*)&As[kk][ty * 8];
      float4 a1 = *(const float4*)&As[kk][ty * 8 + 4];
      float4 w0 = *(const float4*)&Ws[kk][tx * 8];
      float4 w1 = *(const float4*)&Ws[kk][tx * 8 + 4];
      float a[8] = {a0.x, a0.y, a0.z, a0.w, a1.x, a1.y, a1.z, a1.w};
      float w[8] = {w0.x, w0.y, w0.z, w0.w, w1.x, w1.y, w1.z, w1.w};
      #pragma unroll
      for (int i = 0; i < 8; ++i)
        #pragma unroll
        for (int j = 0; j < 8; ++j)
          acc[i][j] = fmaf(a[i], w[j], acc[i][j]);
    }
  }

  // epilogue
  #pragma unroll
  for (int i = 0; i < 8; ++i) {
    const size_t r = (size_t)(row0 + ty * 8 + i);
    #pragma unroll
    for (int jj = 0; jj < 8; jj += 4) {
      const int c = col0 + tx * 8 + jj;
      float4 b4 = *(const float4*)&bias[c];
      float4 o;
      o.x = acc[i][jj + 0] + b4.x;
      o.y = acc[i][jj + 1] + b4.y;
      o.z = acc[i][jj + 2] + b4.z;
      o.w = acc[i][jj + 3] + b4.w;
      if (EPI == 1) {
        o.x = gelu_f(o.x); o.y = gelu_f(o.y); o.z = gelu_f(o.z); o.w = gelu_f(o.w);
      } else if (EPI == 2) {
        float4 rv = *(const float4*)&Res[r * N + c];
        o.x += rv.x; o.y += rv.y; o.z += rv.z; o.w += rv.w;
      }
      *(float4*)&C[r * N + c] = o;
    }
  }
}

// ---------------------------------------------------------------------------
// LayerNorm over D=1024: Y = (x - mean)/sqrt(var+eps) * g + b.  1 block/row.
// ---------------------------------------------------------------------------
__global__ __launch_bounds__(256)
void layernorm_f32(const float* __restrict__ X, const float* __restrict__ g,
                   const float* __restrict__ b, float* __restrict__ Y) {
  const int row = blockIdx.x;
  const int t = threadIdx.x;
  const float* x = X + (size_t)row * D_;

  float4 v = *(const float4*)&x[t * 4];
  float s  = v.x + v.y + v.z + v.w;
  float ss = v.x * v.x + v.y * v.y + v.z * v.z + v.w * v.w;

  #pragma unroll
  for (int off = 1; off < 64; off <<= 1) {
    s  += __shfl_xor(s, off);
    ss += __shfl_xor(ss, off);
  }
  __shared__ float red[4][2];
  const int wid = t >> 6;
  if ((t & 63) == 0) { red[wid][0] = s; red[wid][1] = ss; }
  __syncthreads();
  s  = red[0][0] + red[1][0] + red[2][0] + red[3][0];
  ss = red[0][1] + red[1][1] + red[2][1] + red[3][1];

  const float mean = s * (1.0f / D_);
  const float var  = ss * (1.0f / D_) - mean * mean;
  const float inv  = rsqrtf(var + 1e-5f);

  float4 gv = *(const float4*)&g[t * 4];
  float4 bv = *(const float4*)&b[t * 4];
  float4 o;
  o.x = (v.x - mean) * inv * gv.x + bv.x;
  o.y = (v.y - mean) * inv * gv.y + bv.y;
  o.z = (v.z - mean) * inv * gv.z + bv.z;
  o.w = (v.w - mean) * inv * gv.w + bv.w;
  *(float4*)&Y[(size_t)row * D_ + t * 4] = o;
}

// ---------------------------------------------------------------------------
// Flash-style attention. grid (L/16, B*H), 256 threads.
// 16 queries/block; loop over 64-key tiles staged in LDS; online softmax.
// Q,K,V,O layout: [B, L, H*DH] (i.e. [B,L,D] with head at offset h*64)
// thread (qi = t>>4) handles query qi; lane li = t&15 handles 4 keys in QK
// and 4 ctx dims (li*4..+3) in PV.
// ---------------------------------------------------------------------------
__global__ __launch_bounds__(256)
void attn_f32(const float* __restrict__ Q, const float* __restrict__ Kc,
              const float* __restrict__ Vc, float* __restrict__ O) {
  const int qt = blockIdx.x;        // query tile (16 queries)
  const int bh = blockIdx.y;
  const int b = bh >> 4, h = bh & 15;
  const int t = threadIdx.x;
  const int qi = t >> 4, li = t & 15;

  __shared__ float qs[16][68];
  __shared__ float ks[64][68];
  __shared__ float vs[64][68];
  __shared__ float ps[16][68];

  const size_t base = ((size_t)b * L_) * D_ + (size_t)h * DH_;

  { // load Q tile (pre-scaled by 1/sqrt(DH))
    const int r = t >> 4, c = (t & 15) * 4;
    float4 qv = *(const float4*)&Q[base + (size_t)(qt * 16 + r) * D_ + c];
    float4 sc = {qv.x * 0.125f, qv.y * 0.125f, qv.z * 0.125f, qv.w * 0.125f};
    *(float4*)&qs[r][c] = sc;
  }

  float m = -INFINITY, l = 0.0f;
  float acc0 = 0.f, acc1 = 0.f, acc2 = 0.f, acc3 = 0.f;

  for (int kt = 0; kt < 16; ++kt) {
    __syncthreads();
    { // stage K/V tile (64 keys x 64 dims)
      const int r = t >> 4, c = (t & 15) * 4;
      #pragma unroll
      for (int p = 0; p < 4; ++p) {
        const int rr = p * 16 + r;
        const size_t go = base + (size_t)(kt * 64 + rr) * D_ + c;
        *(float4*)&ks[rr][c] = *(const float4*)&Kc[go];
        *(float4*)&vs[rr][c] = *(const float4*)&Vc[go];
      }
    }
    __syncthreads();

    // QK^T: lane li covers keys li, li+16, li+32, li+48
    float s0 = 0.f, s1 = 0.f, s2 = 0.f, s3 = 0.f;
    #pragma unroll
    for (int dc = 0; dc < 16; ++dc) {
      float4 qv = *(const float4*)&qs[qi][dc * 4];
      float4 k0 = *(const float4*)&ks[li][dc * 4];
      float4 k1 = *(const float4*)&ks[li + 16][dc * 4];
      float4 k2 = *(const float4*)&ks[li + 32][dc * 4];
      float4 k3 = *(const float4*)&ks[li + 48][dc * 4];
      s0 += qv.x * k0.x + qv.y * k0.y + qv.z * k0.z + qv.w * k0.w;
      s1 += qv.x * k1.x + qv.y * k1.y + qv.z * k1.z + qv.w * k1.w;
      s2 += qv.x * k2.x + qv.y * k2.y + qv.z * k2.z + qv.w * k2.w;
      s3 += qv.x * k3.x + qv.y * k3.y + qv.z * k3.z + qv.w * k3.w;
    }

    // online softmax update (within 16-lane query group; xor<16 stays in group)
    float mt = fmaxf(fmaxf(s0, s1), fmaxf(s2, s3));
    #pragma unroll
    for (int off = 1; off < 16; off <<= 1) mt = fmaxf(mt, __shfl_xor(mt, off));
    const float mnew  = fmaxf(m, mt);
    const float alpha = expf(m - mnew);
    const float p0 = expf(s0 - mnew), p1 = expf(s1 - mnew);
    const float p2 = expf(s2 - mnew), p3 = expf(s3 - mnew);
    float lt = p0 + p1 + p2 + p3;
    #pragma unroll
    for (int off = 1; off < 16; off <<= 1) lt += __shfl_xor(lt, off);
    l = l * alpha + lt;
    m = mnew;
    acc0 *= alpha; acc1 *= alpha; acc2 *= alpha; acc3 *= alpha;

    // share p within the wave (producer/consumer are the same wave: no barrier)
    ps[qi][li]      = p0;
    ps[qi][li + 16] = p1;
    ps[qi][li + 32] = p2;
    ps[qi][li + 48] = p3;

    // PV: lane li accumulates ctx dims li*4..+3
    #pragma unroll
    for (int k = 0; k < 64; ++k) {
      const float pk = ps[qi][k];
      float4 vv = *(const float4*)&vs[k][li * 4];
      acc0 = fmaf(pk, vv.x, acc0);
      acc1 = fmaf(pk, vv.y, acc1);
      acc2 = fmaf(pk, vv.z, acc2);
      acc3 = fmaf(pk, vv.w, acc3);
    }
  }

  const float invl = 1.0f / l;
  float4 o = {acc0 * invl, acc1 * invl, acc2 * invl, acc3 * invl};
  *(float4*)&O[base + (size_t)(qt * 16 + qi) * D_ + li * 4] = o;
}

// ---------------------------------------------------------------------------
// Fused adapter: gate logits + top-2 + softmax + 2-expert R->D expansion
// + bias + scaling + residual add with layer_out.  1 block (256 thr) / token.
// ---------------------------------------------------------------------------
__global__ __launch_bounds__(256)
void adapter_combine(const float* __restrict__ X,     // attn_out [NTOK, D]
                     const float* __restrict__ Hall,  // gelu(x@adp_w1+b1) [NTOK, E*R]
                     const float* __restrict__ Lout,  // layer_out [NTOK, D]
                     const float* __restrict__ W2,    // [E, R, D]
                     const float* __restrict__ B2,    // [E, D]
                     const float* __restrict__ GW,    // [D, E]
                     const float* __restrict__ GB,    // [E]
                     float* __restrict__ Out) {
  const int tok = blockIdx.x;
  const int t = threadIdx.x;

  __shared__ float xs[D_];
  __shared__ float part[256];
  __shared__ float logit_s[E_];
  __shared__ float hs[2 * R_];
  __shared__ int   e_sh[2];
  __shared__ float g_sh[2];

  *(float4*)&xs[t * 4] = *(const float4*)&X[(size_t)tok * D_ + t * 4];
  __syncthreads();

  // gate logits: expert e = t&7, segment seg = t>>3 covers 32 dims
  {
    const int e = t & 7, seg = t >> 3;
    float p = 0.f;
    #pragma unroll 8
    for (int i = 0; i < 32; ++i) {
      const int d = seg * 32 + i;
      p = fmaf(xs[d], GW[d * E_ + e], p);
    }
    part[t] = p;
  }
  __syncthreads();
  if (t < E_) {
    float s = GB[t];
    for (int sg = 0; sg < 32; ++sg) s += part[sg * 8 + t];
    logit_s[t] = s;
  }
  __syncthreads();
  if (t == 0) {  // top-2 with first-index tie-break (matches lax.top_k)
    int e1 = 0; float v1 = logit_s[0];
    for (int i = 1; i < E_; ++i) if (logit_s[i] > v1) { v1 = logit_s[i]; e1 = i; }
    int e2 = -1; float v2 = -INFINITY;
    for (int i = 0; i < E_; ++i) if (i != e1 && logit_s[i] > v2) { v2 = logit_s[i]; e2 = i; }
    const float ee = expf(v2 - v1);
    const float den = 1.0f + ee;
    g_sh[0] = 1.0f / den; g_sh[1] = ee / den;
    e_sh[0] = e1; e_sh[1] = e2;
  }
  __syncthreads();
  const int e1 = e_sh[0], e2 = e_sh[1];
  const float g1 = g_sh[0], g2 = g_sh[1];

  if (t < 2 * R_) {  // stage the two selected experts' h rows
    const int ex = (t < R_) ? e1 : e2;
    const int r = t & (R_ - 1);
    hs[t] = Hall[(size_t)tok * (E_ * R_) + ex * R_ + r];
  }
  __syncthreads();

  const int d = t * 4;
  float4 b1v = *(const float4*)&B2[e1 * D_ + d];
  float4 b2v = *(const float4*)&B2[e2 * D_ + d];
  float4 acc;
  acc.x = g1 * b1v.x + g2 * b2v.x;
  acc.y = g1 * b1v.y + g2 * b2v.y;
  acc.z = g1 * b1v.z + g2 * b2v.z;
  acc.w = g1 * b1v.w + g2 * b2v.w;

  #pragma unroll 8
  for (int r = 0; r < R_; ++r) {
    const float f = g1 * hs[r];
    float4 w = *(const float4*)&W2[((size_t)e1 * R_ + r) * D_ + d];
    acc.x = fmaf(f, w.x, acc.x); acc.y = fmaf(f, w.y, acc.y);
    acc.z = fmaf(f, w.z, acc.z); acc.w = fmaf(f, w.w, acc.w);
  }
  #pragma unroll 8
  for (int r = 0; r < R_; ++r) {
    const float f = g2 * hs[R_ + r];
    float4 w = *(const float4*)&W2[((size_t)e2 * R_ + r) * D_ + d];
    acc.x = fmaf(f, w.x, acc.x); acc.y = fmaf(f, w.y, acc.y);
    acc.z = fmaf(f, w.z, acc.z); acc.w = fmaf(f, w.w, acc.w);
  }

  float4 lo = *(const float4*)&Lout[(size_t)tok * D_ + d];
  float4 o = {lo.x + 2.0f * acc.x, lo.y + 2.0f * acc.y,
              lo.z + 2.0f * acc.z, lo.w + 2.0f * acc.w};
  *(float4*)&Out[(size_t)tok * D_ + d] = o;
}

// ---------------------------------------------------------------------------
extern "C" void kernel_launch(void* const* d_in, const int* in_sizes, int n_in,
                              void* d_out, int out_size, void* d_ws, size_t ws_size,
                              hipStream_t stream) {
  const float* x     = (const float*)d_in[0];
  const float* wq    = (const float*)d_in[1];
  const float* wk    = (const float*)d_in[2];
  const float* wv    = (const float*)d_in[3];
  const float* wo    = (const float*)d_in[4];
  const float* bq    = (const float*)d_in[5];
  const float* bk    = (const float*)d_in[6];
  const float* bv    = (const float*)d_in[7];
  const float* bo    = (const float*)d_in[8];
  const float* ln1g  = (const float*)d_in[9];
  const float* ln1b  = (const float*)d_in[10];
  const float* w1    = (const float*)d_in[11];
  const float* b1    = (const float*)d_in[12];
  const float* w2    = (const float*)d_in[13];
  const float* b2    = (const float*)d_in[14];
  const float* ln2g  = (const float*)d_in[15];
  const float* ln2b  = (const float*)d_in[16];
  const float* aw1   = (const float*)d_in[17];
  const float* ab1   = (const float*)d_in[18];
  const float* aw2   = (const float*)d_in[19];
  const float* ab2   = (const float*)d_in[20];
  const float* gw    = (const float*)d_in[21];
  const float* gb    = (const float*)d_in[22];
  float* out = (float*)d_out;
  float* ws  = (float*)d_ws;

  // workspace layout (floats); buffers reused as lifetimes end
  const size_t SZ = (size_t)NTOK * D_;            // 4M floats
  float* Q       = ws + 0 * SZ;
  float* Kbuf    = ws + 1 * SZ;
  float* Vbuf    = ws + 2 * SZ;
  float* CTX     = ws + 3 * SZ;
  float* ATTNPRE = ws + 0 * SZ;                   // reuse Q
  float* ATTNOUT = ws + 1 * SZ;                   // reuse K
  float* FFNPRE  = ws + 2 * SZ;                   // reuse V
  float* LOUT    = ws + 3 * SZ;                   // reuse CTX
  float* INTER   = ws + 4 * SZ;                   // 16M floats [NTOK, FF]
  float* HALL    = ws + 0 * SZ;                   // reuse ATTNPRE (2M floats)

  const dim3 blk(256);

  // QKV projections
  {
    dim3 g(D_ / 128, NTOK / 128);
    hipLaunchKernelGGL((gemm_f32<0>), g, blk, 0, stream, x, wq, bq, nullptr, Q,    NTOK, D_, D_);
    hipLaunchKernelGGL((gemm_f32<0>), g, blk, 0, stream, x, wk, bk, nullptr, Kbuf, NTOK, D_, D_);
    hipLaunchKernelGGL((gemm_f32<0>), g, blk, 0, stream, x, wv, bv, nullptr, Vbuf, NTOK, D_, D_);
  }
  // attention
  {
    dim3 g(L_ / 16, B_ * H_);
    hipLaunchKernelGGL(attn_f32, g, blk, 0, stream, Q, Kbuf, Vbuf, CTX);
  }
  // output projection + residual, then LN1
  {
    dim3 g(D_ / 128, NTOK / 128);
    hipLaunchKernelGGL((gemm_f32<2>), g, blk, 0, stream, CTX, wo, bo, x, ATTNPRE, NTOK, D_, D_);
    hipLaunchKernelGGL(layernorm_f32, dim3(NTOK), blk, 0, stream, ATTNPRE, ln1g, ln1b, ATTNOUT);
  }
  // FFN
  {
    dim3 g1(FF_ / 128, NTOK / 128);
    hipLaunchKernelGGL((gemm_f32<1>), g1, blk, 0, stream, ATTNOUT, w1, b1, nullptr, INTER, NTOK, FF_, D_);
    dim3 g2(D_ / 128, NTOK / 128);
    hipLaunchKernelGGL((gemm_f32<2>), g2, blk, 0, stream, INTER, w2, b2, ATTNOUT, FFNPRE, NTOK, D_, FF_);
    hipLaunchKernelGGL(layernorm_f32, dim3(NTOK), blk, 0, stream, FFNPRE, ln2g, ln2b, LOUT);
  }
  // adapter dense1 (all experts) then fused gate/top2/combine
  {
    dim3 g(E_ * R_ / 128, NTOK / 128);
    hipLaunchKernelGGL((gemm_f32<1>), g, blk, 0, stream, ATTNOUT, aw1, ab1, nullptr, HALL, NTOK, E_ * R_, D_);
    hipLaunchKernelGGL(adapter_combine, dim3(NTOK), blk, 0, stream,
                       ATTNOUT, HALL, LOUT, aw2, ab2, gw, gb, out);
  }
}

// Round 2
// 1293.572 us; speedup vs baseline: 1.7251x; 1.7251x over previous
//
#include <hip/hip_runtime.h>
#include <cstddef>
#include <cstdint>

#define B_   4
#define L_   1024
#define D_   1024
#define H_   16
#define DH_  64
#define E_   8
#define R_   64
#define FF_  4096
#define NTOK (B_ * L_)   // 4096

typedef __attribute__((ext_vector_type(8))) short bf16x8;
typedef __attribute__((ext_vector_type(4))) float f32x4;

__device__ __forceinline__ float gelu_f(float x) {
  return 0.5f * x * (1.0f + erff(x * 0.7071067811865476f));
}

__device__ __forceinline__ unsigned short bf16_of(float f) {
  union { float f; uint32_t u; } x; x.f = f;
  uint32_t r = x.u + 0x7FFFu + ((x.u >> 16) & 1u);   // RNE
  return (unsigned short)(r >> 16);
}
__device__ __forceinline__ float f32_of(unsigned short h) {
  union { uint32_t u; float f; } x; x.u = ((uint32_t)h) << 16;
  return x.f;
}
__device__ __forceinline__ void split_hl(float v, unsigned short& hi, unsigned short& lo) {
  hi = bf16_of(v);
  lo = bf16_of(v - f32_of(hi));
}

__device__ __forceinline__ void glds16(const void* g, const void* l) {
  __builtin_amdgcn_global_load_lds(
      (const __attribute__((address_space(1))) unsigned int*)g,
      (__attribute__((address_space(3))) unsigned int*)l, 16, 0, 0);
}

// ---------------------------------------------------------------------------
// Elementwise fp32 -> bf16 hi/lo split.  n4 = element count / 4.
// ---------------------------------------------------------------------------
__global__ __launch_bounds__(256)
void fsplit(const float* __restrict__ X, unsigned short* __restrict__ Hh,
            unsigned short* __restrict__ Ll, int n4) {
  int i = blockIdx.x * 256 + threadIdx.x;
  if (i >= n4) return;
  float4 v = ((const float4*)X)[i];
  ushort4 h, l;
  split_hl(v.x, h.x, l.x); split_hl(v.y, h.y, l.y);
  split_hl(v.z, h.z, l.z); split_hl(v.w, h.w, l.w);
  ((ushort4*)Hh)[i] = h;
  ((ushort4*)Ll)[i] = l;
}

// ---------------------------------------------------------------------------
// Weight split+transpose: W[K,N] fp32 -> Th,Tl [N,K] bf16.  64x64 tiles.
// grid (N/64, K/64), 256 threads.
// ---------------------------------------------------------------------------
__global__ __launch_bounds__(256)
void wsplit_t(const float* __restrict__ W, unsigned short* __restrict__ Th,
              unsigned short* __restrict__ Tl, int K, int N) {
  __shared__ float tile[64][65];
  const int k0 = blockIdx.y * 64, n0 = blockIdx.x * 64;
  const int t = threadIdx.x;
  const int r = t >> 4, c4 = (t & 15) * 4;
  #pragma unroll
  for (int p = 0; p < 4; ++p) {
    const int k = r + p * 16;
    *(float4*)&tile[k][c4] = *(const float4*)&W[(size_t)(k0 + k) * N + n0 + c4];
  }
  __syncthreads();
  #pragma unroll
  for (int p = 0; p < 4; ++p) {
    const int n = r + p * 16;
    float v0 = tile[c4 + 0][n], v1 = tile[c4 + 1][n];
    float v2 = tile[c4 + 2][n], v3 = tile[c4 + 3][n];
    ushort4 h, l;
    split_hl(v0, h.x, l.x); split_hl(v1, h.y, l.y);
    split_hl(v2, h.z, l.z); split_hl(v3, h.w, l.w);
    const size_t o = (size_t)(n0 + n) * K + k0 + c4;
    *(ushort4*)&Th[o] = h;
    *(ushort4*)&Tl[o] = l;
  }
}

// ---------------------------------------------------------------------------
// Split-bf16 MFMA GEMM: C[M,N] = epi(Ahl[M,K] @ Bhl^T[N,K] + bias (+res))
// = Ah*Bh + Al*Bh + Ah*Bl into one fp32 accumulator (3x mfma_f32_16x16x32_bf16)
// 128x128 tile, BK=32, 256 thr (4 waves 2x2), 4x4 frags/wave, global_load_lds.
// EPI: 0 bias->f32 | 1 bias+gelu->f32 | 2 bias+resF->f32
//      3 bias+gelu->hl | 4 bias+resHL->f32
// ---------------------------------------------------------------------------
template<int EPI>
__global__ __launch_bounds__(256, 2)
void gemm_mfma(const unsigned short* __restrict__ Ah, const unsigned short* __restrict__ Al,
               const unsigned short* __restrict__ Bh, const unsigned short* __restrict__ Bl,
               const float* __restrict__ bias,
               const float* __restrict__ ResF,
               const unsigned short* __restrict__ ResH, const unsigned short* __restrict__ ResL,
               float* __restrict__ Cf, unsigned short* __restrict__ Ch, unsigned short* __restrict__ Cl,
               int M, int N, int K) {
  __shared__ unsigned short sAh[128 * 32], sAl[128 * 32];
  __shared__ unsigned short sBh[128 * 32], sBl[128 * 32];

  const int t = threadIdx.x;
  const int lane = t & 63;
  const int wid = t >> 6;
  const int wm = wid >> 1, wn = wid & 1;

  // bijective XCD swizzle (all grids here have nwg % 8 == 0)
  const int nwgx = gridDim.x;
  const int nwg = nwgx * gridDim.y;
  const int idl = blockIdx.y * nwgx + blockIdx.x;
  const int swz = (idl & 7) * (nwg >> 3) + (idl >> 3);
  const int m0 = (swz / nwgx) * 128;
  const int n0 = (swz % nwgx) * 128;

  const int srow = wid * 32 + (lane >> 2);   // + c*16 per call
  const int skoff = (lane & 3) * 8;          // k element offset

  f32x4 acc[4][4];
  #pragma unroll
  for (int i = 0; i < 4; ++i)
    #pragma unroll
    for (int j = 0; j < 4; ++j)
      acc[i][j] = (f32x4){0.f, 0.f, 0.f, 0.f};

  const int fr = lane & 15, fq = lane >> 4;

  for (int k0 = 0; k0 < K; k0 += 32) {
    __syncthreads();
    #pragma unroll
    for (int c = 0; c < 2; ++c) {
      const size_t ga = (size_t)(m0 + srow + c * 16) * K + k0 + skoff;
      const size_t gb = (size_t)(n0 + srow + c * 16) * K + k0 + skoff;
      const int ldso = (wid * 32 + c * 16) * 32;
      glds16(Ah + ga, &sAh[ldso]);
      glds16(Al + ga, &sAl[ldso]);
      glds16(Bh + gb, &sBh[ldso]);
      glds16(Bl + gb, &sBl[ldso]);
    }
    __syncthreads();

    bf16x8 ah[4], al[4], bh[4], bl[4];
    #pragma unroll
    for (int i = 0; i < 4; ++i) {
      const int ra = (wm * 64 + i * 16 + fr) * 32 + fq * 8;
      ah[i] = *(const bf16x8*)&sAh[ra];
      al[i] = *(const bf16x8*)&sAl[ra];
      const int rb = (wn * 64 + i * 16 + fr) * 32 + fq * 8;
      bh[i] = *(const bf16x8*)&sBh[rb];
      bl[i] = *(const bf16x8*)&sBl[rb];
    }
    #pragma unroll
    for (int i = 0; i < 4; ++i)
      #pragma unroll
      for (int j = 0; j < 4; ++j) {
        acc[i][j] = __builtin_amdgcn_mfma_f32_16x16x32_bf16(ah[i], bh[j], acc[i][j], 0, 0, 0);
        acc[i][j] = __builtin_amdgcn_mfma_f32_16x16x32_bf16(al[i], bh[j], acc[i][j], 0, 0, 0);
        acc[i][j] = __builtin_amdgcn_mfma_f32_16x16x32_bf16(ah[i], bl[j], acc[i][j], 0, 0, 0);
      }
  }

  // epilogue: C/D layout col = lane&15, row = (lane>>4)*4 + reg  [m89-verified]
  float bcol[4];
  #pragma unroll
  for (int j = 0; j < 4; ++j) bcol[j] = bias[n0 + wn * 64 + j * 16 + fr];

  #pragma unroll
  for (int i = 0; i < 4; ++i) {
    #pragma unroll
    for (int r = 0; r < 4; ++r) {
      const int row = m0 + wm * 64 + i * 16 + fq * 4 + r;
      const size_t ro = (size_t)row * N;
      #pragma unroll
      for (int j = 0; j < 4; ++j) {
        const int col = n0 + wn * 64 + j * 16 + fr;
        float v = acc[i][j][r] + bcol[j];
        if (EPI == 1) {
          v = gelu_f(v);
          Cf[ro + col] = v;
        } else if (EPI == 2) {
          Cf[ro + col] = v + ResF[ro + col];
        } else if (EPI == 3) {
          v = gelu_f(v);
          unsigned short h, l;
          split_hl(v, h, l);
          Ch[ro + col] = h;
          Cl[ro + col] = l;
        } else if (EPI == 4) {
          Cf[ro + col] = v + f32_of(ResH[ro + col]) + f32_of(ResL[ro + col]);
        } else {
          Cf[ro + col] = v;
        }
      }
    }
  }
}

// ---------------------------------------------------------------------------
// LayerNorm over D=1024.  MODE 0: fp32 out; MODE 1: bf16 hi/lo out.
// ---------------------------------------------------------------------------
template<int MODE>
__global__ __launch_bounds__(256)
void layernorm_k(const float* __restrict__ X, const float* __restrict__ g,
                 const float* __restrict__ b, float* __restrict__ Yf,
                 unsigned short* __restrict__ Yh, unsigned short* __restrict__ Yl) {
  const int row = blockIdx.x;
  const int t = threadIdx.x;
  const float* x = X + (size_t)row * D_;

  float4 v = *(const float4*)&x[t * 4];
  float s  = v.x + v.y + v.z + v.w;
  float ss = v.x * v.x + v.y * v.y + v.z * v.z + v.w * v.w;

  #pragma unroll
  for (int off = 1; off < 64; off <<= 1) {
    s  += __shfl_xor(s, off);
    ss += __shfl_xor(ss, off);
  }
  __shared__ float red[4][2];
  const int wid = t >> 6;
  if ((t & 63) == 0) { red[wid][0] = s; red[wid][1] = ss; }
  __syncthreads();
  s  = red[0][0] + red[1][0] + red[2][0] + red[3][0];
  ss = red[0][1] + red[1][1] + red[2][1] + red[3][1];

  const float mean = s * (1.0f / D_);
  const float var  = ss * (1.0f / D_) - mean * mean;
  const float inv  = rsqrtf(var + 1e-5f);

  float4 gv = *(const float4*)&g[t * 4];
  float4 bv = *(const float4*)&b[t * 4];
  float4 o;
  o.x = (v.x - mean) * inv * gv.x + bv.x;
  o.y = (v.y - mean) * inv * gv.y + bv.y;
  o.z = (v.z - mean) * inv * gv.z + bv.z;
  o.w = (v.w - mean) * inv * gv.w + bv.w;
  if (MODE == 0) {
    *(float4*)&Yf[(size_t)row * D_ + t * 4] = o;
  } else {
    ushort4 h, l;
    split_hl(o.x, h.x, l.x); split_hl(o.y, h.y, l.y);
    split_hl(o.z, h.z, l.z); split_hl(o.w, h.w, l.w);
    *(ushort4*)&Yh[(size_t)row * D_ + t * 4] = h;
    *(ushort4*)&Yl[(size_t)row * D_ + t * 4] = l;
  }
}

// ---------------------------------------------------------------------------
// Flash-style fp32 attention (unchanged math); writes ctx as bf16 hi/lo.
// ---------------------------------------------------------------------------
__global__ __launch_bounds__(256)
void attn_f32(const float* __restrict__ Q, const float* __restrict__ Kc,
              const float* __restrict__ Vc, unsigned short* __restrict__ Oh,
              unsigned short* __restrict__ Ol) {
  const int qt = blockIdx.x;
  const int bh = blockIdx.y;
  const int b = bh >> 4, h = bh & 15;
  const int t = threadIdx.x;
  const int qi = t >> 4, li = t & 15;

  __shared__ float qs[16][68];
  __shared__ float ks[64][68];
  __shared__ float vs[64][68];
  __shared__ float ps[16][68];

  const size_t base = ((size_t)b * L_) * D_ + (size_t)h * DH_;

  {
    const int r = t >> 4, c = (t & 15) * 4;
    float4 qv = *(const float4*)&Q[base + (size_t)(qt * 16 + r) * D_ + c];
    float4 sc = {qv.x * 0.125f, qv.y * 0.125f, qv.z * 0.125f, qv.w * 0.125f};
    *(float4*)&qs[r][c] = sc;
  }

  float m = -INFINITY, l = 0.0f;
  float acc0 = 0.f, acc1 = 0.f, acc2 = 0.f, acc3 = 0.f;

  for (int kt = 0; kt < 16; ++kt) {
    __syncthreads();
    {
      const int r = t >> 4, c = (t & 15) * 4;
      #pragma unroll
      for (int p = 0; p < 4; ++p) {
        const int rr = p * 16 + r;
        const size_t go = base + (size_t)(kt * 64 + rr) * D_ + c;
        *(float4*)&ks[rr][c] = *(const float4*)&Kc[go];
        *(float4*)&vs[rr][c] = *(const float4*)&Vc[go];
      }
    }
    __syncthreads();

    float s0 = 0.f, s1 = 0.f, s2 = 0.f, s3 = 0.f;
    #pragma unroll
    for (int dc = 0; dc < 16; ++dc) {
      float4 qv = *(const float4*)&qs[qi][dc * 4];
      float4 k0 = *(const float4*)&ks[li][dc * 4];
      float4 k1 = *(const float4*)&ks[li + 16][dc * 4];
      float4 k2 = *(const float4*)&ks[li + 32][dc * 4];
      float4 k3 = *(const float4*)&ks[li + 48][dc * 4];
      s0 += qv.x * k0.x + qv.y * k0.y + qv.z * k0.z + qv.w * k0.w;
      s1 += qv.x * k1.x + qv.y * k1.y + qv.z * k1.z + qv.w * k1.w;
      s2 += qv.x * k2.x + qv.y * k2.y + qv.z * k2.z + qv.w * k2.w;
      s3 += qv.x * k3.x + qv.y * k3.y + qv.z * k3.z + qv.w * k3.w;
    }

    float mt = fmaxf(fmaxf(s0, s1), fmaxf(s2, s3));
    #pragma unroll
    for (int off = 1; off < 16; off <<= 1) mt = fmaxf(mt, __shfl_xor(mt, off));
    const float mnew  = fmaxf(m, mt);
    const float alpha = expf(m - mnew);
    const float p0 = expf(s0 - mnew), p1 = expf(s1 - mnew);
    const float p2 = expf(s2 - mnew), p3 = expf(s3 - mnew);
    float lt = p0 + p1 + p2 + p3;
    #pragma unroll
    for (int off = 1; off < 16; off <<= 1) lt += __shfl_xor(lt, off);
    l = l * alpha + lt;
    m = mnew;
    acc0 *= alpha; acc1 *= alpha; acc2 *= alpha; acc3 *= alpha;

    ps[qi][li]      = p0;
    ps[qi][li + 16] = p1;
    ps[qi][li + 32] = p2;
    ps[qi][li + 48] = p3;

    #pragma unroll
    for (int k = 0; k < 64; ++k) {
      const float pk = ps[qi][k];
      float4 vv = *(const float4*)&vs[k][li * 4];
      acc0 = fmaf(pk, vv.x, acc0);
      acc1 = fmaf(pk, vv.y, acc1);
      acc2 = fmaf(pk, vv.z, acc2);
      acc3 = fmaf(pk, vv.w, acc3);
    }
  }

  const float invl = 1.0f / l;
  float4 o = {acc0 * invl, acc1 * invl, acc2 * invl, acc3 * invl};
  ushort4 oh, ol;
  split_hl(o.x, oh.x, ol.x); split_hl(o.y, oh.y, ol.y);
  split_hl(o.z, oh.z, ol.z); split_hl(o.w, oh.w, ol.w);
  const size_t oo = base + (size_t)(qt * 16 + qi) * D_ + li * 4;
  *(ushort4*)&Oh[oo] = oh;
  *(ushort4*)&Ol[oo] = ol;
}

// ---------------------------------------------------------------------------
// Fused adapter: gate + top-2 + softmax + 2-expert R->D + residual combine.
// X given as bf16 hi/lo.
// ---------------------------------------------------------------------------
__global__ __launch_bounds__(256)
void adapter_combine_hl(const unsigned short* __restrict__ Xh, const unsigned short* __restrict__ Xl,
                        const float* __restrict__ Hall,
                        const float* __restrict__ Lout,
                        const float* __restrict__ W2,
                        const float* __restrict__ B2,
                        const float* __restrict__ GW,
                        const float* __restrict__ GB,
                        float* __restrict__ Out) {
  const int tok = blockIdx.x;
  const int t = threadIdx.x;

  __shared__ float xs[D_];
  __shared__ float part[256];
  __shared__ float logit_s[E_];
  __shared__ float hs[2 * R_];
  __shared__ int   e_sh[2];
  __shared__ float g_sh[2];

  {
    ushort4 h = *(const ushort4*)&Xh[(size_t)tok * D_ + t * 4];
    ushort4 l = *(const ushort4*)&Xl[(size_t)tok * D_ + t * 4];
    xs[t * 4 + 0] = f32_of(h.x) + f32_of(l.x);
    xs[t * 4 + 1] = f32_of(h.y) + f32_of(l.y);
    xs[t * 4 + 2] = f32_of(h.z) + f32_of(l.z);
    xs[t * 4 + 3] = f32_of(h.w) + f32_of(l.w);
  }
  __syncthreads();

  {
    const int e = t & 7, seg = t >> 3;
    float p = 0.f;
    #pragma unroll 8
    for (int i = 0; i < 32; ++i) {
      const int d = seg * 32 + i;
      p = fmaf(xs[d], GW[d * E_ + e], p);
    }
    part[t] = p;
  }
  __syncthreads();
  if (t < E_) {
    float s = GB[t];
    for (int sg = 0; sg < 32; ++sg) s += part[sg * 8 + t];
    logit_s[t] = s;
  }
  __syncthreads();
  if (t == 0) {
    int e1 = 0; float v1 = logit_s[0];
    for (int i = 1; i < E_; ++i) if (logit_s[i] > v1) { v1 = logit_s[i]; e1 = i; }
    int e2 = -1; float v2 = -INFINITY;
    for (int i = 0; i < E_; ++i) if (i != e1 && logit_s[i] > v2) { v2 = logit_s[i]; e2 = i; }
    const float ee = expf(v2 - v1);
    const float den = 1.0f + ee;
    g_sh[0] = 1.0f / den; g_sh[1] = ee / den;
    e_sh[0] = e1; e_sh[1] = e2;
  }
  __syncthreads();
  const int e1 = e_sh[0], e2 = e_sh[1];
  const float g1 = g_sh[0], g2 = g_sh[1];

  if (t < 2 * R_) {
    const int ex = (t < R_) ? e1 : e2;
    const int r = t & (R_ - 1);
    hs[t] = Hall[(size_t)tok * (E_ * R_) + ex * R_ + r];
  }
  __syncthreads();

  const int d = t * 4;
  float4 b1v = *(const float4*)&B2[e1 * D_ + d];
  float4 b2v = *(const float4*)&B2[e2 * D_ + d];
  float4 acc;
  acc.x = g1 * b1v.x + g2 * b2v.x;
  acc.y = g1 * b1v.y + g2 * b2v.y;
  acc.z = g1 * b1v.z + g2 * b2v.z;
  acc.w = g1 * b1v.w + g2 * b2v.w;

  #pragma unroll 8
  for (int r = 0; r < R_; ++r) {
    const float f = g1 * hs[r];
    float4 w = *(const float4*)&W2[((size_t)e1 * R_ + r) * D_ + d];
    acc.x = fmaf(f, w.x, acc.x); acc.y = fmaf(f, w.y, acc.y);
    acc.z = fmaf(f, w.z, acc.z); acc.w = fmaf(f, w.w, acc.w);
  }
  #pragma unroll 8
  for (int r = 0; r < R_; ++r) {
    const float f = g2 * hs[R_ + r];
    float4 w = *(const float4*)&W2[((size_t)e2 * R_ + r) * D_ + d];
    acc.x = fmaf(f, w.x, acc.x); acc.y = fmaf(f, w.y, acc.y);
    acc.z = fmaf(f, w.z, acc.z); acc.w = fmaf(f, w.w, acc.w);
  }

  float4 lo = *(const float4*)&Lout[(size_t)tok * D_ + d];
  float4 o = {lo.x + 2.0f * acc.x, lo.y + 2.0f * acc.y,
              lo.z + 2.0f * acc.z, lo.w + 2.0f * acc.w};
  *(float4*)&Out[(size_t)tok * D_ + d] = o;
}

// ---------------------------------------------------------------------------
extern "C" void kernel_launch(void* const* d_in, const int* in_sizes, int n_in,
                              void* d_out, int out_size, void* d_ws, size_t ws_size,
                              hipStream_t stream) {
  const float* x     = (const float*)d_in[0];
  const float* wq    = (const float*)d_in[1];
  const float* wk    = (const float*)d_in[2];
  const float* wv    = (const float*)d_in[3];
  const float* wo    = (const float*)d_in[4];
  const float* bq    = (const float*)d_in[5];
  const float* bk    = (const float*)d_in[6];
  const float* bv    = (const float*)d_in[7];
  const float* bo    = (const float*)d_in[8];
  const float* ln1g  = (const float*)d_in[9];
  const float* ln1b  = (const float*)d_in[10];
  const float* w1    = (const float*)d_in[11];
  const float* b1    = (const float*)d_in[12];
  const float* w2    = (const float*)d_in[13];
  const float* b2    = (const float*)d_in[14];
  const float* ln2g  = (const float*)d_in[15];
  const float* ln2b  = (const float*)d_in[16];
  const float* aw1   = (const float*)d_in[17];
  const float* ab1   = (const float*)d_in[18];
  const float* aw2   = (const float*)d_in[19];
  const float* ab2   = (const float*)d_in[20];
  const float* gw    = (const float*)d_in[21];
  const float* gb    = (const float*)d_in[22];
  float* out = (float*)d_out;

  typedef unsigned short us;
  char* base = (char*)d_ws;
  const size_t MB = 1ull << 20;

  // weights (persistent, 50 MB)
  us* wqTh = (us*)(base + 0 * MB);   us* wqTl = (us*)(base + 2 * MB);
  us* wkTh = (us*)(base + 4 * MB);   us* wkTl = (us*)(base + 6 * MB);
  us* wvTh = (us*)(base + 8 * MB);   us* wvTl = (us*)(base + 10 * MB);
  us* woTh = (us*)(base + 12 * MB);  us* woTl = (us*)(base + 14 * MB);
  us* w1Th = (us*)(base + 16 * MB);  us* w1Tl = (us*)(base + 24 * MB);
  us* w2Th = (us*)(base + 32 * MB);  us* w2Tl = (us*)(base + 40 * MB);
  us* a1Th = (us*)(base + 48 * MB);  us* a1Tl = (us*)(base + 49 * MB);
  // region A @50 (16 MB): x h/l -> ctx h/l -> FFNPRE f32
  us* xh   = (us*)(base + 50 * MB);  us* xl   = (us*)(base + 58 * MB);
  us* ctxh = xh;                     us* ctxl = xl;
  float* FFNPRE = (float*)(base + 50 * MB);
  // region B @66 (16 MB): Q f32 -> ATTNPRE -> LOUT
  float* Qb      = (float*)(base + 66 * MB);
  float* ATTNPRE = Qb;
  float* LOUT    = Qb;
  // region C @82 (16 MB): K f32 -> AO h/l
  float* Kb  = (float*)(base + 82 * MB);
  us* aoh = (us*)(base + 82 * MB);   us* aol = (us*)(base + 90 * MB);
  // region D @98 (16 MB): V f32 -> HALL f32
  float* Vb   = (float*)(base + 98 * MB);
  float* HALL = (float*)(base + 98 * MB);
  // region E @114 (64 MB): INTER h/l
  us* inth = (us*)(base + 114 * MB); us* intl = (us*)(base + 146 * MB);

  const dim3 blk(256);
  const us* nu = nullptr;
  const float* nf = nullptr;

  // --- precompute splits ---
  fsplit<<<dim3(NTOK * D_ / 1024), blk, 0, stream>>>(x, xh, xl, NTOK * D_ / 4);
  wsplit_t<<<dim3(16, 16), blk, 0, stream>>>(wq, wqTh, wqTl, D_, D_);
  wsplit_t<<<dim3(16, 16), blk, 0, stream>>>(wk, wkTh, wkTl, D_, D_);
  wsplit_t<<<dim3(16, 16), blk, 0, stream>>>(wv, wvTh, wvTl, D_, D_);
  wsplit_t<<<dim3(16, 16), blk, 0, stream>>>(wo, woTh, woTl, D_, D_);
  wsplit_t<<<dim3(64, 16), blk, 0, stream>>>(w1, w1Th, w1Tl, D_, FF_);
  wsplit_t<<<dim3(16, 64), blk, 0, stream>>>(w2, w2Th, w2Tl, FF_, D_);
  wsplit_t<<<dim3(8, 16),  blk, 0, stream>>>(aw1, a1Th, a1Tl, D_, E_ * R_);

  // --- QKV projections ---
  {
    dim3 g(D_ / 128, NTOK / 128);
    gemm_mfma<0><<<g, blk, 0, stream>>>(xh, xl, wqTh, wqTl, bq, nf, nu, nu, Qb, nullptr, nullptr, NTOK, D_, D_);
    gemm_mfma<0><<<g, blk, 0, stream>>>(xh, xl, wkTh, wkTl, bk, nf, nu, nu, Kb, nullptr, nullptr, NTOK, D_, D_);
    gemm_mfma<0><<<g, blk, 0, stream>>>(xh, xl, wvTh, wvTl, bv, nf, nu, nu, Vb, nullptr, nullptr, NTOK, D_, D_);
  }
  // --- attention (fp32, ctx -> hi/lo) ---
  attn_f32<<<dim3(L_ / 16, B_ * H_), blk, 0, stream>>>(Qb, Kb, Vb, ctxh, ctxl);
  // --- output projection + residual(x), LN1 -> AO hi/lo ---
  {
    dim3 g(D_ / 128, NTOK / 128);
    gemm_mfma<2><<<g, blk, 0, stream>>>(ctxh, ctxl, woTh, woTl, bo, x, nu, nu, ATTNPRE, nullptr, nullptr, NTOK, D_, D_);
    layernorm_k<1><<<dim3(NTOK), blk, 0, stream>>>(ATTNPRE, ln1g, ln1b, nullptr, aoh, aol);
  }
  // --- FFN ---
  {
    dim3 g1(FF_ / 128, NTOK / 128);
    gemm_mfma<3><<<g1, blk, 0, stream>>>(aoh, aol, w1Th, w1Tl, b1, nf, nu, nu, nullptr, inth, intl, NTOK, FF_, D_);
    dim3 g2(D_ / 128, NTOK / 128);
    gemm_mfma<4><<<g2, blk, 0, stream>>>(inth, intl, w2Th, w2Tl, b2, nf, aoh, aol, FFNPRE, nullptr, nullptr, NTOK, D_, FF_);
    layernorm_k<0><<<dim3(NTOK), blk, 0, stream>>>(FFNPRE, ln2g, ln2b, LOUT, nullptr, nullptr);
  }
  // --- adapter (after FFN2: HALL overlays V region, INTER still in E) ---
  {
    dim3 g(E_ * R_ / 128, NTOK / 128);
    gemm_mfma<1><<<g, blk, 0, stream>>>(aoh, aol, a1Th, a1Tl, ab1, nf, nu, nu, HALL, nullptr, nullptr, NTOK, E_ * R_, D_);
    adapter_combine_hl<<<dim3(NTOK), blk, 0, stream>>>(aoh, aol, HALL, LOUT, aw2, ab2, gw, gb, out);
  }
}

// Round 3
// 866.156 us; speedup vs baseline: 2.5764x; 1.4935x over previous
//
#include <hip/hip_runtime.h>
#include <cstddef>
#include <cstdint>

#define B_   4
#define L_   1024
#define D_   1024
#define H_   16
#define DH_  64
#define E_   8
#define R_   64
#define FF_  4096
#define NTOK (B_ * L_)   // 4096

typedef __attribute__((ext_vector_type(8))) short bf16x8;
typedef __attribute__((ext_vector_type(4))) float f32x4;
typedef unsigned short us;

__device__ __forceinline__ float gelu_f(float x) {
  return 0.5f * x * (1.0f + erff(x * 0.7071067811865476f));
}

__device__ __forceinline__ us bf16_of(float f) {
  union { float f; uint32_t u; } x; x.f = f;
  uint32_t r = x.u + 0x7FFFu + ((x.u >> 16) & 1u);   // RNE
  return (us)(r >> 16);
}
__device__ __forceinline__ float f32_of(us h) {
  union { uint32_t u; float f; } x; x.u = ((uint32_t)h) << 16;
  return x.f;
}
__device__ __forceinline__ void split_hl(float v, us& hi, us& lo) {
  hi = bf16_of(v);
  lo = bf16_of(v - f32_of(hi));
}

__device__ __forceinline__ void glds16(const void* g, const void* l) {
  __builtin_amdgcn_global_load_lds(
      (const __attribute__((address_space(1))) unsigned int*)g,
      (__attribute__((address_space(3))) unsigned int*)l, 16, 0, 0);
}

// ---------------------------------------------------------------------------
// Elementwise fp32 -> bf16 hi/lo split.
// ---------------------------------------------------------------------------
__global__ __launch_bounds__(256)
void fsplit(const float* __restrict__ X, us* __restrict__ Hh,
            us* __restrict__ Ll, int n4) {
  int i = blockIdx.x * 256 + threadIdx.x;
  if (i >= n4) return;
  float4 v = ((const float4*)X)[i];
  ushort4 h, l;
  split_hl(v.x, h.x, l.x); split_hl(v.y, h.y, l.y);
  split_hl(v.z, h.z, l.z); split_hl(v.w, h.w, l.w);
  ((ushort4*)Hh)[i] = h;
  ((ushort4*)Ll)[i] = l;
}

// ---------------------------------------------------------------------------
// Weight split+transpose: W[K,N] fp32 -> Th,Tl [N,K] bf16.
// ---------------------------------------------------------------------------
__global__ __launch_bounds__(256)
void wsplit_t(const float* __restrict__ W, us* __restrict__ Th,
              us* __restrict__ Tl, int K, int N) {
  __shared__ float tile[64][65];
  const int k0 = blockIdx.y * 64, n0 = blockIdx.x * 64;
  const int t = threadIdx.x;
  const int r = t >> 4, c4 = (t & 15) * 4;
  #pragma unroll
  for (int p = 0; p < 4; ++p) {
    const int k = r + p * 16;
    *(float4*)&tile[k][c4] = *(const float4*)&W[(size_t)(k0 + k) * N + n0 + c4];
  }
  __syncthreads();
  #pragma unroll
  for (int p = 0; p < 4; ++p) {
    const int n = r + p * 16;
    float v0 = tile[c4 + 0][n], v1 = tile[c4 + 1][n];
    float v2 = tile[c4 + 2][n], v3 = tile[c4 + 3][n];
    ushort4 h, l;
    split_hl(v0, h.x, l.x); split_hl(v1, h.y, l.y);
    split_hl(v2, h.z, l.z); split_hl(v3, h.w, l.w);
    const size_t o = (size_t)(n0 + n) * K + k0 + c4;
    *(ushort4*)&Th[o] = h;
    *(ushort4*)&Tl[o] = l;
  }
}

// ---------------------------------------------------------------------------
// Split-bf16 MFMA GEMM, 128x128 tile, BK=32, 4 waves, 4x4 frags.
// EPI: 0 bias->f32 | 1 bias+gelu->f32 | 2 bias+resF->f32 | 3 bias+gelu->hl
//      4 bias+resHL->f32 | 5 bias->hl | 6 bias->hl V-TRANSPOSED [B*H*64][L]
// ---------------------------------------------------------------------------
template<int EPI>
__global__ __launch_bounds__(256, 2)
void gemm_mfma(const us* __restrict__ Ah, const us* __restrict__ Al,
               const us* __restrict__ Bh, const us* __restrict__ Bl,
               const float* __restrict__ bias,
               const float* __restrict__ ResF,
               const us* __restrict__ ResH, const us* __restrict__ ResL,
               float* __restrict__ Cf, us* __restrict__ Ch, us* __restrict__ Cl,
               int M, int N, int K) {
  __shared__ us sAh[128 * 32], sAl[128 * 32];
  __shared__ us sBh[128 * 32], sBl[128 * 32];

  const int t = threadIdx.x;
  const int lane = t & 63;
  const int wid = t >> 6;
  const int wm = wid >> 1, wn = wid & 1;

  const int nwgx = gridDim.x;
  const int nwg = nwgx * gridDim.y;
  const int idl = blockIdx.y * nwgx + blockIdx.x;
  const int swz = (idl & 7) * (nwg >> 3) + (idl >> 3);
  const int m0 = (swz / nwgx) * 128;
  const int n0 = (swz % nwgx) * 128;

  const int srow = wid * 32 + (lane >> 2);
  const int skoff = (lane & 3) * 8;

  f32x4 acc[4][4];
  #pragma unroll
  for (int i = 0; i < 4; ++i)
    #pragma unroll
    for (int j = 0; j < 4; ++j)
      acc[i][j] = (f32x4){0.f, 0.f, 0.f, 0.f};

  const int fr = lane & 15, fq = lane >> 4;

  for (int k0 = 0; k0 < K; k0 += 32) {
    __syncthreads();
    #pragma unroll
    for (int c = 0; c < 2; ++c) {
      const size_t ga = (size_t)(m0 + srow + c * 16) * K + k0 + skoff;
      const size_t gb = (size_t)(n0 + srow + c * 16) * K + k0 + skoff;
      const int ldso = (wid * 32 + c * 16) * 32;
      glds16(Ah + ga, &sAh[ldso]);
      glds16(Al + ga, &sAl[ldso]);
      glds16(Bh + gb, &sBh[ldso]);
      glds16(Bl + gb, &sBl[ldso]);
    }
    __syncthreads();

    bf16x8 ah[4], al[4], bh[4], bl[4];
    #pragma unroll
    for (int i = 0; i < 4; ++i) {
      const int ra = (wm * 64 + i * 16 + fr) * 32 + fq * 8;
      ah[i] = *(const bf16x8*)&sAh[ra];
      al[i] = *(const bf16x8*)&sAl[ra];
      const int rb = (wn * 64 + i * 16 + fr) * 32 + fq * 8;
      bh[i] = *(const bf16x8*)&sBh[rb];
      bl[i] = *(const bf16x8*)&sBl[rb];
    }
    #pragma unroll
    for (int i = 0; i < 4; ++i)
      #pragma unroll
      for (int j = 0; j < 4; ++j) {
        acc[i][j] = __builtin_amdgcn_mfma_f32_16x16x32_bf16(ah[i], bh[j], acc[i][j], 0, 0, 0);
        acc[i][j] = __builtin_amdgcn_mfma_f32_16x16x32_bf16(al[i], bh[j], acc[i][j], 0, 0, 0);
        acc[i][j] = __builtin_amdgcn_mfma_f32_16x16x32_bf16(ah[i], bl[j], acc[i][j], 0, 0, 0);
      }
  }

  float bcol[4];
  #pragma unroll
  for (int j = 0; j < 4; ++j) bcol[j] = bias[n0 + wn * 64 + j * 16 + fr];

  if (EPI == 6) {
    // V-transposed write: Ch/Cl are Vt [B*H*64(dh)][L] bf16 hi/lo
    #pragma unroll
    for (int i = 0; i < 4; ++i) {
      #pragma unroll
      for (int j = 0; j < 4; ++j) {
        ushort4 h4, l4;
        float v0 = acc[i][j][0] + bcol[j];
        float v1 = acc[i][j][1] + bcol[j];
        float v2 = acc[i][j][2] + bcol[j];
        float v3 = acc[i][j][3] + bcol[j];
        split_hl(v0, h4.x, l4.x); split_hl(v1, h4.y, l4.y);
        split_hl(v2, h4.z, l4.z); split_hl(v3, h4.w, l4.w);
        const int colg = n0 + wn * 64 + j * 16 + fr;      // d global
        const int hh2 = colg >> 6, dh = colg & 63;
        const int row0r = m0 + wm * 64 + i * 16 + fq * 4; // token
        const int bb = row0r >> 10, ltok = row0r & 1023;
        const size_t off = ((size_t)(bb * 16 + hh2) * 64 + dh) * L_ + ltok;
        *(ushort4*)&Ch[off] = h4;
        *(ushort4*)&Cl[off] = l4;
      }
    }
    return;
  }

  #pragma unroll
  for (int i = 0; i < 4; ++i) {
    #pragma unroll
    for (int r = 0; r < 4; ++r) {
      const int row = m0 + wm * 64 + i * 16 + fq * 4 + r;
      const size_t ro = (size_t)row * N;
      #pragma unroll
      for (int j = 0; j < 4; ++j) {
        const int col = n0 + wn * 64 + j * 16 + fr;
        float v = acc[i][j][r] + bcol[j];
        if (EPI == 1) {
          Cf[ro + col] = gelu_f(v);
        } else if (EPI == 2) {
          Cf[ro + col] = v + ResF[ro + col];
        } else if (EPI == 3) {
          v = gelu_f(v);
          us h, l; split_hl(v, h, l);
          Ch[ro + col] = h; Cl[ro + col] = l;
        } else if (EPI == 4) {
          Cf[ro + col] = v + f32_of(ResH[ro + col]) + f32_of(ResL[ro + col]);
        } else if (EPI == 5) {
          us h, l; split_hl(v, h, l);
          Ch[ro + col] = h; Cl[ro + col] = l;
        } else {
          Cf[ro + col] = v;
        }
      }
    }
  }
}

// ---------------------------------------------------------------------------
// MFMA flash attention, split-bf16 everywhere (fp32-class accuracy).
// Grid (16, 64): 64 queries/block, one (b,h); 4 waves x 16 queries.
// Swapped QK^T (S^T = K·Q^T) and swapped PV (ctx^T = Vt·P^T): softmax state
// and ctx rescale are lane-local (q = lane&15).
// ---------------------------------------------------------------------------
__global__ __launch_bounds__(256, 3)
void attn_mfma(const us* __restrict__ Qh, const us* __restrict__ Ql,
               const us* __restrict__ Kh, const us* __restrict__ Kl,
               const us* __restrict__ Vth, const us* __restrict__ Vtl,
               us* __restrict__ Oh, us* __restrict__ Ol) {
  // XCD swizzle: all 16 q-tiles of a head (and 8 heads) land on one XCD
  const int raw = blockIdx.x + blockIdx.y * 16;
  const int hh = (raw & 7) + 8 * ((raw >> 3) >> 4);  // global head 0..63
  const int qq = (raw >> 3) & 15;                    // q-tile 0..15
  const int b = hh >> 4, h = hh & 15;

  const int t = threadIdx.x;
  const int w = t >> 6, lane = t & 63;
  const int fr = lane & 15, g = lane >> 4;

  __shared__ __align__(16) unsigned char smem[51200];
  us* sKh = (us*)(smem);            // [2 ks][64 key][32]   8192 B
  us* sKl = (us*)(smem + 8192);
  us* sVh = (us*)(smem + 16384);    // [64 d][64 key] (chunk-swizzled) 8192 B
  us* sVl = (us*)(smem + 24576);
  us* sPh = (us*)(smem + 32768);    // [4 w][16 q][72] 9216 B
  us* sPl = (us*)(smem + 41984);
  float* fb = (float*)smem;         // [64 d][64 q] f32 epilogue reuse

  // Q fragments in registers (B-operand: lane reads Q[q=fr][ks*32+g*8..])
  const int tok0 = b * L_ + qq * 64 + w * 16;
  bf16x8 qfh[2], qfl[2];
  #pragma unroll
  for (int ks = 0; ks < 2; ++ks) {
    const size_t qo = (size_t)(tok0 + fr) * D_ + h * 64 + ks * 32 + g * 8;
    qfh[ks] = *(const bf16x8*)&Qh[qo];
    qfl[ks] = *(const bf16x8*)&Ql[qo];
  }

  float m = -INFINITY, l = 0.0f;
  f32x4 ctx[4];
  #pragma unroll
  for (int i = 0; i < 4; ++i) ctx[i] = (f32x4){0.f, 0.f, 0.f, 0.f};

  for (int kt = 0; kt < 16; ++kt) {
    const int k0 = kt * 64;
    __syncthreads();
    // ---- stage K (hi/lo) and Vt (hi/lo, chunk-swizzled) via global_load_lds
    #pragma unroll
    for (int p = 0; p < 2; ++p) {
      const int ci = w * 128 + p * 64 + lane;   // chunk index 0..511
      const int dbase = (w * 128 + p * 64) * 8; // us offset of wave-uniform dest
      // K: ci -> (ks, key, sub)
      {
        const int ks = ci >> 8, rem = ci & 255, key = rem >> 2, sub = rem & 3;
        const size_t src = (size_t)(b * L_ + k0 + key) * D_ + h * 64 + ks * 32 + sub * 8;
        glds16(Kh + src, sKh + dbase);
        glds16(Kl + src, sKl + dbase);
      }
      // Vt: ci -> (d, chunk c); source chunk = c ^ (d&7)  (read-side XOR matches)
      {
        const int d = ci >> 3, c = ci & 7;
        const size_t src = (size_t)(hh * 64 + d) * L_ + k0 + ((c ^ (d & 7)) * 8);
        glds16(Vth + src, sVh + dbase);
        glds16(Vtl + src, sVl + dbase);
      }
    }
    __syncthreads();

    // ---- QK^T (swapped): accS[i] rows = key i*16+g*4+r, col = q = fr
    f32x4 accS[4];
    #pragma unroll
    for (int i = 0; i < 4; ++i) accS[i] = (f32x4){0.f, 0.f, 0.f, 0.f};
    #pragma unroll
    for (int ks = 0; ks < 2; ++ks) {
      #pragma unroll
      for (int i = 0; i < 4; ++i) {
        const int ra = (ks * 64 + i * 16 + fr) * 32 + g * 8;
        bf16x8 ah = *(const bf16x8*)&sKh[ra];
        bf16x8 al = *(const bf16x8*)&sKl[ra];
        accS[i] = __builtin_amdgcn_mfma_f32_16x16x32_bf16(ah, qfh[ks], accS[i], 0, 0, 0);
        accS[i] = __builtin_amdgcn_mfma_f32_16x16x32_bf16(al, qfh[ks], accS[i], 0, 0, 0);
        accS[i] = __builtin_amdgcn_mfma_f32_16x16x32_bf16(ah, qfl[ks], accS[i], 0, 0, 0);
      }
    }

    // ---- online softmax (per lane, q = fr; reduce across g via xor 16,32)
    float sv[4][4];
    float mloc = -INFINITY;
    #pragma unroll
    for (int i = 0; i < 4; ++i)
      #pragma unroll
      for (int r = 0; r < 4; ++r) {
        sv[i][r] = accS[i][r] * 0.125f;
        mloc = fmaxf(mloc, sv[i][r]);
      }
    mloc = fmaxf(mloc, __shfl_xor(mloc, 16));
    mloc = fmaxf(mloc, __shfl_xor(mloc, 32));
    const float mnew = fmaxf(m, mloc);
    const float alpha = expf(m - mnew);
    float p[4][4];
    float lt = 0.f;
    #pragma unroll
    for (int i = 0; i < 4; ++i)
      #pragma unroll
      for (int r = 0; r < 4; ++r) {
        p[i][r] = expf(sv[i][r] - mnew);
        lt += p[i][r];
      }
    lt += __shfl_xor(lt, 16);
    lt += __shfl_xor(lt, 32);
    l = l * alpha + lt;
    m = mnew;
    #pragma unroll
    for (int i = 0; i < 4; ++i) {
      ctx[i][0] *= alpha; ctx[i][1] *= alpha;
      ctx[i][2] *= alpha; ctx[i][3] *= alpha;
    }

    // ---- pack P to bf16 hi/lo, write to per-wave LDS [q=fr][key]
    #pragma unroll
    for (int i = 0; i < 4; ++i) {
      us h0 = bf16_of(p[i][0]), h1 = bf16_of(p[i][1]);
      us h2 = bf16_of(p[i][2]), h3 = bf16_of(p[i][3]);
      uint2 hv = {(uint32_t)h0 | ((uint32_t)h1 << 16),
                  (uint32_t)h2 | ((uint32_t)h3 << 16)};
      us l0 = bf16_of(p[i][0] - f32_of(h0)), l1 = bf16_of(p[i][1] - f32_of(h1));
      us l2 = bf16_of(p[i][2] - f32_of(h2)), l3 = bf16_of(p[i][3] - f32_of(h3));
      uint2 lv = {(uint32_t)l0 | ((uint32_t)l1 << 16),
                  (uint32_t)l2 | ((uint32_t)l3 << 16)};
      const int po = (w * 16 + fr) * 72 + i * 16 + g * 4;
      *(uint2*)&sPh[po] = hv;
      *(uint2*)&sPl[po] = lv;
    }

    // ---- PV (swapped): ctx[i] rows = d = i*16+g*4+r, col = q = fr
    #pragma unroll
    for (int ks = 0; ks < 2; ++ks) {
      const int pb = (w * 16 + fr) * 72 + ks * 32 + g * 8;
      bf16x8 pah = *(const bf16x8*)&sPh[pb];
      bf16x8 pal = *(const bf16x8*)&sPl[pb];
      #pragma unroll
      for (int i = 0; i < 4; ++i) {
        const int d = i * 16 + fr;
        const int pc = (ks * 4 + g) ^ (d & 7);
        bf16x8 vh = *(const bf16x8*)&sVh[d * 64 + pc * 8];
        bf16x8 vl = *(const bf16x8*)&sVl[d * 64 + pc * 8];
        ctx[i] = __builtin_amdgcn_mfma_f32_16x16x32_bf16(vh, pah, ctx[i], 0, 0, 0);
        ctx[i] = __builtin_amdgcn_mfma_f32_16x16x32_bf16(vl, pah, ctx[i], 0, 0, 0);
        ctx[i] = __builtin_amdgcn_mfma_f32_16x16x32_bf16(vh, pal, ctx[i], 0, 0, 0);
      }
    }
  }

  // ---- epilogue: normalize, transpose ctx^T[d][q] -> ctx[q][d] via LDS
  const float invl = 1.0f / l;
  __syncthreads();
  #pragma unroll
  for (int i = 0; i < 4; ++i)
    #pragma unroll
    for (int r = 0; r < 4; ++r)
      fb[(i * 16 + g * 4 + r) * 64 + w * 16 + fr] = ctx[i][r] * invl;
  __syncthreads();

  {
    const int q = t >> 2, dg = t & 3;
    const size_t ob = (size_t)(b * L_ + qq * 64 + q) * D_ + h * 64;
    #pragma unroll
    for (int u = 0; u < 4; ++u) {
      const int d0 = dg * 16 + u * 4;
      ushort4 h4, l4;
      float v0 = fb[(d0 + 0) * 64 + q];
      float v1 = fb[(d0 + 1) * 64 + q];
      float v2 = fb[(d0 + 2) * 64 + q];
      float v3 = fb[(d0 + 3) * 64 + q];
      split_hl(v0, h4.x, l4.x); split_hl(v1, h4.y, l4.y);
      split_hl(v2, h4.z, l4.z); split_hl(v3, h4.w, l4.w);
      *(ushort4*)&Oh[ob + d0] = h4;
      *(ushort4*)&Ol[ob + d0] = l4;
    }
  }
}

// ---------------------------------------------------------------------------
// LayerNorm over D=1024.  MODE 0: fp32 out; MODE 1: bf16 hi/lo out.
// ---------------------------------------------------------------------------
template<int MODE>
__global__ __launch_bounds__(256)
void layernorm_k(const float* __restrict__ X, const float* __restrict__ g,
                 const float* __restrict__ b, float* __restrict__ Yf,
                 us* __restrict__ Yh, us* __restrict__ Yl) {
  const int row = blockIdx.x;
  const int t = threadIdx.x;
  const float* x = X + (size_t)row * D_;

  float4 v = *(const float4*)&x[t * 4];
  float s  = v.x + v.y + v.z + v.w;
  float ss = v.x * v.x + v.y * v.y + v.z * v.z + v.w * v.w;

  #pragma unroll
  for (int off = 1; off < 64; off <<= 1) {
    s  += __shfl_xor(s, off);
    ss += __shfl_xor(ss, off);
  }
  __shared__ float red[4][2];
  const int wid = t >> 6;
  if ((t & 63) == 0) { red[wid][0] = s; red[wid][1] = ss; }
  __syncthreads();
  s  = red[0][0] + red[1][0] + red[2][0] + red[3][0];
  ss = red[0][1] + red[1][1] + red[2][1] + red[3][1];

  const float mean = s * (1.0f / D_);
  const float var  = ss * (1.0f / D_) - mean * mean;
  const float inv  = rsqrtf(var + 1e-5f);

  float4 gv = *(const float4*)&g[t * 4];
  float4 bv = *(const float4*)&b[t * 4];
  float4 o;
  o.x = (v.x - mean) * inv * gv.x + bv.x;
  o.y = (v.y - mean) * inv * gv.y + bv.y;
  o.z = (v.z - mean) * inv * gv.z + bv.z;
  o.w = (v.w - mean) * inv * gv.w + bv.w;
  if (MODE == 0) {
    *(float4*)&Yf[(size_t)row * D_ + t * 4] = o;
  } else {
    ushort4 h, l;
    split_hl(o.x, h.x, l.x); split_hl(o.y, h.y, l.y);
    split_hl(o.z, h.z, l.z); split_hl(o.w, h.w, l.w);
    *(ushort4*)&Yh[(size_t)row * D_ + t * 4] = h;
    *(ushort4*)&Yl[(size_t)row * D_ + t * 4] = l;
  }
}

// ---------------------------------------------------------------------------
// Fused adapter: gate + top-2 + softmax + 2-expert R->D + residual combine.
// ---------------------------------------------------------------------------
__global__ __launch_bounds__(256)
void adapter_combine_hl(const us* __restrict__ Xh, const us* __restrict__ Xl,
                        const float* __restrict__ Hall,
                        const float* __restrict__ Lout,
                        const float* __restrict__ W2,
                        const float* __restrict__ B2,
                        const float* __restrict__ GW,
                        const float* __restrict__ GB,
                        float* __restrict__ Out) {
  const int tok = blockIdx.x;
  const int t = threadIdx.x;

  __shared__ float xs[D_];
  __shared__ float part[256];
  __shared__ float logit_s[E_];
  __shared__ float hs[2 * R_];
  __shared__ int   e_sh[2];
  __shared__ float g_sh[2];

  {
    ushort4 h = *(const ushort4*)&Xh[(size_t)tok * D_ + t * 4];
    ushort4 l = *(const ushort4*)&Xl[(size_t)tok * D_ + t * 4];
    xs[t * 4 + 0] = f32_of(h.x) + f32_of(l.x);
    xs[t * 4 + 1] = f32_of(h.y) + f32_of(l.y);
    xs[t * 4 + 2] = f32_of(h.z) + f32_of(l.z);
    xs[t * 4 + 3] = f32_of(h.w) + f32_of(l.w);
  }
  __syncthreads();

  {
    const int e = t & 7, seg = t >> 3;
    float p = 0.f;
    #pragma unroll 8
    for (int i = 0; i < 32; ++i) {
      const int d = seg * 32 + i;
      p = fmaf(xs[d], GW[d * E_ + e], p);
    }
    part[t] = p;
  }
  __syncthreads();
  if (t < E_) {
    float s = GB[t];
    for (int sg = 0; sg < 32; ++sg) s += part[sg * 8 + t];
    logit_s[t] = s;
  }
  __syncthreads();
  if (t == 0) {
    int e1 = 0; float v1 = logit_s[0];
    for (int i = 1; i < E_; ++i) if (logit_s[i] > v1) { v1 = logit_s[i]; e1 = i; }
    int e2 = -1; float v2 = -INFINITY;
    for (int i = 0; i < E_; ++i) if (i != e1 && logit_s[i] > v2) { v2 = logit_s[i]; e2 = i; }
    const float ee = expf(v2 - v1);
    const float den = 1.0f + ee;
    g_sh[0] = 1.0f / den; g_sh[1] = ee / den;
    e_sh[0] = e1; e_sh[1] = e2;
  }
  __syncthreads();
  const int e1 = e_sh[0], e2 = e_sh[1];
  const float g1 = g_sh[0], g2 = g_sh[1];

  if (t < 2 * R_) {
    const int ex = (t < R_) ? e1 : e2;
    const int r = t & (R_ - 1);
    hs[t] = Hall[(size_t)tok * (E_ * R_) + ex * R_ + r];
  }
  __syncthreads();

  const int d = t * 4;
  float4 b1v = *(const float4*)&B2[e1 * D_ + d];
  float4 b2v = *(const float4*)&B2[e2 * D_ + d];
  float4 acc;
  acc.x = g1 * b1v.x + g2 * b2v.x;
  acc.y = g1 * b1v.y + g2 * b2v.y;
  acc.z = g1 * b1v.z + g2 * b2v.z;
  acc.w = g1 * b1v.w + g2 * b2v.w;

  #pragma unroll 8
  for (int r = 0; r < R_; ++r) {
    const float f = g1 * hs[r];
    float4 w = *(const float4*)&W2[((size_t)e1 * R_ + r) * D_ + d];
    acc.x = fmaf(f, w.x, acc.x); acc.y = fmaf(f, w.y, acc.y);
    acc.z = fmaf(f, w.z, acc.z); acc.w = fmaf(f, w.w, acc.w);
  }
  #pragma unroll 8
  for (int r = 0; r < R_; ++r) {
    const float f = g2 * hs[R_ + r];
    float4 w = *(const float4*)&W2[((size_t)e2 * R_ + r) * D_ + d];
    acc.x = fmaf(f, w.x, acc.x); acc.y = fmaf(f, w.y, acc.y);
    acc.z = fmaf(f, w.z, acc.z); acc.w = fmaf(f, w.w, acc.w);
  }

  float4 lo = *(const float4*)&Lout[(size_t)tok * D_ + d];
  float4 o = {lo.x + 2.0f * acc.x, lo.y + 2.0f * acc.y,
              lo.z + 2.0f * acc.z, lo.w + 2.0f * acc.w};
  *(float4*)&Out[(size_t)tok * D_ + d] = o;
}

// ---------------------------------------------------------------------------
extern "C" void kernel_launch(void* const* d_in, const int* in_sizes, int n_in,
                              void* d_out, int out_size, void* d_ws, size_t ws_size,
                              hipStream_t stream) {
  const float* x     = (const float*)d_in[0];
  const float* wq    = (const float*)d_in[1];
  const float* wk    = (const float*)d_in[2];
  const float* wv    = (const float*)d_in[3];
  const float* wo    = (const float*)d_in[4];
  const float* bq    = (const float*)d_in[5];
  const float* bk    = (const float*)d_in[6];
  const float* bv    = (const float*)d_in[7];
  const float* bo    = (const float*)d_in[8];
  const float* ln1g  = (const float*)d_in[9];
  const float* ln1b  = (const float*)d_in[10];
  const float* w1    = (const float*)d_in[11];
  const float* b1    = (const float*)d_in[12];
  const float* w2    = (const float*)d_in[13];
  const float* b2    = (const float*)d_in[14];
  const float* ln2g  = (const float*)d_in[15];
  const float* ln2b  = (const float*)d_in[16];
  const float* aw1   = (const float*)d_in[17];
  const float* ab1   = (const float*)d_in[18];
  const float* aw2   = (const float*)d_in[19];
  const float* ab2   = (const float*)d_in[20];
  const float* gw    = (const float*)d_in[21];
  const float* gb    = (const float*)d_in[22];
  float* out = (float*)d_out;

  char* base = (char*)d_ws;
  const size_t MB = 1ull << 20;

  // weights (persistent, 50 MB)
  us* wqTh = (us*)(base + 0 * MB);   us* wqTl = (us*)(base + 2 * MB);
  us* wkTh = (us*)(base + 4 * MB);   us* wkTl = (us*)(base + 6 * MB);
  us* wvTh = (us*)(base + 8 * MB);   us* wvTl = (us*)(base + 10 * MB);
  us* woTh = (us*)(base + 12 * MB);  us* woTl = (us*)(base + 14 * MB);
  us* w1Th = (us*)(base + 16 * MB);  us* w1Tl = (us*)(base + 24 * MB);
  us* w2Th = (us*)(base + 32 * MB);  us* w2Tl = (us*)(base + 40 * MB);
  us* a1Th = (us*)(base + 48 * MB);  us* a1Tl = (us*)(base + 49 * MB);
  // region A @50: xh/xl -> ctxh/ctxl -> LOUT f32
  us* xh   = (us*)(base + 50 * MB);  us* xl   = (us*)(base + 58 * MB);
  us* ctxh = xh;                     us* ctxl = xl;
  float* LOUT = (float*)(base + 50 * MB);
  // region B @66: Qh/Ql -> ATTNPRE f32 -> HALL f32
  us* qbh = (us*)(base + 66 * MB);   us* qbl = (us*)(base + 74 * MB);
  float* ATTNPRE = (float*)(base + 66 * MB);
  float* HALL    = (float*)(base + 66 * MB);
  // region C @82: Kh/Kl -> aoh/aol
  us* kbh = (us*)(base + 82 * MB);   us* kbl = (us*)(base + 90 * MB);
  us* aoh = (us*)(base + 82 * MB);   us* aol = (us*)(base + 90 * MB);
  // region D @98: Vth/Vtl -> FFNPRE f32
  us* vth = (us*)(base + 98 * MB);   us* vtl = (us*)(base + 106 * MB);
  float* FFNPRE = (float*)(base + 98 * MB);
  // region E @114: INTER h/l (64 MB)
  us* inth = (us*)(base + 114 * MB); us* intl = (us*)(base + 146 * MB);

  const dim3 blk(256);
  const us* nu = nullptr;
  const float* nf = nullptr;

  // --- precompute splits ---
  fsplit<<<dim3(NTOK * D_ / 1024), blk, 0, stream>>>(x, xh, xl, NTOK * D_ / 4);
  wsplit_t<<<dim3(16, 16), blk, 0, stream>>>(wq, wqTh, wqTl, D_, D_);
  wsplit_t<<<dim3(16, 16), blk, 0, stream>>>(wk, wkTh, wkTl, D_, D_);
  wsplit_t<<<dim3(16, 16), blk, 0, stream>>>(wv, wvTh, wvTl, D_, D_);
  wsplit_t<<<dim3(16, 16), blk, 0, stream>>>(wo, woTh, woTl, D_, D_);
  wsplit_t<<<dim3(64, 16), blk, 0, stream>>>(w1, w1Th, w1Tl, D_, FF_);
  wsplit_t<<<dim3(16, 64), blk, 0, stream>>>(w2, w2Th, w2Tl, FF_, D_);
  wsplit_t<<<dim3(8, 16),  blk, 0, stream>>>(aw1, a1Th, a1Tl, D_, E_ * R_);

  // --- QKV projections: Q,K -> [tok][D] hi/lo; V -> transposed [B*H*64][L]
  {
    dim3 g(D_ / 128, NTOK / 128);
    gemm_mfma<5><<<g, blk, 0, stream>>>(xh, xl, wqTh, wqTl, bq, nf, nu, nu, nullptr, qbh, qbl, NTOK, D_, D_);
    gemm_mfma<5><<<g, blk, 0, stream>>>(xh, xl, wkTh, wkTl, bk, nf, nu, nu, nullptr, kbh, kbl, NTOK, D_, D_);
    gemm_mfma<6><<<g, blk, 0, stream>>>(xh, xl, wvTh, wvTl, bv, nf, nu, nu, nullptr, vth, vtl, NTOK, D_, D_);
  }
  // --- attention (MFMA, split-bf16): ctx hi/lo ---
  attn_mfma<<<dim3(16, 64), blk, 0, stream>>>(qbh, qbl, kbh, kbl, vth, vtl, ctxh, ctxl);
  // --- output projection + residual(x), LN1 -> AO hi/lo ---
  {
    dim3 g(D_ / 128, NTOK / 128);
    gemm_mfma<2><<<g, blk, 0, stream>>>(ctxh, ctxl, woTh, woTl, bo, x, nu, nu, ATTNPRE, nullptr, nullptr, NTOK, D_, D_);
    layernorm_k<1><<<dim3(NTOK), blk, 0, stream>>>(ATTNPRE, ln1g, ln1b, nullptr, aoh, aol);
  }
  // --- FFN ---
  {
    dim3 g1(FF_ / 128, NTOK / 128);
    gemm_mfma<3><<<g1, blk, 0, stream>>>(aoh, aol, w1Th, w1Tl, b1, nf, nu, nu, nullptr, inth, intl, NTOK, FF_, D_);
    dim3 g2(D_ / 128, NTOK / 128);
    gemm_mfma<4><<<g2, blk, 0, stream>>>(inth, intl, w2Th, w2Tl, b2, nf, aoh, aol, FFNPRE, nullptr, nullptr, NTOK, D_, FF_);
    layernorm_k<0><<<dim3(NTOK), blk, 0, stream>>>(FFNPRE, ln2g, ln2b, LOUT, nullptr, nullptr);
  }
  // --- adapter ---
  {
    dim3 g(E_ * R_ / 128, NTOK / 128);
    gemm_mfma<1><<<g, blk, 0, stream>>>(aoh, aol, a1Th, a1Tl, ab1, nf, nu, nu, HALL, nullptr, nullptr, NTOK, E_ * R_, D_);
    adapter_combine_hl<<<dim3(NTOK), blk, 0, stream>>>(aoh, aol, HALL, LOUT, aw2, ab2, gw, gb, out);
  }
}

// Round 4
// 853.092 us; speedup vs baseline: 2.6158x; 1.0153x over previous
//
#include <hip/hip_runtime.h>
#include <cstddef>
#include <cstdint>

#define B_   4
#define L_   1024
#define D_   1024
#define H_   16
#define DH_  64
#define E_   8
#define R_   64
#define FF_  4096
#define NTOK (B_ * L_)   // 4096

typedef __attribute__((ext_vector_type(8))) short bf16x8;
typedef __attribute__((ext_vector_type(4))) float f32x4;
typedef unsigned short us;

__device__ __forceinline__ float gelu_f(float x) {
  return 0.5f * x * (1.0f + erff(x * 0.7071067811865476f));
}

__device__ __forceinline__ us bf16_of(float f) {
  union { float f; uint32_t u; } x; x.f = f;
  uint32_t r = x.u + 0x7FFFu + ((x.u >> 16) & 1u);   // RNE
  return (us)(r >> 16);
}
__device__ __forceinline__ float f32_of(us h) {
  union { uint32_t u; float f; } x; x.u = ((uint32_t)h) << 16;
  return x.f;
}
__device__ __forceinline__ void split_hl(float v, us& hi, us& lo) {
  hi = bf16_of(v);
  lo = bf16_of(v - f32_of(hi));
}

__device__ __forceinline__ void glds16(const void* g, const void* l) {
  __builtin_amdgcn_global_load_lds(
      (const __attribute__((address_space(1))) unsigned int*)g,
      (__attribute__((address_space(3))) unsigned int*)l, 16, 0, 0);
}

// ---------------------------------------------------------------------------
// fp32 -> bf16 hi/lo split
// ---------------------------------------------------------------------------
__global__ __launch_bounds__(256)
void fsplit(const float* __restrict__ X, us* __restrict__ Hh,
            us* __restrict__ Ll, int n4) {
  int i = blockIdx.x * 256 + threadIdx.x;
  if (i >= n4) return;
  float4 v = ((const float4*)X)[i];
  ushort4 h, l;
  split_hl(v.x, h.x, l.x); split_hl(v.y, h.y, l.y);
  split_hl(v.z, h.z, l.z); split_hl(v.w, h.w, l.w);
  ((ushort4*)Hh)[i] = h;
  ((ushort4*)Ll)[i] = l;
}

// fp32 -> bf16 (hi only)
__global__ __launch_bounds__(256)
void fhi(const float* __restrict__ X, us* __restrict__ Hh, int n4) {
  int i = blockIdx.x * 256 + threadIdx.x;
  if (i >= n4) return;
  float4 v = ((const float4*)X)[i];
  ushort4 h = {bf16_of(v.x), bf16_of(v.y), bf16_of(v.z), bf16_of(v.w)};
  ((ushort4*)Hh)[i] = h;
}

// concat 3 x [1024] biases -> [3072]
__global__ __launch_bounds__(256)
void bconcat(const float* __restrict__ a, const float* __restrict__ b,
             const float* __restrict__ c, float* __restrict__ o) {
  int i = blockIdx.x * 256 + threadIdx.x;
  if (i >= 3072) return;
  o[i] = (i < 1024) ? a[i] : (i < 2048 ? b[i - 1024] : c[i - 2048]);
}

// ---------------------------------------------------------------------------
// Weight split+transpose: W[K,N] fp32 -> Th,Tl [N,K] bf16.
// ---------------------------------------------------------------------------
__global__ __launch_bounds__(256)
void wsplit_t(const float* __restrict__ W, us* __restrict__ Th,
              us* __restrict__ Tl, int K, int N) {
  __shared__ float tile[64][65];
  const int k0 = blockIdx.y * 64, n0 = blockIdx.x * 64;
  const int t = threadIdx.x;
  const int r = t >> 4, c4 = (t & 15) * 4;
  #pragma unroll
  for (int p = 0; p < 4; ++p) {
    const int k = r + p * 16;
    *(float4*)&tile[k][c4] = *(const float4*)&W[(size_t)(k0 + k) * N + n0 + c4];
  }
  __syncthreads();
  #pragma unroll
  for (int p = 0; p < 4; ++p) {
    const int n = r + p * 16;
    float v0 = tile[c4 + 0][n], v1 = tile[c4 + 1][n];
    float v2 = tile[c4 + 2][n], v3 = tile[c4 + 3][n];
    ushort4 h, l;
    split_hl(v0, h.x, l.x); split_hl(v1, h.y, l.y);
    split_hl(v2, h.z, l.z); split_hl(v3, h.w, l.w);
    const size_t o = (size_t)(n0 + n) * K + k0 + c4;
    *(ushort4*)&Th[o] = h;
    *(ushort4*)&Tl[o] = l;
  }
}

// ---------------------------------------------------------------------------
// OLD split-bf16 MFMA GEMM (kept for skinny GEMMs: proj, adapter dense1)
// EPI: 1 bias+gelu->f32 | 2 bias+resF->f32 | 4 bias+resHL->f32
// ---------------------------------------------------------------------------
template<int EPI>
__global__ __launch_bounds__(256, 2)
void gemm_mfma(const us* __restrict__ Ah, const us* __restrict__ Al,
               const us* __restrict__ Bh, const us* __restrict__ Bl,
               const float* __restrict__ bias,
               const float* __restrict__ ResF,
               const us* __restrict__ ResH, const us* __restrict__ ResL,
               float* __restrict__ Cf, us* __restrict__ Ch, us* __restrict__ Cl,
               int M, int N, int K) {
  __shared__ us sAh[128 * 32], sAl[128 * 32];
  __shared__ us sBh[128 * 32], sBl[128 * 32];

  const int t = threadIdx.x;
  const int lane = t & 63;
  const int wid = t >> 6;
  const int wm = wid >> 1, wn = wid & 1;

  const int nwgx = gridDim.x;
  const int nwg = nwgx * gridDim.y;
  const int idl = blockIdx.y * nwgx + blockIdx.x;
  const int swz = (idl & 7) * (nwg >> 3) + (idl >> 3);
  const int m0 = (swz / nwgx) * 128;
  const int n0 = (swz % nwgx) * 128;

  const int srow = wid * 32 + (lane >> 2);
  const int skoff = (lane & 3) * 8;

  f32x4 acc[4][4];
  #pragma unroll
  for (int i = 0; i < 4; ++i)
    #pragma unroll
    for (int j = 0; j < 4; ++j)
      acc[i][j] = (f32x4){0.f, 0.f, 0.f, 0.f};

  const int fr = lane & 15, fq = lane >> 4;

  for (int k0 = 0; k0 < K; k0 += 32) {
    __syncthreads();
    #pragma unroll
    for (int c = 0; c < 2; ++c) {
      const size_t ga = (size_t)(m0 + srow + c * 16) * K + k0 + skoff;
      const size_t gb = (size_t)(n0 + srow + c * 16) * K + k0 + skoff;
      const int ldso = (wid * 32 + c * 16) * 32;
      glds16(Ah + ga, &sAh[ldso]);
      glds16(Al + ga, &sAl[ldso]);
      glds16(Bh + gb, &sBh[ldso]);
      glds16(Bl + gb, &sBl[ldso]);
    }
    __syncthreads();

    bf16x8 ah[4], al[4], bh[4], bl[4];
    #pragma unroll
    for (int i = 0; i < 4; ++i) {
      const int ra = (wm * 64 + i * 16 + fr) * 32 + fq * 8;
      ah[i] = *(const bf16x8*)&sAh[ra];
      al[i] = *(const bf16x8*)&sAl[ra];
      const int rb = (wn * 64 + i * 16 + fr) * 32 + fq * 8;
      bh[i] = *(const bf16x8*)&sBh[rb];
      bl[i] = *(const bf16x8*)&sBl[rb];
    }
    #pragma unroll
    for (int i = 0; i < 4; ++i)
      #pragma unroll
      for (int j = 0; j < 4; ++j) {
        acc[i][j] = __builtin_amdgcn_mfma_f32_16x16x32_bf16(ah[i], bh[j], acc[i][j], 0, 0, 0);
        acc[i][j] = __builtin_amdgcn_mfma_f32_16x16x32_bf16(al[i], bh[j], acc[i][j], 0, 0, 0);
        acc[i][j] = __builtin_amdgcn_mfma_f32_16x16x32_bf16(ah[i], bl[j], acc[i][j], 0, 0, 0);
      }
  }

  float bcol[4];
  #pragma unroll
  for (int j = 0; j < 4; ++j) bcol[j] = bias[n0 + wn * 64 + j * 16 + fr];

  #pragma unroll
  for (int i = 0; i < 4; ++i) {
    #pragma unroll
    for (int r = 0; r < 4; ++r) {
      const int row = m0 + wm * 64 + i * 16 + fq * 4 + r;
      const size_t ro = (size_t)row * N;
      #pragma unroll
      for (int j = 0; j < 4; ++j) {
        const int col = n0 + wn * 64 + j * 16 + fr;
        float v = acc[i][j][r] + bcol[j];
        if (EPI == 1) {
          Cf[ro + col] = gelu_f(v);
        } else if (EPI == 2) {
          Cf[ro + col] = v + ResF[ro + col];
        } else if (EPI == 4) {
          Cf[ro + col] = v + f32_of(ResH[ro + col]) + f32_of(ResL[ro + col]);
        } else {
          Cf[ro + col] = v;
        }
      }
    }
  }
}

// ---------------------------------------------------------------------------
// NEW: 256x256 8-phase split-bf16 GEMM (T3+T4 counted vmcnt, T2 swizzle, T5).
// BK=32, 512 thr (8 waves 2x4), per-wave 128x64 out, 4 phases/K-tile,
// 128 KB LDS double-buffered, prefetch spread phases 0-2, vmcnt(4) counted.
// EPI: 10 = QKV routing (Q/K -> hl rows, V -> transposed)
//      11 = bias+gelu -> hl
//      12 = raw f32 partial (split-K plane at blockIdx.z)
// ---------------------------------------------------------------------------
template<int EPI>
__global__ __launch_bounds__(512, 2)
void gemm256(const us* __restrict__ Ah, const us* __restrict__ Al,
             const us* __restrict__ Bh, const us* __restrict__ Bl,
             const float* __restrict__ bias,
             float* __restrict__ Cf, us* __restrict__ Ch, us* __restrict__ Cl,
             us* __restrict__ Kh2, us* __restrict__ Kl2,
             us* __restrict__ Vh2, us* __restrict__ Vl2,
             int M, int N, int Kfull, int klen) {
  __shared__ us sm[2][4][256 * 32];   // [buf][Ah,Al,Bh,Bl][row*32+col] 128 KB

  const int t = threadIdx.x;
  const int lane = t & 63, wid = t >> 6;
  const int wm = wid >> 2, wn = wid & 3;
  const int fr = lane & 15, fq = lane >> 4;
  const int rsw = (fq ^ (fr & 3)) * 8;          // swizzled k-chunk (read side)

  const int nx = N >> 8;
  const int idl = blockIdx.x + blockIdx.y * nx; // within z-plane
  const int xcd = idl & 7, jj = idl >> 3;
  const int band = (M >> 8) >> 3;               // rows per XCD band (M=4096 -> 2)
  const int m0 = (xcd * band + (jj % band)) << 8;
  const int n0 = (jj / band) << 8;
  const int koff = blockIdx.z * klen;

  // stage coords: per stream, thread covers chunks p*512+t (p=0,1)
  const int clog = (t & 3) ^ ((t >> 2) & 3);    // inverse-swizzled source chunk

  auto stage2 = [&](int bf, int kt, int s, const us* gp, int rbase) {
    #pragma unroll
    for (int p = 0; p < 2; ++p) {
      const int row = p * 128 + (t >> 2);
      const size_t g = (size_t)(rbase + row) * Kfull + koff + kt * 32 + clog * 8;
      glds16(gp + g, &sm[bf][s][(p * 512 + t) * 8]);
    }
  };

  f32x4 acc[8][4];
  #pragma unroll
  for (int i = 0; i < 8; ++i)
    #pragma unroll
    for (int n = 0; n < 4; ++n) acc[i][n] = (f32x4){0.f, 0.f, 0.f, 0.f};

  // prologue: stage tile 0 (8 loads/thread)
  stage2(0, 0, 0, Ah, m0); stage2(0, 0, 1, Al, m0);
  stage2(0, 0, 2, Bh, n0); stage2(0, 0, 3, Bl, n0);

  const int ng = klen >> 5;
  bf16x8 bhf[4], blf[4];

#define PH_MFMA(qq)                                                              \
  {                                                                              \
    bf16x8 a0h = *(const bf16x8*)&sm[cur][0][(wm * 128 + (2*qq) * 16 + fr) * 32 + rsw];   \
    bf16x8 a0l = *(const bf16x8*)&sm[cur][1][(wm * 128 + (2*qq) * 16 + fr) * 32 + rsw];   \
    bf16x8 a1h = *(const bf16x8*)&sm[cur][0][(wm * 128 + (2*qq+1) * 16 + fr) * 32 + rsw]; \
    bf16x8 a1l = *(const bf16x8*)&sm[cur][1][(wm * 128 + (2*qq+1) * 16 + fr) * 32 + rsw]; \
    asm volatile("s_waitcnt lgkmcnt(0)" ::: "memory");                           \
    __builtin_amdgcn_sched_barrier(0);                                           \
    __builtin_amdgcn_s_setprio(1);                                               \
    _Pragma("unroll")                                                            \
    for (int n = 0; n < 4; ++n) {                                                \
      acc[2*qq][n]   = __builtin_amdgcn_mfma_f32_16x16x32_bf16(a0h, bhf[n], acc[2*qq][n], 0,0,0);   \
      acc[2*qq][n]   = __builtin_amdgcn_mfma_f32_16x16x32_bf16(a0l, bhf[n], acc[2*qq][n], 0,0,0);   \
      acc[2*qq][n]   = __builtin_amdgcn_mfma_f32_16x16x32_bf16(a0h, blf[n], acc[2*qq][n], 0,0,0);   \
      acc[2*qq+1][n] = __builtin_amdgcn_mfma_f32_16x16x32_bf16(a1h, bhf[n], acc[2*qq+1][n], 0,0,0); \
      acc[2*qq+1][n] = __builtin_amdgcn_mfma_f32_16x16x32_bf16(a1l, bhf[n], acc[2*qq+1][n], 0,0,0); \
      acc[2*qq+1][n] = __builtin_amdgcn_mfma_f32_16x16x32_bf16(a1h, blf[n], acc[2*qq+1][n], 0,0,0); \
    }                                                                            \
    __builtin_amdgcn_s_setprio(0);                                               \
    __builtin_amdgcn_s_barrier();                                                \
  }

  for (int g = 0; g < ng; ++g) {
    const int cur = g & 1, nxt = cur ^ 1;
    const bool pf = (g + 1 < ng);
    // ---- phase 0: prefetch A(next), counted wait, barrier, B frags, MFMA m0,m1
    if (pf) {
      stage2(nxt, g + 1, 0, Ah, m0);
      stage2(nxt, g + 1, 1, Al, m0);
      asm volatile("s_waitcnt vmcnt(4)" ::: "memory");
    } else {
      asm volatile("s_waitcnt vmcnt(0)" ::: "memory");
    }
    __builtin_amdgcn_sched_barrier(0);
    __builtin_amdgcn_s_barrier();
    __builtin_amdgcn_sched_barrier(0);
    #pragma unroll
    for (int n = 0; n < 4; ++n) {
      const int rb = (wn * 64 + n * 16 + fr) * 32 + rsw;
      bhf[n] = *(const bf16x8*)&sm[cur][2][rb];
      blf[n] = *(const bf16x8*)&sm[cur][3][rb];
    }
    PH_MFMA(0)
    // ---- phase 1
    if (pf) stage2(nxt, g + 1, 2, Bh, n0);
    PH_MFMA(1)
    // ---- phase 2
    if (pf) stage2(nxt, g + 1, 3, Bl, n0);
    PH_MFMA(2)
    // ---- phase 3
    PH_MFMA(3)
  }
#undef PH_MFMA

  // ---- epilogue ----
  if (EPI == 12) {
    const size_t zoff = (size_t)blockIdx.z * M * N;
    #pragma unroll
    for (int i = 0; i < 8; ++i) {
      #pragma unroll
      for (int r = 0; r < 4; ++r) {
        const int row = m0 + wm * 128 + i * 16 + fq * 4 + r;
        const size_t ro = zoff + (size_t)row * N;
        #pragma unroll
        for (int n = 0; n < 4; ++n) {
          const int col = n0 + wn * 64 + n * 16 + fr;
          Cf[ro + col] = acc[i][n][r];
        }
      }
    }
    return;
  }

  float bcol[4];
  #pragma unroll
  for (int n = 0; n < 4; ++n) bcol[n] = bias[n0 + wn * 64 + n * 16 + fr];

  if (EPI == 11) {
    #pragma unroll
    for (int i = 0; i < 8; ++i) {
      #pragma unroll
      for (int r = 0; r < 4; ++r) {
        const int row = m0 + wm * 128 + i * 16 + fq * 4 + r;
        const size_t ro = (size_t)row * N;
        #pragma unroll
        for (int n = 0; n < 4; ++n) {
          const int col = n0 + wn * 64 + n * 16 + fr;
          float v = gelu_f(acc[i][n][r] + bcol[n]);
          us h, l; split_hl(v, h, l);
          Ch[ro + col] = h; Cl[ro + col] = l;
        }
      }
    }
    return;
  }

  // EPI == 10: QKV routing.  sel uniform per block (256-col tile in one 1024 group)
  {
    const int sel = n0 >> 10;
    if (sel < 2) {
      us* dh = (sel == 0) ? Ch : Kh2;
      us* dl = (sel == 0) ? Cl : Kl2;
      #pragma unroll
      for (int i = 0; i < 8; ++i) {
        #pragma unroll
        for (int r = 0; r < 4; ++r) {
          const int row = m0 + wm * 128 + i * 16 + fq * 4 + r;
          const size_t ro = (size_t)row * 1024;
          #pragma unroll
          for (int n = 0; n < 4; ++n) {
            const int c10 = (n0 & 1023) + wn * 64 + n * 16 + fr;
            float v = acc[i][n][r] + bcol[n];
            us h, l; split_hl(v, h, l);
            dh[ro + c10] = h; dl[ro + c10] = l;
          }
        }
      }
    } else {
      #pragma unroll
      for (int i = 0; i < 8; ++i) {
        #pragma unroll
        for (int n = 0; n < 4; ++n) {
          const int c10 = (n0 & 1023) + wn * 64 + n * 16 + fr;
          const int hh2 = c10 >> 6, dh = c10 & 63;
          const int row0 = m0 + wm * 128 + i * 16 + fq * 4;
          const int bb = row0 >> 10, ltok = row0 & 1023;
          ushort4 h4, l4;
          float v0 = acc[i][n][0] + bcol[n];
          float v1 = acc[i][n][1] + bcol[n];
          float v2 = acc[i][n][2] + bcol[n];
          float v3 = acc[i][n][3] + bcol[n];
          split_hl(v0, h4.x, l4.x); split_hl(v1, h4.y, l4.y);
          split_hl(v2, h4.z, l4.z); split_hl(v3, h4.w, l4.w);
          const size_t off = ((size_t)(bb * 16 + hh2) * 64 + dh) * L_ + ltok;
          *(ushort4*)&Vh2[off] = h4;
          *(ushort4*)&Vl2[off] = l4;
        }
      }
    }
  }
}

// ---------------------------------------------------------------------------
// MFMA flash attention (unchanged from round 3, verified)
// ---------------------------------------------------------------------------
__global__ __launch_bounds__(256, 3)
void attn_mfma(const us* __restrict__ Qh, const us* __restrict__ Ql,
               const us* __restrict__ Kh, const us* __restrict__ Kl,
               const us* __restrict__ Vth, const us* __restrict__ Vtl,
               us* __restrict__ Oh, us* __restrict__ Ol) {
  const int raw = blockIdx.x + blockIdx.y * 16;
  const int hh = (raw & 7) + 8 * ((raw >> 3) >> 4);
  const int qq = (raw >> 3) & 15;
  const int b = hh >> 4, h = hh & 15;

  const int t = threadIdx.x;
  const int w = t >> 6, lane = t & 63;
  const int fr = lane & 15, g = lane >> 4;

  __shared__ __align__(16) unsigned char smem[51200];
  us* sKh = (us*)(smem);
  us* sKl = (us*)(smem + 8192);
  us* sVh = (us*)(smem + 16384);
  us* sVl = (us*)(smem + 24576);
  us* sPh = (us*)(smem + 32768);
  us* sPl = (us*)(smem + 41984);
  float* fb = (float*)smem;

  const int tok0 = b * L_ + qq * 64 + w * 16;
  bf16x8 qfh[2], qfl[2];
  #pragma unroll
  for (int ks = 0; ks < 2; ++ks) {
    const size_t qo = (size_t)(tok0 + fr) * D_ + h * 64 + ks * 32 + g * 8;
    qfh[ks] = *(const bf16x8*)&Qh[qo];
    qfl[ks] = *(const bf16x8*)&Ql[qo];
  }

  float m = -INFINITY, l = 0.0f;
  f32x4 ctx[4];
  #pragma unroll
  for (int i = 0; i < 4; ++i) ctx[i] = (f32x4){0.f, 0.f, 0.f, 0.f};

  for (int kt = 0; kt < 16; ++kt) {
    const int k0 = kt * 64;
    __syncthreads();
    #pragma unroll
    for (int p = 0; p < 2; ++p) {
      const int ci = w * 128 + p * 64 + lane;
      const int dbase = (w * 128 + p * 64) * 8;
      {
        const int ks = ci >> 8, rem = ci & 255, key = rem >> 2, sub = rem & 3;
        const size_t src = (size_t)(b * L_ + k0 + key) * D_ + h * 64 + ks * 32 + sub * 8;
        glds16(Kh + src, sKh + dbase);
        glds16(Kl + src, sKl + dbase);
      }
      {
        const int d = ci >> 3, c = ci & 7;
        const size_t src = (size_t)(hh * 64 + d) * L_ + k0 + ((c ^ (d & 7)) * 8);
        glds16(Vth + src, sVh + dbase);
        glds16(Vtl + src, sVl + dbase);
      }
    }
    __syncthreads();

    f32x4 accS[4];
    #pragma unroll
    for (int i = 0; i < 4; ++i) accS[i] = (f32x4){0.f, 0.f, 0.f, 0.f};
    #pragma unroll
    for (int ks = 0; ks < 2; ++ks) {
      #pragma unroll
      for (int i = 0; i < 4; ++i) {
        const int ra = (ks * 64 + i * 16 + fr) * 32 + g * 8;
        bf16x8 ah = *(const bf16x8*)&sKh[ra];
        bf16x8 al = *(const bf16x8*)&sKl[ra];
        accS[i] = __builtin_amdgcn_mfma_f32_16x16x32_bf16(ah, qfh[ks], accS[i], 0, 0, 0);
        accS[i] = __builtin_amdgcn_mfma_f32_16x16x32_bf16(al, qfh[ks], accS[i], 0, 0, 0);
        accS[i] = __builtin_amdgcn_mfma_f32_16x16x32_bf16(ah, qfl[ks], accS[i], 0, 0, 0);
      }
    }

    float sv[4][4];
    float mloc = -INFINITY;
    #pragma unroll
    for (int i = 0; i < 4; ++i)
      #pragma unroll
      for (int r = 0; r < 4; ++r) {
        sv[i][r] = accS[i][r] * 0.125f;
        mloc = fmaxf(mloc, sv[i][r]);
      }
    mloc = fmaxf(mloc, __shfl_xor(mloc, 16));
    mloc = fmaxf(mloc, __shfl_xor(mloc, 32));
    const float mnew = fmaxf(m, mloc);
    const float alpha = expf(m - mnew);
    float p[4][4];
    float lt = 0.f;
    #pragma unroll
    for (int i = 0; i < 4; ++i)
      #pragma unroll
      for (int r = 0; r < 4; ++r) {
        p[i][r] = expf(sv[i][r] - mnew);
        lt += p[i][r];
      }
    lt += __shfl_xor(lt, 16);
    lt += __shfl_xor(lt, 32);
    l = l * alpha + lt;
    m = mnew;
    #pragma unroll
    for (int i = 0; i < 4; ++i) {
      ctx[i][0] *= alpha; ctx[i][1] *= alpha;
      ctx[i][2] *= alpha; ctx[i][3] *= alpha;
    }

    #pragma unroll
    for (int i = 0; i < 4; ++i) {
      us h0 = bf16_of(p[i][0]), h1 = bf16_of(p[i][1]);
      us h2 = bf16_of(p[i][2]), h3 = bf16_of(p[i][3]);
      uint2 hv = {(uint32_t)h0 | ((uint32_t)h1 << 16),
                  (uint32_t)h2 | ((uint32_t)h3 << 16)};
      us l0 = bf16_of(p[i][0] - f32_of(h0)), l1 = bf16_of(p[i][1] - f32_of(h1));
      us l2 = bf16_of(p[i][2] - f32_of(h2)), l3 = bf16_of(p[i][3] - f32_of(h3));
      uint2 lv = {(uint32_t)l0 | ((uint32_t)l1 << 16),
                  (uint32_t)l2 | ((uint32_t)l3 << 16)};
      const int po = (w * 16 + fr) * 72 + i * 16 + g * 4;
      *(uint2*)&sPh[po] = hv;
      *(uint2*)&sPl[po] = lv;
    }

    #pragma unroll
    for (int ks = 0; ks < 2; ++ks) {
      const int pb = (w * 16 + fr) * 72 + ks * 32 + g * 8;
      bf16x8 pah = *(const bf16x8*)&sPh[pb];
      bf16x8 pal = *(const bf16x8*)&sPl[pb];
      #pragma unroll
      for (int i = 0; i < 4; ++i) {
        const int d = i * 16 + fr;
        const int pc = (ks * 4 + g) ^ (d & 7);
        bf16x8 vh = *(const bf16x8*)&sVh[d * 64 + pc * 8];
        bf16x8 vl = *(const bf16x8*)&sVl[d * 64 + pc * 8];
        ctx[i] = __builtin_amdgcn_mfma_f32_16x16x32_bf16(vh, pah, ctx[i], 0, 0, 0);
        ctx[i] = __builtin_amdgcn_mfma_f32_16x16x32_bf16(vl, pah, ctx[i], 0, 0, 0);
        ctx[i] = __builtin_amdgcn_mfma_f32_16x16x32_bf16(vh, pal, ctx[i], 0, 0, 0);
      }
    }
  }

  const float invl = 1.0f / l;
  __syncthreads();
  #pragma unroll
  for (int i = 0; i < 4; ++i)
    #pragma unroll
    for (int r = 0; r < 4; ++r)
      fb[(i * 16 + g * 4 + r) * 64 + w * 16 + fr] = ctx[i][r] * invl;
  __syncthreads();

  {
    const int q = t >> 2, dg = t & 3;
    const size_t ob = (size_t)(b * L_ + qq * 64 + q) * D_ + h * 64;
    #pragma unroll
    for (int u = 0; u < 4; ++u) {
      const int d0 = dg * 16 + u * 4;
      ushort4 h4, l4;
      float v0 = fb[(d0 + 0) * 64 + q];
      float v1 = fb[(d0 + 1) * 64 + q];
      float v2 = fb[(d0 + 2) * 64 + q];
      float v3 = fb[(d0 + 3) * 64 + q];
      split_hl(v0, h4.x, l4.x); split_hl(v1, h4.y, l4.y);
      split_hl(v2, h4.z, l4.z); split_hl(v3, h4.w, l4.w);
      *(ushort4*)&Oh[ob + d0] = h4;
      *(ushort4*)&Ol[ob + d0] = l4;
    }
  }
}

// ---------------------------------------------------------------------------
// LayerNorm over D=1024.  MODE 0: fp32 out; MODE 1: bf16 hi/lo out.
// ---------------------------------------------------------------------------
template<int MODE>
__global__ __launch_bounds__(256)
void layernorm_k(const float* __restrict__ X, const float* __restrict__ g,
                 const float* __restrict__ b, float* __restrict__ Yf,
                 us* __restrict__ Yh, us* __restrict__ Yl) {
  const int row = blockIdx.x;
  const int t = threadIdx.x;
  const float* x = X + (size_t)row * D_;

  float4 v = *(const float4*)&x[t * 4];
  float s  = v.x + v.y + v.z + v.w;
  float ss = v.x * v.x + v.y * v.y + v.z * v.z + v.w * v.w;

  #pragma unroll
  for (int off = 1; off < 64; off <<= 1) {
    s  += __shfl_xor(s, off);
    ss += __shfl_xor(ss, off);
  }
  __shared__ float red[4][2];
  const int wid = t >> 6;
  if ((t & 63) == 0) { red[wid][0] = s; red[wid][1] = ss; }
  __syncthreads();
  s  = red[0][0] + red[1][0] + red[2][0] + red[3][0];
  ss = red[0][1] + red[1][1] + red[2][1] + red[3][1];

  const float mean = s * (1.0f / D_);
  const float var  = ss * (1.0f / D_) - mean * mean;
  const float inv  = rsqrtf(var + 1e-5f);

  float4 gv = *(const float4*)&g[t * 4];
  float4 bv = *(const float4*)&b[t * 4];
  float4 o;
  o.x = (v.x - mean) * inv * gv.x + bv.x;
  o.y = (v.y - mean) * inv * gv.y + bv.y;
  o.z = (v.z - mean) * inv * gv.z + bv.z;
  o.w = (v.w - mean) * inv * gv.w + bv.w;
  if (MODE == 0) {
    *(float4*)&Yf[(size_t)row * D_ + t * 4] = o;
  } else {
    ushort4 h, l;
    split_hl(o.x, h.x, l.x); split_hl(o.y, h.y, l.y);
    split_hl(o.z, h.z, l.z); split_hl(o.w, h.w, l.w);
    *(ushort4*)&Yh[(size_t)row * D_ + t * 4] = h;
    *(ushort4*)&Yl[(size_t)row * D_ + t * 4] = l;
  }
}

// ---------------------------------------------------------------------------
// Split-K reduce (4 planes) + bias + residual(hl) + LayerNorm -> f32
// ---------------------------------------------------------------------------
__global__ __launch_bounds__(256)
void lnred4(const float* __restrict__ P, const float* __restrict__ b2,
            const us* __restrict__ Rh, const us* __restrict__ Rl,
            const float* __restrict__ g, const float* __restrict__ be,
            float* __restrict__ Y) {
  const int row = blockIdx.x;
  const int t = threadIdx.x;
  const size_t PL = (size_t)NTOK * D_;
  const size_t o = (size_t)row * D_ + t * 4;

  float4 v0 = *(const float4*)&P[o];
  float4 v1 = *(const float4*)&P[o + PL];
  float4 v2 = *(const float4*)&P[o + 2 * PL];
  float4 v3 = *(const float4*)&P[o + 3 * PL];
  float4 bb = *(const float4*)&b2[t * 4];
  ushort4 rh = *(const ushort4*)&Rh[o];
  ushort4 rl = *(const ushort4*)&Rl[o];
  float4 v;
  v.x = v0.x + v1.x + v2.x + v3.x + bb.x + f32_of(rh.x) + f32_of(rl.x);
  v.y = v0.y + v1.y + v2.y + v3.y + bb.y + f32_of(rh.y) + f32_of(rl.y);
  v.z = v0.z + v1.z + v2.z + v3.z + bb.z + f32_of(rh.z) + f32_of(rl.z);
  v.w = v0.w + v1.w + v2.w + v3.w + bb.w + f32_of(rh.w) + f32_of(rl.w);

  float s  = v.x + v.y + v.z + v.w;
  float ss = v.x * v.x + v.y * v.y + v.z * v.z + v.w * v.w;
  #pragma unroll
  for (int off = 1; off < 64; off <<= 1) {
    s  += __shfl_xor(s, off);
    ss += __shfl_xor(ss, off);
  }
  __shared__ float red[4][2];
  const int wid = t >> 6;
  if ((t & 63) == 0) { red[wid][0] = s; red[wid][1] = ss; }
  __syncthreads();
  s  = red[0][0] + red[1][0] + red[2][0] + red[3][0];
  ss = red[0][1] + red[1][1] + red[2][1] + red[3][1];

  const float mean = s * (1.0f / D_);
  const float var  = ss * (1.0f / D_) - mean * mean;
  const float inv  = rsqrtf(var + 1e-5f);

  float4 gv = *(const float4*)&g[t * 4];
  float4 bv = *(const float4*)&be[t * 4];
  float4 y;
  y.x = (v.x - mean) * inv * gv.x + bv.x;
  y.y = (v.y - mean) * inv * gv.y + bv.y;
  y.z = (v.z - mean) * inv * gv.z + bv.z;
  y.w = (v.w - mean) * inv * gv.w + bv.w;
  *(float4*)&Y[o] = y;
}

// ---------------------------------------------------------------------------
// Fused adapter: gate + top-2 + softmax + 2-expert R->D + residual combine.
// W2 in bf16 (hi only): error ~1e-4 on an O(0.1) term, negligible.
// ---------------------------------------------------------------------------
__global__ __launch_bounds__(256)
void adapter_combine_hl(const us* __restrict__ Xh, const us* __restrict__ Xl,
                        const float* __restrict__ Hall,
                        const float* __restrict__ Lout,
                        const us* __restrict__ W2b,
                        const float* __restrict__ B2,
                        const float* __restrict__ GW,
                        const float* __restrict__ GB,
                        float* __restrict__ Out) {
  const int tok = blockIdx.x;
  const int t = threadIdx.x;

  __shared__ float xs[D_];
  __shared__ float part[256];
  __shared__ float logit_s[E_];
  __shared__ float hs[2 * R_];
  __shared__ int   e_sh[2];
  __shared__ float g_sh[2];

  {
    ushort4 h = *(const ushort4*)&Xh[(size_t)tok * D_ + t * 4];
    ushort4 l = *(const ushort4*)&Xl[(size_t)tok * D_ + t * 4];
    xs[t * 4 + 0] = f32_of(h.x) + f32_of(l.x);
    xs[t * 4 + 1] = f32_of(h.y) + f32_of(l.y);
    xs[t * 4 + 2] = f32_of(h.z) + f32_of(l.z);
    xs[t * 4 + 3] = f32_of(h.w) + f32_of(l.w);
  }
  __syncthreads();

  {
    const int e = t & 7, seg = t >> 3;
    float p = 0.f;
    #pragma unroll 8
    for (int i = 0; i < 32; ++i) {
      const int d = seg * 32 + i;
      p = fmaf(xs[d], GW[d * E_ + e], p);
    }
    part[t] = p;
  }
  __syncthreads();
  if (t < E_) {
    float s = GB[t];
    for (int sg = 0; sg < 32; ++sg) s += part[sg * 8 + t];
    logit_s[t] = s;
  }
  __syncthreads();
  if (t == 0) {
    int e1 = 0; float v1 = logit_s[0];
    for (int i = 1; i < E_; ++i) if (logit_s[i] > v1) { v1 = logit_s[i]; e1 = i; }
    int e2 = -1; float v2 = -INFINITY;
    for (int i = 0; i < E_; ++i) if (i != e1 && logit_s[i] > v2) { v2 = logit_s[i]; e2 = i; }
    const float ee = expf(v2 - v1);
    const float den = 1.0f + ee;
    g_sh[0] = 1.0f / den; g_sh[1] = ee / den;
    e_sh[0] = e1; e_sh[1] = e2;
  }
  __syncthreads();
  const int e1 = e_sh[0], e2 = e_sh[1];
  const float g1 = g_sh[0], g2 = g_sh[1];

  if (t < 2 * R_) {
    const int ex = (t < R_) ? e1 : e2;
    const int r = t & (R_ - 1);
    hs[t] = Hall[(size_t)tok * (E_ * R_) + ex * R_ + r];
  }
  __syncthreads();

  const int d = t * 4;
  float4 b1v = *(const float4*)&B2[e1 * D_ + d];
  float4 b2v = *(const float4*)&B2[e2 * D_ + d];
  float4 acc;
  acc.x = g1 * b1v.x + g2 * b2v.x;
  acc.y = g1 * b1v.y + g2 * b2v.y;
  acc.z = g1 * b1v.z + g2 * b2v.z;
  acc.w = g1 * b1v.w + g2 * b2v.w;

  #pragma unroll 8
  for (int r = 0; r < R_; ++r) {
    const float f = g1 * hs[r];
    ushort4 w = *(const ushort4*)&W2b[((size_t)e1 * R_ + r) * D_ + d];
    acc.x = fmaf(f, f32_of(w.x), acc.x); acc.y = fmaf(f, f32_of(w.y), acc.y);
    acc.z = fmaf(f, f32_of(w.z), acc.z); acc.w = fmaf(f, f32_of(w.w), acc.w);
  }
  #pragma unroll 8
  for (int r = 0; r < R_; ++r) {
    const float f = g2 * hs[R_ + r];
    ushort4 w = *(const ushort4*)&W2b[((size_t)e2 * R_ + r) * D_ + d];
    acc.x = fmaf(f, f32_of(w.x), acc.x); acc.y = fmaf(f, f32_of(w.y), acc.y);
    acc.z = fmaf(f, f32_of(w.z), acc.z); acc.w = fmaf(f, f32_of(w.w), acc.w);
  }

  float4 lo = *(const float4*)&Lout[(size_t)tok * D_ + d];
  float4 o = {lo.x + 2.0f * acc.x, lo.y + 2.0f * acc.y,
              lo.z + 2.0f * acc.z, lo.w + 2.0f * acc.w};
  *(float4*)&Out[(size_t)tok * D_ + d] = o;
}

// ---------------------------------------------------------------------------
extern "C" void kernel_launch(void* const* d_in, const int* in_sizes, int n_in,
                              void* d_out, int out_size, void* d_ws, size_t ws_size,
                              hipStream_t stream) {
  const float* x     = (const float*)d_in[0];
  const float* wq    = (const float*)d_in[1];
  const float* wk    = (const float*)d_in[2];
  const float* wv    = (const float*)d_in[3];
  const float* wo    = (const float*)d_in[4];
  const float* bq    = (const float*)d_in[5];
  const float* bk    = (const float*)d_in[6];
  const float* bv    = (const float*)d_in[7];
  const float* bo    = (const float*)d_in[8];
  const float* ln1g  = (const float*)d_in[9];
  const float* ln1b  = (const float*)d_in[10];
  const float* w1    = (const float*)d_in[11];
  const float* b1    = (const float*)d_in[12];
  const float* w2    = (const float*)d_in[13];
  const float* b2    = (const float*)d_in[14];
  const float* ln2g  = (const float*)d_in[15];
  const float* ln2b  = (const float*)d_in[16];
  const float* aw1   = (const float*)d_in[17];
  const float* ab1   = (const float*)d_in[18];
  const float* aw2   = (const float*)d_in[19];
  const float* ab2   = (const float*)d_in[20];
  const float* gw    = (const float*)d_in[21];
  const float* gb    = (const float*)d_in[22];
  float* out = (float*)d_out;

  char* base = (char*)d_ws;
  const size_t MB = 1ull << 20;
  const bool big = ws_size >= 244 * MB;

  // weights (persistent)
  us* qkvTh = (us*)(base + 0 * MB);  us* qkvTl = (us*)(base + 6 * MB);   // [3072][1024]
  us* woTh  = (us*)(base + 12 * MB); us* woTl  = (us*)(base + 14 * MB);
  us* w1Th  = (us*)(base + 16 * MB); us* w1Tl  = (us*)(base + 24 * MB);
  us* w2Th  = (us*)(base + 32 * MB); us* w2Tl  = (us*)(base + 40 * MB);
  us* a1Th  = (us*)(base + 48 * MB); us* a1Tl  = (us*)(base + 49 * MB);
  us* w2b   = (us*)(base + 50 * MB);
  float* bqkv = (float*)(base + 51 * MB);
  // activations
  us* xh   = (us*)(base + 52 * MB);  us* xl   = (us*)(base + 60 * MB);
  us* ctxh = xh;                     us* ctxl = xl;
  us* qbh  = (us*)(base + 68 * MB);  us* qbl  = (us*)(base + 76 * MB);
  float* ATTNPRE = (float*)(base + 68 * MB);
  us* kbh  = (us*)(base + 84 * MB);  us* kbl  = (us*)(base + 92 * MB);
  us* aoh  = (us*)(base + 84 * MB);  us* aol  = (us*)(base + 92 * MB);
  us* vth  = (us*)(base + 100 * MB); us* vtl  = (us*)(base + 108 * MB);
  us* inth = (us*)(base + 116 * MB); us* intl = (us*)(base + 148 * MB);
  // big path: split-K planes @180 (64 MB), LOUT @52, HALL @68
  float* PK    = (float*)(base + 180 * MB);
  float* LOUT  = big ? (float*)(base + 52 * MB) : (float*)(base + 68 * MB);
  float* HALL  = big ? (float*)(base + 68 * MB) : (float*)(base + 100 * MB);
  float* FFNPRE = (float*)(base + 52 * MB);   // small path only

  const dim3 blk(256);
  const us* nu = nullptr;
  const float* nf = nullptr;

  // --- precompute splits ---
  fsplit<<<dim3(NTOK * D_ / 1024), blk, 0, stream>>>(x, xh, xl, NTOK * D_ / 4);
  wsplit_t<<<dim3(16, 16), blk, 0, stream>>>(wq, qkvTh, qkvTl, D_, D_);
  wsplit_t<<<dim3(16, 16), blk, 0, stream>>>(wk, qkvTh + 1024 * 1024, qkvTl + 1024 * 1024, D_, D_);
  wsplit_t<<<dim3(16, 16), blk, 0, stream>>>(wv, qkvTh + 2048 * 1024, qkvTl + 2048 * 1024, D_, D_);
  wsplit_t<<<dim3(16, 16), blk, 0, stream>>>(wo, woTh, woTl, D_, D_);
  wsplit_t<<<dim3(64, 16), blk, 0, stream>>>(w1, w1Th, w1Tl, D_, FF_);
  wsplit_t<<<dim3(16, 64), blk, 0, stream>>>(w2, w2Th, w2Tl, FF_, D_);
  wsplit_t<<<dim3(8, 16),  blk, 0, stream>>>(aw1, a1Th, a1Tl, D_, E_ * R_);
  fhi<<<dim3(E_ * R_ * D_ / 1024), blk, 0, stream>>>(aw2, w2b, E_ * R_ * D_ / 4);
  bconcat<<<dim3(12), blk, 0, stream>>>(bq, bk, bv, bqkv);

  // --- fused QKV projection (8-phase 256^2), routing epilogue ---
  gemm256<10><<<dim3(12, 16), dim3(512), 0, stream>>>(
      xh, xl, qkvTh, qkvTl, bqkv, nullptr, qbh, qbl, kbh, kbl, vth, vtl,
      NTOK, 3072, D_, D_);
  // --- attention ---
  attn_mfma<<<dim3(16, 64), blk, 0, stream>>>(qbh, qbl, kbh, kbl, vth, vtl, ctxh, ctxl);
  // --- output projection + residual(x), LN1 -> AO hi/lo ---
  gemm_mfma<2><<<dim3(8, 32), blk, 0, stream>>>(ctxh, ctxl, woTh, woTl, bo, x, nu, nu,
                                                ATTNPRE, nullptr, nullptr, NTOK, D_, D_);
  layernorm_k<1><<<dim3(NTOK), blk, 0, stream>>>(ATTNPRE, ln1g, ln1b, nullptr, aoh, aol);
  // --- FFN1 (8-phase 256^2, gelu -> hl) ---
  gemm256<11><<<dim3(16, 16), dim3(512), 0, stream>>>(
      aoh, aol, w1Th, w1Tl, b1, nullptr, inth, intl, nullptr, nullptr, nullptr, nullptr,
      NTOK, FF_, D_, D_);
  // --- FFN2 ---
  if (big) {
    gemm256<12><<<dim3(4, 16, 4), dim3(512), 0, stream>>>(
        inth, intl, w2Th, w2Tl, nf, PK, nullptr, nullptr, nullptr, nullptr, nullptr, nullptr,
        NTOK, D_, FF_, 1024);
    lnred4<<<dim3(NTOK), blk, 0, stream>>>(PK, b2, aoh, aol, ln2g, ln2b, LOUT);
  } else {
    gemm_mfma<4><<<dim3(8, 32), blk, 0, stream>>>(inth, intl, w2Th, w2Tl, b2, nf, aoh, aol,
                                                  FFNPRE, nullptr, nullptr, NTOK, D_, FF_);
    layernorm_k<0><<<dim3(NTOK), blk, 0, stream>>>(FFNPRE, ln2g, ln2b, LOUT, nullptr, nullptr);
  }
  // --- adapter ---
  gemm_mfma<1><<<dim3(4, 32), blk, 0, stream>>>(aoh, aol, a1Th, a1Tl, ab1, nf, nu, nu,
                                                HALL, nullptr, nullptr, NTOK, E_ * R_, D_);
  adapter_combine_hl<<<dim3(NTOK), blk, 0, stream>>>(aoh, aol, HALL, LOUT, w2b, ab2, gw, gb, out);
}

// Round 5
// 635.161 us; speedup vs baseline: 3.5134x; 1.3431x over previous
//
#include <hip/hip_runtime.h>
#include <cstddef>
#include <cstdint>

#define B_   4
#define L_   1024
#define D_   1024
#define H_   16
#define DH_  64
#define E_   8
#define R_   64
#define FF_  4096
#define NTOK (B_ * L_)   // 4096

typedef __attribute__((ext_vector_type(8))) short bf16x8;
typedef __attribute__((ext_vector_type(4))) float f32x4;
typedef unsigned short us;

__device__ __forceinline__ float gelu_f(float x) {
  return 0.5f * x * (1.0f + erff(x * 0.7071067811865476f));
}

__device__ __forceinline__ us bf16_of(float f) {
  union { float f; uint32_t u; } x; x.f = f;
  uint32_t r = x.u + 0x7FFFu + ((x.u >> 16) & 1u);   // RNE
  return (us)(r >> 16);
}
__device__ __forceinline__ float f32_of(us h) {
  union { uint32_t u; float f; } x; x.u = ((uint32_t)h) << 16;
  return x.f;
}
__device__ __forceinline__ void split_hl(float v, us& hi, us& lo) {
  hi = bf16_of(v);
  lo = bf16_of(v - f32_of(hi));
}

__device__ __forceinline__ void glds16(const void* g, const void* l) {
  __builtin_amdgcn_global_load_lds(
      (const __attribute__((address_space(1))) unsigned int*)g,
      (__attribute__((address_space(3))) unsigned int*)l, 16, 0, 0);
}

// ---------------------------------------------------------------------------
// fp32 -> bf16 (hi only)
// ---------------------------------------------------------------------------
__global__ __launch_bounds__(256)
void fhi(const float* __restrict__ X, us* __restrict__ Hh, int n4) {
  int i = blockIdx.x * 256 + threadIdx.x;
  if (i >= n4) return;
  float4 v = ((const float4*)X)[i];
  ushort4 h = {bf16_of(v.x), bf16_of(v.y), bf16_of(v.z), bf16_of(v.w)};
  ((ushort4*)Hh)[i] = h;
}

// concat 3 x [1024] biases -> [3072]
__global__ __launch_bounds__(256)
void bconcat(const float* __restrict__ a, const float* __restrict__ b,
             const float* __restrict__ c, float* __restrict__ o) {
  int i = blockIdx.x * 256 + threadIdx.x;
  if (i >= 3072) return;
  o[i] = (i < 1024) ? a[i] : (i < 2048 ? b[i - 1024] : c[i - 2048]);
}

// ---------------------------------------------------------------------------
// Weight split+transpose: W[K,N] fp32 -> Th,Tl [N,K] bf16.
// ---------------------------------------------------------------------------
__global__ __launch_bounds__(256)
void wsplit_t(const float* __restrict__ W, us* __restrict__ Th,
              us* __restrict__ Tl, int K, int N) {
  __shared__ float tile[64][65];
  const int k0 = blockIdx.y * 64, n0 = blockIdx.x * 64;
  const int t = threadIdx.x;
  const int r = t >> 4, c4 = (t & 15) * 4;
  #pragma unroll
  for (int p = 0; p < 4; ++p) {
    const int k = r + p * 16;
    *(float4*)&tile[k][c4] = *(const float4*)&W[(size_t)(k0 + k) * N + n0 + c4];
  }
  __syncthreads();
  #pragma unroll
  for (int p = 0; p < 4; ++p) {
    const int n = r + p * 16;
    float v0 = tile[c4 + 0][n], v1 = tile[c4 + 1][n];
    float v2 = tile[c4 + 2][n], v3 = tile[c4 + 3][n];
    ushort4 h, l;
    split_hl(v0, h.x, l.x); split_hl(v1, h.y, l.y);
    split_hl(v2, h.z, l.z); split_hl(v3, h.w, l.w);
    const size_t o = (size_t)(n0 + n) * K + k0 + c4;
    *(ushort4*)&Th[o] = h;
    *(ushort4*)&Tl[o] = l;
  }
}

// ---------------------------------------------------------------------------
// OLD split-bf16 MFMA GEMM (3-term, verified) — kept for skinny GEMMs.
// EPI: 1 bias+gelu->f32 | 2 bias+resF->f32
// ---------------------------------------------------------------------------
template<int EPI>
__global__ __launch_bounds__(256, 2)
void gemm_mfma(const us* __restrict__ Ah, const us* __restrict__ Al,
               const us* __restrict__ Bh, const us* __restrict__ Bl,
               const float* __restrict__ bias,
               const float* __restrict__ ResF,
               float* __restrict__ Cf, int M, int N, int K) {
  __shared__ us sAh[128 * 32], sAl[128 * 32];
  __shared__ us sBh[128 * 32], sBl[128 * 32];

  const int t = threadIdx.x;
  const int lane = t & 63;
  const int wid = t >> 6;
  const int wm = wid >> 1, wn = wid & 1;

  const int nwgx = gridDim.x;
  const int nwg = nwgx * gridDim.y;
  const int idl = blockIdx.y * nwgx + blockIdx.x;
  const int swz = (idl & 7) * (nwg >> 3) + (idl >> 3);
  const int m0 = (swz / nwgx) * 128;
  const int n0 = (swz % nwgx) * 128;

  const int srow = wid * 32 + (lane >> 2);
  const int skoff = (lane & 3) * 8;

  f32x4 acc[4][4];
  #pragma unroll
  for (int i = 0; i < 4; ++i)
    #pragma unroll
    for (int j = 0; j < 4; ++j)
      acc[i][j] = (f32x4){0.f, 0.f, 0.f, 0.f};

  const int fr = lane & 15, fq = lane >> 4;

  for (int k0 = 0; k0 < K; k0 += 32) {
    __syncthreads();
    #pragma unroll
    for (int c = 0; c < 2; ++c) {
      const size_t ga = (size_t)(m0 + srow + c * 16) * K + k0 + skoff;
      const size_t gb = (size_t)(n0 + srow + c * 16) * K + k0 + skoff;
      const int ldso = (wid * 32 + c * 16) * 32;
      glds16(Ah + ga, &sAh[ldso]);
      glds16(Al + ga, &sAl[ldso]);
      glds16(Bh + gb, &sBh[ldso]);
      glds16(Bl + gb, &sBl[ldso]);
    }
    __syncthreads();

    bf16x8 ah[4], al[4], bh[4], bl[4];
    #pragma unroll
    for (int i = 0; i < 4; ++i) {
      const int ra = (wm * 64 + i * 16 + fr) * 32 + fq * 8;
      ah[i] = *(const bf16x8*)&sAh[ra];
      al[i] = *(const bf16x8*)&sAl[ra];
      const int rb = (wn * 64 + i * 16 + fr) * 32 + fq * 8;
      bh[i] = *(const bf16x8*)&sBh[rb];
      bl[i] = *(const bf16x8*)&sBl[rb];
    }
    #pragma unroll
    for (int i = 0; i < 4; ++i)
      #pragma unroll
      for (int j = 0; j < 4; ++j) {
        acc[i][j] = __builtin_amdgcn_mfma_f32_16x16x32_bf16(ah[i], bh[j], acc[i][j], 0, 0, 0);
        acc[i][j] = __builtin_amdgcn_mfma_f32_16x16x32_bf16(al[i], bh[j], acc[i][j], 0, 0, 0);
        acc[i][j] = __builtin_amdgcn_mfma_f32_16x16x32_bf16(ah[i], bl[j], acc[i][j], 0, 0, 0);
      }
  }

  float bcol[4];
  #pragma unroll
  for (int j = 0; j < 4; ++j) bcol[j] = bias[n0 + wn * 64 + j * 16 + fr];

  #pragma unroll
  for (int i = 0; i < 4; ++i) {
    #pragma unroll
    for (int r = 0; r < 4; ++r) {
      const int row = m0 + wm * 64 + i * 16 + fq * 4 + r;
      const size_t ro = (size_t)row * N;
      #pragma unroll
      for (int j = 0; j < 4; ++j) {
        const int col = n0 + wn * 64 + j * 16 + fr;
        float v = acc[i][j][r] + bcol[j];
        if (EPI == 1) {
          Cf[ro + col] = gelu_f(v);
        } else if (EPI == 2) {
          Cf[ro + col] = v + ResF[ro + col];
        } else {
          Cf[ro + col] = v;
        }
      }
    }
  }
}

// ---------------------------------------------------------------------------
// NEW: 256x256 2-term GEMM, triple-buffered deep pipeline.
// C = epi(A_bf16[M,K] @ (Bh+Bl)^T[N,K] + bias)
// BK=32, 512 thr (8 waves 2Mx4N), per-wave 128x64 out (8x4 frags, 2 MFMA ea).
// LDS: 3 bufs x 3 streams (Ah,Bh,Bl) x 256x32 bf16 = 144 KB.
// One vmcnt(6)+s_barrier per K-tile; prefetch distance = 2 tiles (~5000 cy).
// Swizzle: chunk' = chunk ^ ((row>>1)&3), applied on BOTH stage-src and read.
// EPI: 10 QKV routing (Q/K -> hl rows, V -> transposed hl)
//      11 bias+gelu -> bf16 hi
//      12 raw f32 partial (split-K plane via blockIdx.z; planes P0..P3 passed
//         through Cf, Kh2, Kl2, Vh2 pointer slots)
// ---------------------------------------------------------------------------
template<int EPI>
__global__ __launch_bounds__(512, 2)
void gemm256(const us* __restrict__ Ah,
             const us* __restrict__ Bh, const us* __restrict__ Bl,
             const float* __restrict__ bias,
             float* __restrict__ Cf, us* __restrict__ Ch, us* __restrict__ Cl,
             us* __restrict__ Kh2, us* __restrict__ Kl2,
             us* __restrict__ Vh2, us* __restrict__ Vl2,
             int M, int N, int Kfull, int klen) {
  __shared__ us sm3[3][3][8192];   // [buf][Ah,Bh,Bl][row*32+k]  144 KB

  const int t = threadIdx.x;
  const int lane = t & 63, wid = t >> 6;
  const int wm = wid >> 2, wn = wid & 3;
  const int fr = lane & 15, fq = lane >> 4;
  const int rsw8 = (fq ^ ((fr >> 1) & 3)) * 8;   // swizzled read chunk (us)

  const int nx = N >> 8;
  const int idl = blockIdx.x + blockIdx.y * nx;
  const int xcd = idl & 7, jj = idl >> 3;
  const int band = (M >> 8) >> 3;
  const int m0 = (xcd * band + (jj % band)) << 8;
  const int n0 = (jj / band) << 8;
  const int koff = blockIdx.z * klen;

  // staging: thread covers LDS slot (row = half*128 + t>>2, chunk = t&3);
  // inverse-swizzled global chunk:
  const int srow = t >> 2;
  const int gchunk = (t & 3) ^ ((t >> 3) & 3);
  const int dso = srow * 32 + (t & 3) * 8;       // dest us-off (half 0)

  auto stage1 = [&](int buf, int kt, int idx) {
    const int stream = idx >> 1;                 // 0:Ah 1:Bh 2:Bl
    const int half = idx & 1;
    const us* gp = (stream == 0) ? Ah : (stream == 1 ? Bh : Bl);
    const int rbase = ((stream == 0) ? m0 : n0) + half * 128 + srow;
    const size_t g = (size_t)rbase * Kfull + koff + kt * 32 + gchunk * 8;
    glds16(gp + g, &sm3[buf][stream][half * 4096 + dso]);
  };

  f32x4 acc[8][4];
  #pragma unroll
  for (int i = 0; i < 8; ++i)
    #pragma unroll
    for (int n = 0; n < 4; ++n) acc[i][n] = (f32x4){0.f, 0.f, 0.f, 0.f};

  // prologue: stage tiles 0 and 1 (6 loads each)
  #pragma unroll
  for (int idx = 0; idx < 6; ++idx) stage1(0, 0, idx);
  #pragma unroll
  for (int idx = 0; idx < 6; ++idx) stage1(1, 1, idx);

  const int nt = klen >> 5;
  for (int g = 0; g < nt; ++g) {
    const int cb = g % 3;
    if (g < nt - 1) { asm volatile("s_waitcnt vmcnt(6)" ::: "memory"); }
    else            { asm volatile("s_waitcnt vmcnt(0)" ::: "memory"); }
    __builtin_amdgcn_sched_barrier(0);
    __builtin_amdgcn_s_barrier();
    __builtin_amdgcn_sched_barrier(0);

    const us* sA  = sm3[cb][0];
    const us* sBh = sm3[cb][1];
    const us* sBl = sm3[cb][2];

    bf16x8 bhf[4], blf[4];
    #pragma unroll
    for (int n = 0; n < 4; ++n) {
      const int rb = (wn * 64 + n * 16 + fr) * 32 + rsw8;
      bhf[n] = *(const bf16x8*)&sBh[rb];
      blf[n] = *(const bf16x8*)&sBl[rb];
    }
    bf16x8 a_cur = *(const bf16x8*)&sA[(wm * 128 + fr) * 32 + rsw8];

    const bool pf = (g + 2 < nt);
    const int nb = (g + 2) % 3;

    #pragma unroll
    for (int i = 0; i < 8; ++i) {
      if (pf && i < 6) stage1(nb, g + 2, i);
      bf16x8 a_nxt;
      if (i < 7) {
        a_nxt = *(const bf16x8*)&sA[(wm * 128 + (i + 1) * 16 + fr) * 32 + rsw8];
        asm volatile("s_waitcnt lgkmcnt(1)" ::: "memory");
      } else {
        asm volatile("s_waitcnt lgkmcnt(0)" ::: "memory");
      }
      __builtin_amdgcn_sched_barrier(0);
      __builtin_amdgcn_s_setprio(1);
      #pragma unroll
      for (int n = 0; n < 4; ++n) {
        acc[i][n] = __builtin_amdgcn_mfma_f32_16x16x32_bf16(a_cur, bhf[n], acc[i][n], 0, 0, 0);
        acc[i][n] = __builtin_amdgcn_mfma_f32_16x16x32_bf16(a_cur, blf[n], acc[i][n], 0, 0, 0);
      }
      __builtin_amdgcn_s_setprio(0);
      if (i < 7) a_cur = a_nxt;
    }
  }

  // ---- epilogues (C/D frag: col = n0+wn*64+n*16+fr, row = m0+wm*128+i*16+fq*4+r)
  if (EPI == 12) {
    float* pk = (blockIdx.z == 0) ? Cf :
                (blockIdx.z == 1) ? (float*)Kh2 :
                (blockIdx.z == 2) ? (float*)Kl2 : (float*)Vh2;
    #pragma unroll
    for (int i = 0; i < 8; ++i) {
      #pragma unroll
      for (int r = 0; r < 4; ++r) {
        const int row = m0 + wm * 128 + i * 16 + fq * 4 + r;
        const size_t ro = (size_t)row * N;
        #pragma unroll
        for (int n = 0; n < 4; ++n) {
          const int col = n0 + wn * 64 + n * 16 + fr;
          pk[ro + col] = acc[i][n][r];
        }
      }
    }
    return;
  }

  float bcol[4];
  #pragma unroll
  for (int n = 0; n < 4; ++n) bcol[n] = bias[n0 + wn * 64 + n * 16 + fr];

  if (EPI == 11) {
    #pragma unroll
    for (int i = 0; i < 8; ++i) {
      #pragma unroll
      for (int r = 0; r < 4; ++r) {
        const int row = m0 + wm * 128 + i * 16 + fq * 4 + r;
        const size_t ro = (size_t)row * N;
        #pragma unroll
        for (int n = 0; n < 4; ++n) {
          const int col = n0 + wn * 64 + n * 16 + fr;
          Ch[ro + col] = bf16_of(gelu_f(acc[i][n][r] + bcol[n]));
        }
      }
    }
    return;
  }

  // EPI == 10: QKV routing (256-col tile lies in one 1024 group)
  {
    const int sel = n0 >> 10;
    if (sel < 2) {
      us* dh = (sel == 0) ? Ch : Kh2;
      us* dl = (sel == 0) ? Cl : Kl2;
      #pragma unroll
      for (int i = 0; i < 8; ++i) {
        #pragma unroll
        for (int r = 0; r < 4; ++r) {
          const int row = m0 + wm * 128 + i * 16 + fq * 4 + r;
          const size_t ro = (size_t)row * 1024;
          #pragma unroll
          for (int n = 0; n < 4; ++n) {
            const int c10 = (n0 & 1023) + wn * 64 + n * 16 + fr;
            float v = acc[i][n][r] + bcol[n];
            us h, l; split_hl(v, h, l);
            dh[ro + c10] = h; dl[ro + c10] = l;
          }
        }
      }
    } else {
      #pragma unroll
      for (int i = 0; i < 8; ++i) {
        #pragma unroll
        for (int n = 0; n < 4; ++n) {
          const int c10 = (n0 & 1023) + wn * 64 + n * 16 + fr;
          const int hh2 = c10 >> 6, dh = c10 & 63;
          const int row0 = m0 + wm * 128 + i * 16 + fq * 4;
          const int bb = row0 >> 10, ltok = row0 & 1023;
          ushort4 h4, l4;
          float v0 = acc[i][n][0] + bcol[n];
          float v1 = acc[i][n][1] + bcol[n];
          float v2 = acc[i][n][2] + bcol[n];
          float v3 = acc[i][n][3] + bcol[n];
          split_hl(v0, h4.x, l4.x); split_hl(v1, h4.y, l4.y);
          split_hl(v2, h4.z, l4.z); split_hl(v3, h4.w, l4.w);
          const size_t off = ((size_t)(bb * 16 + hh2) * 64 + dh) * L_ + ltok;
          *(ushort4*)&Vh2[off] = h4;
          *(ushort4*)&Vl2[off] = l4;
        }
      }
    }
  }
}

// ---------------------------------------------------------------------------
// MFMA flash attention (unchanged, verified)
// ---------------------------------------------------------------------------
__global__ __launch_bounds__(256, 3)
void attn_mfma(const us* __restrict__ Qh, const us* __restrict__ Ql,
               const us* __restrict__ Kh, const us* __restrict__ Kl,
               const us* __restrict__ Vth, const us* __restrict__ Vtl,
               us* __restrict__ Oh, us* __restrict__ Ol) {
  const int raw = blockIdx.x + blockIdx.y * 16;
  const int hh = (raw & 7) + 8 * ((raw >> 3) >> 4);
  const int qq = (raw >> 3) & 15;
  const int b = hh >> 4, h = hh & 15;

  const int t = threadIdx.x;
  const int w = t >> 6, lane = t & 63;
  const int fr = lane & 15, g = lane >> 4;

  __shared__ __align__(16) unsigned char smem[51200];
  us* sKh = (us*)(smem);
  us* sKl = (us*)(smem + 8192);
  us* sVh = (us*)(smem + 16384);
  us* sVl = (us*)(smem + 24576);
  us* sPh = (us*)(smem + 32768);
  us* sPl = (us*)(smem + 41984);
  float* fb = (float*)smem;

  const int tok0 = b * L_ + qq * 64 + w * 16;
  bf16x8 qfh[2], qfl[2];
  #pragma unroll
  for (int ks = 0; ks < 2; ++ks) {
    const size_t qo = (size_t)(tok0 + fr) * D_ + h * 64 + ks * 32 + g * 8;
    qfh[ks] = *(const bf16x8*)&Qh[qo];
    qfl[ks] = *(const bf16x8*)&Ql[qo];
  }

  float m = -INFINITY, l = 0.0f;
  f32x4 ctx[4];
  #pragma unroll
  for (int i = 0; i < 4; ++i) ctx[i] = (f32x4){0.f, 0.f, 0.f, 0.f};

  for (int kt = 0; kt < 16; ++kt) {
    const int k0 = kt * 64;
    __syncthreads();
    #pragma unroll
    for (int p = 0; p < 2; ++p) {
      const int ci = w * 128 + p * 64 + lane;
      const int dbase = (w * 128 + p * 64) * 8;
      {
        const int ks = ci >> 8, rem = ci & 255, key = rem >> 2, sub = rem & 3;
        const size_t src = (size_t)(b * L_ + k0 + key) * D_ + h * 64 + ks * 32 + sub * 8;
        glds16(Kh + src, sKh + dbase);
        glds16(Kl + src, sKl + dbase);
      }
      {
        const int d = ci >> 3, c = ci & 7;
        const size_t src = (size_t)(hh * 64 + d) * L_ + k0 + ((c ^ (d & 7)) * 8);
        glds16(Vth + src, sVh + dbase);
        glds16(Vtl + src, sVl + dbase);
      }
    }
    __syncthreads();

    f32x4 accS[4];
    #pragma unroll
    for (int i = 0; i < 4; ++i) accS[i] = (f32x4){0.f, 0.f, 0.f, 0.f};
    #pragma unroll
    for (int ks = 0; ks < 2; ++ks) {
      #pragma unroll
      for (int i = 0; i < 4; ++i) {
        const int ra = (ks * 64 + i * 16 + fr) * 32 + g * 8;
        bf16x8 ah = *(const bf16x8*)&sKh[ra];
        bf16x8 al = *(const bf16x8*)&sKl[ra];
        accS[i] = __builtin_amdgcn_mfma_f32_16x16x32_bf16(ah, qfh[ks], accS[i], 0, 0, 0);
        accS[i] = __builtin_amdgcn_mfma_f32_16x16x32_bf16(al, qfh[ks], accS[i], 0, 0, 0);
        accS[i] = __builtin_amdgcn_mfma_f32_16x16x32_bf16(ah, qfl[ks], accS[i], 0, 0, 0);
      }
    }

    float sv[4][4];
    float mloc = -INFINITY;
    #pragma unroll
    for (int i = 0; i < 4; ++i)
      #pragma unroll
      for (int r = 0; r < 4; ++r) {
        sv[i][r] = accS[i][r] * 0.125f;
        mloc = fmaxf(mloc, sv[i][r]);
      }
    mloc = fmaxf(mloc, __shfl_xor(mloc, 16));
    mloc = fmaxf(mloc, __shfl_xor(mloc, 32));
    const float mnew = fmaxf(m, mloc);
    const float alpha = expf(m - mnew);
    float p[4][4];
    float lt = 0.f;
    #pragma unroll
    for (int i = 0; i < 4; ++i)
      #pragma unroll
      for (int r = 0; r < 4; ++r) {
        p[i][r] = expf(sv[i][r] - mnew);
        lt += p[i][r];
      }
    lt += __shfl_xor(lt, 16);
    lt += __shfl_xor(lt, 32);
    l = l * alpha + lt;
    m = mnew;
    #pragma unroll
    for (int i = 0; i < 4; ++i) {
      ctx[i][0] *= alpha; ctx[i][1] *= alpha;
      ctx[i][2] *= alpha; ctx[i][3] *= alpha;
    }

    #pragma unroll
    for (int i = 0; i < 4; ++i) {
      us h0 = bf16_of(p[i][0]), h1 = bf16_of(p[i][1]);
      us h2 = bf16_of(p[i][2]), h3 = bf16_of(p[i][3]);
      uint2 hv = {(uint32_t)h0 | ((uint32_t)h1 << 16),
                  (uint32_t)h2 | ((uint32_t)h3 << 16)};
      us l0 = bf16_of(p[i][0] - f32_of(h0)), l1 = bf16_of(p[i][1] - f32_of(h1));
      us l2 = bf16_of(p[i][2] - f32_of(h2)), l3 = bf16_of(p[i][3] - f32_of(h3));
      uint2 lv = {(uint32_t)l0 | ((uint32_t)l1 << 16),
                  (uint32_t)l2 | ((uint32_t)l3 << 16)};
      const int po = (w * 16 + fr) * 72 + i * 16 + g * 4;
      *(uint2*)&sPh[po] = hv;
      *(uint2*)&sPl[po] = lv;
    }

    #pragma unroll
    for (int ks = 0; ks < 2; ++ks) {
      const int pb = (w * 16 + fr) * 72 + ks * 32 + g * 8;
      bf16x8 pah = *(const bf16x8*)&sPh[pb];
      bf16x8 pal = *(const bf16x8*)&sPl[pb];
      #pragma unroll
      for (int i = 0; i < 4; ++i) {
        const int d = i * 16 + fr;
        const int pc = (ks * 4 + g) ^ (d & 7);
        bf16x8 vh = *(const bf16x8*)&sVh[d * 64 + pc * 8];
        bf16x8 vl = *(const bf16x8*)&sVl[d * 64 + pc * 8];
        ctx[i] = __builtin_amdgcn_mfma_f32_16x16x32_bf16(vh, pah, ctx[i], 0, 0, 0);
        ctx[i] = __builtin_amdgcn_mfma_f32_16x16x32_bf16(vl, pah, ctx[i], 0, 0, 0);
        ctx[i] = __builtin_amdgcn_mfma_f32_16x16x32_bf16(vh, pal, ctx[i], 0, 0, 0);
      }
    }
  }

  const float invl = 1.0f / l;
  __syncthreads();
  #pragma unroll
  for (int i = 0; i < 4; ++i)
    #pragma unroll
    for (int r = 0; r < 4; ++r)
      fb[(i * 16 + g * 4 + r) * 64 + w * 16 + fr] = ctx[i][r] * invl;
  __syncthreads();

  {
    const int q = t >> 2, dg = t & 3;
    const size_t ob = (size_t)(b * L_ + qq * 64 + q) * D_ + h * 64;
    #pragma unroll
    for (int u = 0; u < 4; ++u) {
      const int d0 = dg * 16 + u * 4;
      ushort4 h4, l4;
      float v0 = fb[(d0 + 0) * 64 + q];
      float v1 = fb[(d0 + 1) * 64 + q];
      float v2 = fb[(d0 + 2) * 64 + q];
      float v3 = fb[(d0 + 3) * 64 + q];
      split_hl(v0, h4.x, l4.x); split_hl(v1, h4.y, l4.y);
      split_hl(v2, h4.z, l4.z); split_hl(v3, h4.w, l4.w);
      *(ushort4*)&Oh[ob + d0] = h4;
      *(ushort4*)&Ol[ob + d0] = l4;
    }
  }
}

// ---------------------------------------------------------------------------
// LayerNorm over D=1024.  MODE 0: fp32 out; MODE 1: bf16 hi/lo out.
// ---------------------------------------------------------------------------
template<int MODE>
__global__ __launch_bounds__(256)
void layernorm_k(const float* __restrict__ X, const float* __restrict__ g,
                 const float* __restrict__ b, float* __restrict__ Yf,
                 us* __restrict__ Yh, us* __restrict__ Yl) {
  const int row = blockIdx.x;
  const int t = threadIdx.x;
  const float* x = X + (size_t)row * D_;

  float4 v = *(const float4*)&x[t * 4];
  float s  = v.x + v.y + v.z + v.w;
  float ss = v.x * v.x + v.y * v.y + v.z * v.z + v.w * v.w;

  #pragma unroll
  for (int off = 1; off < 64; off <<= 1) {
    s  += __shfl_xor(s, off);
    ss += __shfl_xor(ss, off);
  }
  __shared__ float red[4][2];
  const int wid = t >> 6;
  if ((t & 63) == 0) { red[wid][0] = s; red[wid][1] = ss; }
  __syncthreads();
  s  = red[0][0] + red[1][0] + red[2][0] + red[3][0];
  ss = red[0][1] + red[1][1] + red[2][1] + red[3][1];

  const float mean = s * (1.0f / D_);
  const float var  = ss * (1.0f / D_) - mean * mean;
  const float inv  = rsqrtf(var + 1e-5f);

  float4 gv = *(const float4*)&g[t * 4];
  float4 bv = *(const float4*)&b[t * 4];
  float4 o;
  o.x = (v.x - mean) * inv * gv.x + bv.x;
  o.y = (v.y - mean) * inv * gv.y + bv.y;
  o.z = (v.z - mean) * inv * gv.z + bv.z;
  o.w = (v.w - mean) * inv * gv.w + bv.w;
  if (MODE == 0) {
    *(float4*)&Yf[(size_t)row * D_ + t * 4] = o;
  } else {
    ushort4 h, l;
    split_hl(o.x, h.x, l.x); split_hl(o.y, h.y, l.y);
    split_hl(o.z, h.z, l.z); split_hl(o.w, h.w, l.w);
    *(ushort4*)&Yh[(size_t)row * D_ + t * 4] = h;
    *(ushort4*)&Yl[(size_t)row * D_ + t * 4] = l;
  }
}

// ---------------------------------------------------------------------------
// Split-K reduce (4 planes, separate base ptrs) + bias + residual(hl) + LN.
// Y may alias P0 (each element read+written by the same thread only).
// ---------------------------------------------------------------------------
__global__ __launch_bounds__(256)
void lnred4(const float* __restrict__ P0, const float* __restrict__ P1,
            const float* __restrict__ P2, const float* __restrict__ P3,
            const float* __restrict__ b2,
            const us* __restrict__ Rh, const us* __restrict__ Rl,
            const float* __restrict__ g, const float* __restrict__ be,
            float* __restrict__ Y) {
  const int row = blockIdx.x;
  const int t = threadIdx.x;
  const size_t o = (size_t)row * D_ + t * 4;

  float4 v0 = *(const float4*)&P0[o];
  float4 v1 = *(const float4*)&P1[o];
  float4 v2 = *(const float4*)&P2[o];
  float4 v3 = *(const float4*)&P3[o];
  float4 bb = *(const float4*)&b2[t * 4];
  ushort4 rh = *(const ushort4*)&Rh[o];
  ushort4 rl = *(const ushort4*)&Rl[o];
  float4 v;
  v.x = v0.x + v1.x + v2.x + v3.x + bb.x + f32_of(rh.x) + f32_of(rl.x);
  v.y = v0.y + v1.y + v2.y + v3.y + bb.y + f32_of(rh.y) + f32_of(rl.y);
  v.z = v0.z + v1.z + v2.z + v3.z + bb.z + f32_of(rh.z) + f32_of(rl.z);
  v.w = v0.w + v1.w + v2.w + v3.w + bb.w + f32_of(rh.w) + f32_of(rl.w);

  float s  = v.x + v.y + v.z + v.w;
  float ss = v.x * v.x + v.y * v.y + v.z * v.z + v.w * v.w;
  #pragma unroll
  for (int off = 1; off < 64; off <<= 1) {
    s  += __shfl_xor(s, off);
    ss += __shfl_xor(ss, off);
  }
  __shared__ float red[4][2];
  const int wid = t >> 6;
  if ((t & 63) == 0) { red[wid][0] = s; red[wid][1] = ss; }
  __syncthreads();
  s  = red[0][0] + red[1][0] + red[2][0] + red[3][0];
  ss = red[0][1] + red[1][1] + red[2][1] + red[3][1];

  const float mean = s * (1.0f / D_);
  const float var  = ss * (1.0f / D_) - mean * mean;
  const float inv  = rsqrtf(var + 1e-5f);

  float4 gv = *(const float4*)&g[t * 4];
  float4 bv = *(const float4*)&be[t * 4];
  float4 y;
  y.x = (v.x - mean) * inv * gv.x + bv.x;
  y.y = (v.y - mean) * inv * gv.y + bv.y;
  y.z = (v.z - mean) * inv * gv.z + bv.z;
  y.w = (v.w - mean) * inv * gv.w + bv.w;
  *(float4*)&Y[o] = y;
}

// ---------------------------------------------------------------------------
// Fused adapter: gate + top-2 + softmax + 2-expert R->D + residual combine.
// ---------------------------------------------------------------------------
__global__ __launch_bounds__(256)
void adapter_combine_hl(const us* __restrict__ Xh, const us* __restrict__ Xl,
                        const float* __restrict__ Hall,
                        const float* __restrict__ Lout,
                        const us* __restrict__ W2b,
                        const float* __restrict__ B2,
                        const float* __restrict__ GW,
                        const float* __restrict__ GB,
                        float* __restrict__ Out) {
  const int tok = blockIdx.x;
  const int t = threadIdx.x;

  __shared__ float xs[D_];
  __shared__ float part[256];
  __shared__ float logit_s[E_];
  __shared__ float hs[2 * R_];
  __shared__ int   e_sh[2];
  __shared__ float g_sh[2];

  {
    ushort4 h = *(const ushort4*)&Xh[(size_t)tok * D_ + t * 4];
    ushort4 l = *(const ushort4*)&Xl[(size_t)tok * D_ + t * 4];
    xs[t * 4 + 0] = f32_of(h.x) + f32_of(l.x);
    xs[t * 4 + 1] = f32_of(h.y) + f32_of(l.y);
    xs[t * 4 + 2] = f32_of(h.z) + f32_of(l.z);
    xs[t * 4 + 3] = f32_of(h.w) + f32_of(l.w);
  }
  __syncthreads();

  {
    const int e = t & 7, seg = t >> 3;
    float p = 0.f;
    #pragma unroll 8
    for (int i = 0; i < 32; ++i) {
      const int d = seg * 32 + i;
      p = fmaf(xs[d], GW[d * E_ + e], p);
    }
    part[t] = p;
  }
  __syncthreads();
  if (t < E_) {
    float s = GB[t];
    for (int sg = 0; sg < 32; ++sg) s += part[sg * 8 + t];
    logit_s[t] = s;
  }
  __syncthreads();
  if (t == 0) {
    int e1 = 0; float v1 = logit_s[0];
    for (int i = 1; i < E_; ++i) if (logit_s[i] > v1) { v1 = logit_s[i]; e1 = i; }
    int e2 = -1; float v2 = -INFINITY;
    for (int i = 0; i < E_; ++i) if (i != e1 && logit_s[i] > v2) { v2 = logit_s[i]; e2 = i; }
    const float ee = expf(v2 - v1);
    const float den = 1.0f + ee;
    g_sh[0] = 1.0f / den; g_sh[1] = ee / den;
    e_sh[0] = e1; e_sh[1] = e2;
  }
  __syncthreads();
  const int e1 = e_sh[0], e2 = e_sh[1];
  const float g1 = g_sh[0], g2 = g_sh[1];

  if (t < 2 * R_) {
    const int ex = (t < R_) ? e1 : e2;
    const int r = t & (R_ - 1);
    hs[t] = Hall[(size_t)tok * (E_ * R_) + ex * R_ + r];
  }
  __syncthreads();

  const int d = t * 4;
  float4 b1v = *(const float4*)&B2[e1 * D_ + d];
  float4 b2v = *(const float4*)&B2[e2 * D_ + d];
  float4 acc;
  acc.x = g1 * b1v.x + g2 * b2v.x;
  acc.y = g1 * b1v.y + g2 * b2v.y;
  acc.z = g1 * b1v.z + g2 * b2v.z;
  acc.w = g1 * b1v.w + g2 * b2v.w;

  #pragma unroll 8
  for (int r = 0; r < R_; ++r) {
    const float f = g1 * hs[r];
    ushort4 w = *(const ushort4*)&W2b[((size_t)e1 * R_ + r) * D_ + d];
    acc.x = fmaf(f, f32_of(w.x), acc.x); acc.y = fmaf(f, f32_of(w.y), acc.y);
    acc.z = fmaf(f, f32_of(w.z), acc.z); acc.w = fmaf(f, f32_of(w.w), acc.w);
  }
  #pragma unroll 8
  for (int r = 0; r < R_; ++r) {
    const float f = g2 * hs[R_ + r];
    ushort4 w = *(const ushort4*)&W2b[((size_t)e2 * R_ + r) * D_ + d];
    acc.x = fmaf(f, f32_of(w.x), acc.x); acc.y = fmaf(f, f32_of(w.y), acc.y);
    acc.z = fmaf(f, f32_of(w.z), acc.z); acc.w = fmaf(f, f32_of(w.w), acc.w);
  }

  float4 lo = *(const float4*)&Lout[(size_t)tok * D_ + d];
  float4 o = {lo.x + 2.0f * acc.x, lo.y + 2.0f * acc.y,
              lo.z + 2.0f * acc.z, lo.w + 2.0f * acc.w};
  *(float4*)&Out[(size_t)tok * D_ + d] = o;
}

// ---------------------------------------------------------------------------
extern "C" void kernel_launch(void* const* d_in, const int* in_sizes, int n_in,
                              void* d_out, int out_size, void* d_ws, size_t ws_size,
                              hipStream_t stream) {
  const float* x     = (const float*)d_in[0];
  const float* wq    = (const float*)d_in[1];
  const float* wk    = (const float*)d_in[2];
  const float* wv    = (const float*)d_in[3];
  const float* wo    = (const float*)d_in[4];
  const float* bq    = (const float*)d_in[5];
  const float* bk    = (const float*)d_in[6];
  const float* bv    = (const float*)d_in[7];
  const float* bo    = (const float*)d_in[8];
  const float* ln1g  = (const float*)d_in[9];
  const float* ln1b  = (const float*)d_in[10];
  const float* w1    = (const float*)d_in[11];
  const float* b1    = (const float*)d_in[12];
  const float* w2    = (const float*)d_in[13];
  const float* b2    = (const float*)d_in[14];
  const float* ln2g  = (const float*)d_in[15];
  const float* ln2b  = (const float*)d_in[16];
  const float* aw1   = (const float*)d_in[17];
  const float* ab1   = (const float*)d_in[18];
  const float* aw2   = (const float*)d_in[19];
  const float* ab2   = (const float*)d_in[20];
  const float* gw    = (const float*)d_in[21];
  const float* gb    = (const float*)d_in[22];
  float* out = (float*)d_out;

  char* base = (char*)d_ws;
  const size_t MB = 1ull << 20;

  // weights (persistent)
  us* qkvTh = (us*)(base + 0 * MB);  us* qkvTl = (us*)(base + 6 * MB);   // [3072][1024]
  us* woTh  = (us*)(base + 12 * MB); us* woTl  = (us*)(base + 14 * MB);
  us* w1Th  = (us*)(base + 16 * MB); us* w1Tl  = (us*)(base + 24 * MB);
  us* w2Th  = (us*)(base + 32 * MB); us* w2Tl  = (us*)(base + 40 * MB);
  us* a1Th  = (us*)(base + 48 * MB); us* a1Tl  = (us*)(base + 49 * MB);
  us* w2b   = (us*)(base + 50 * MB);
  float* bqkv = (float*)(base + 51 * MB);
  // activations (regions reused as lifetimes end)
  us* xh   = (us*)(base + 52 * MB);                       // 8 MB
  us* ctxh = (us*)(base + 52 * MB);  us* ctxl = (us*)(base + 60 * MB);
  us* qbh  = (us*)(base + 68 * MB);  us* qbl  = (us*)(base + 76 * MB);
  us* kbh  = (us*)(base + 84 * MB);  us* kbl  = (us*)(base + 92 * MB);
  us* vth  = (us*)(base + 100 * MB); us* vtl  = (us*)(base + 108 * MB);
  float* ATTNPRE = (float*)(base + 68 * MB);              // after attn (q dead)
  us* aoh  = (us*)(base + 84 * MB);  us* aol  = (us*)(base + 92 * MB);  // k dead
  us* inth = (us*)(base + 116 * MB);                      // 32 MB [NTOK,FF] bf16
  // FFN2 split-K planes in dead regions:
  float* P0 = (float*)(base + 52 * MB);    // ctx dead after WO-proj
  float* P1 = (float*)(base + 68 * MB);    // ATTNPRE dead after LN1
  float* P2 = (float*)(base + 100 * MB);   // vt dead after attn
  float* P3 = (float*)(base + 148 * MB);   // fresh (16 MB) -> max 164 MB
  float* LOUT = P0;                        // lnred4 writes in place over P0
  float* HALL = (float*)(base + 68 * MB);  // P1 dead after lnred4

  const dim3 blk(256);
  const us* nu = nullptr;
  const float* nf = nullptr;

  // --- precompute splits ---
  fhi<<<dim3(NTOK * D_ / 1024), blk, 0, stream>>>(x, xh, NTOK * D_ / 4);
  wsplit_t<<<dim3(16, 16), blk, 0, stream>>>(wq, qkvTh, qkvTl, D_, D_);
  wsplit_t<<<dim3(16, 16), blk, 0, stream>>>(wk, qkvTh + 1024 * 1024, qkvTl + 1024 * 1024, D_, D_);
  wsplit_t<<<dim3(16, 16), blk, 0, stream>>>(wv, qkvTh + 2048 * 1024, qkvTl + 2048 * 1024, D_, D_);
  wsplit_t<<<dim3(16, 16), blk, 0, stream>>>(wo, woTh, woTl, D_, D_);
  wsplit_t<<<dim3(64, 16), blk, 0, stream>>>(w1, w1Th, w1Tl, D_, FF_);
  wsplit_t<<<dim3(16, 64), blk, 0, stream>>>(w2, w2Th, w2Tl, FF_, D_);
  wsplit_t<<<dim3(8, 16),  blk, 0, stream>>>(aw1, a1Th, a1Tl, D_, E_ * R_);
  fhi<<<dim3(E_ * R_ * D_ / 1024), blk, 0, stream>>>(aw2, w2b, E_ * R_ * D_ / 4);
  bconcat<<<dim3(12), blk, 0, stream>>>(bq, bk, bv, bqkv);

  // --- fused QKV projection (2-term deep-pipe), routing epilogue ---
  gemm256<10><<<dim3(12, 16), dim3(512), 0, stream>>>(
      xh, qkvTh, qkvTl, bqkv, nullptr, qbh, qbl, kbh, kbl, vth, vtl,
      NTOK, 3072, D_, D_);
  // --- attention (3-term, verified) ---
  attn_mfma<<<dim3(16, 64), blk, 0, stream>>>(qbh, qbl, kbh, kbl, vth, vtl, ctxh, ctxl);
  // --- output projection + residual(x), LN1 -> AO hi/lo ---
  gemm_mfma<2><<<dim3(8, 32), blk, 0, stream>>>(ctxh, ctxl, woTh, woTl, bo, x,
                                                ATTNPRE, NTOK, D_, D_);
  layernorm_k<1><<<dim3(NTOK), blk, 0, stream>>>(ATTNPRE, ln1g, ln1b, nullptr, aoh, aol);
  // --- FFN1 (2-term deep-pipe, gelu -> bf16 hi) ---
  gemm256<11><<<dim3(16, 16), dim3(512), 0, stream>>>(
      aoh, w1Th, w1Tl, b1, nullptr, inth, nullptr, nullptr, nullptr, nullptr, nullptr,
      NTOK, FF_, D_, D_);
  // --- FFN2 (2-term deep-pipe, split-K=4 into P0..P3) + fused reduce+LN2 ---
  gemm256<12><<<dim3(4, 16, 4), dim3(512), 0, stream>>>(
      inth, w2Th, w2Tl, nf, P0, nullptr, nullptr, (us*)P1, (us*)P2, (us*)P3, nullptr,
      NTOK, D_, FF_, 1024);
  lnred4<<<dim3(NTOK), blk, 0, stream>>>(P0, P1, P2, P3, b2, aoh, aol, ln2g, ln2b, LOUT);
  // --- adapter ---
  gemm_mfma<1><<<dim3(4, 32), blk, 0, stream>>>(aoh, aol, a1Th, a1Tl, ab1, nf,
                                                HALL, NTOK, E_ * R_, D_);
  adapter_combine_hl<<<dim3(NTOK), blk, 0, stream>>>(aoh, aol, HALL, LOUT, w2b, ab2, gw, gb, out);
}

// Round 6
// 571.351 us; speedup vs baseline: 3.9057x; 1.1117x over previous
//
#include <hip/hip_runtime.h>
#include <cstddef>
#include <cstdint>

#define B_   4
#define L_   1024
#define D_   1024
#define H_   16
#define DH_  64
#define E_   8
#define R_   64
#define FF_  4096
#define NTOK (B_ * L_)   // 4096

typedef __attribute__((ext_vector_type(8))) short bf16x8;
typedef __attribute__((ext_vector_type(4))) float f32x4;
typedef unsigned short us;

__device__ __forceinline__ float gelu_f(float x) {
  return 0.5f * x * (1.0f + erff(x * 0.7071067811865476f));
}

__device__ __forceinline__ us bf16_of(float f) {
  union { float f; uint32_t u; } x; x.f = f;
  uint32_t r = x.u + 0x7FFFu + ((x.u >> 16) & 1u);   // RNE
  return (us)(r >> 16);
}
__device__ __forceinline__ float f32_of(us h) {
  union { uint32_t u; float f; } x; x.u = ((uint32_t)h) << 16;
  return x.f;
}
__device__ __forceinline__ void split_hl(float v, us& hi, us& lo) {
  hi = bf16_of(v);
  lo = bf16_of(v - f32_of(hi));
}

__device__ __forceinline__ void glds16(const void* g, const void* l) {
  __builtin_amdgcn_global_load_lds(
      (const __attribute__((address_space(1))) unsigned int*)g,
      (__attribute__((address_space(3))) unsigned int*)l, 16, 0, 0);
}

// ---------------------------------------------------------------------------
// fp32 -> bf16 (hi only)
// ---------------------------------------------------------------------------
__global__ __launch_bounds__(256)
void fhi(const float* __restrict__ X, us* __restrict__ Hh, int n4) {
  int i = blockIdx.x * 256 + threadIdx.x;
  if (i >= n4) return;
  float4 v = ((const float4*)X)[i];
  ushort4 h = {bf16_of(v.x), bf16_of(v.y), bf16_of(v.z), bf16_of(v.w)};
  ((ushort4*)Hh)[i] = h;
}

// concat 3 x [1024] biases -> [3072]
__global__ __launch_bounds__(256)
void bconcat(const float* __restrict__ a, const float* __restrict__ b,
             const float* __restrict__ c, float* __restrict__ o) {
  int i = blockIdx.x * 256 + threadIdx.x;
  if (i >= 3072) return;
  o[i] = (i < 1024) ? a[i] : (i < 2048 ? b[i - 1024] : c[i - 2048]);
}

// ---------------------------------------------------------------------------
// Weight split+transpose: W[K,N] fp32 -> Th,Tl [N,K] bf16.
// ---------------------------------------------------------------------------
__global__ __launch_bounds__(256)
void wsplit_t(const float* __restrict__ W, us* __restrict__ Th,
              us* __restrict__ Tl, int K, int N) {
  __shared__ float tile[64][65];
  const int k0 = blockIdx.y * 64, n0 = blockIdx.x * 64;
  const int t = threadIdx.x;
  const int r = t >> 4, c4 = (t & 15) * 4;
  #pragma unroll
  for (int p = 0; p < 4; ++p) {
    const int k = r + p * 16;
    *(float4*)&tile[k][c4] = *(const float4*)&W[(size_t)(k0 + k) * N + n0 + c4];
  }
  __syncthreads();
  #pragma unroll
  for (int p = 0; p < 4; ++p) {
    const int n = r + p * 16;
    float v0 = tile[c4 + 0][n], v1 = tile[c4 + 1][n];
    float v2 = tile[c4 + 2][n], v3 = tile[c4 + 3][n];
    ushort4 h, l;
    split_hl(v0, h.x, l.x); split_hl(v1, h.y, l.y);
    split_hl(v2, h.z, l.z); split_hl(v3, h.w, l.w);
    const size_t o = (size_t)(n0 + n) * K + k0 + c4;
    *(ushort4*)&Th[o] = h;
    *(ushort4*)&Tl[o] = l;
  }
}

// ---------------------------------------------------------------------------
// 128x128 2-term GEMM, triple-buffered deep pipeline (counted vmcnt(6)).
// C = epi(A_bf16[M,K] @ (Bh+Bl)^T[N,K] + bias)
// 256 thr (4 waves 2x2), per-wave 64x64 out, LDS 3 bufs x 3 streams = 72 KB.
// Chunk swizzle sub^((row>>1)&3) on both stage-source and read.
// EPI: 1 bias+gelu->f32 | 2 bias+resF->f32
// ---------------------------------------------------------------------------
template<int EPI>
__global__ __launch_bounds__(256, 2)
void gemm128(const us* __restrict__ Ah,
             const us* __restrict__ Bh, const us* __restrict__ Bl,
             const float* __restrict__ bias, const float* __restrict__ ResF,
             float* __restrict__ Cf, int M, int N, int K) {
  __shared__ us sm3[3][3][4096];   // [buf][A,Bh,Bl][128*32] 72 KB

  const int t = threadIdx.x;
  const int lane = t & 63, wid = t >> 6;
  const int wm = wid >> 1, wn = wid & 1;
  const int fr = lane & 15, fq = lane >> 4;
  const int rsw8 = (fq ^ ((fr >> 1) & 3)) * 8;

  const int nx = N >> 7;
  const int idl = blockIdx.x + blockIdx.y * nx;
  const int xcd = idl & 7, jj = idl >> 3;
  const int band = (M >> 7) >> 3;
  const int m0 = (xcd * band + (jj % band)) << 7;
  const int n0 = (jj / band) << 7;

  const int srow = t >> 2;          // 0..63
  const int gsub = t & 3;

  auto stage1 = [&](int buf, int kt, int idx) {
    const int stream = idx >> 1;    // 0:A 1:Bh 2:Bl
    const int half = idx & 1;
    const us* gp = (stream == 0) ? Ah : (stream == 1 ? Bh : Bl);
    const int row = half * 64 + srow;
    const int gchunk = gsub ^ ((row >> 1) & 3);
    const int rbase = ((stream == 0) ? m0 : n0) + row;
    const size_t g = (size_t)rbase * K + kt * 32 + gchunk * 8;
    glds16(gp + g, &sm3[buf][stream][row * 32 + gsub * 8]);
  };

  f32x4 acc[4][4];
  #pragma unroll
  for (int i = 0; i < 4; ++i)
    #pragma unroll
    for (int n = 0; n < 4; ++n) acc[i][n] = (f32x4){0.f, 0.f, 0.f, 0.f};

  #pragma unroll
  for (int idx = 0; idx < 6; ++idx) stage1(0, 0, idx);
  #pragma unroll
  for (int idx = 0; idx < 6; ++idx) stage1(1, 1, idx);

  const int nt = K >> 5;
  for (int g = 0; g < nt; ++g) {
    const int cb = g % 3;
    if (g < nt - 1) { asm volatile("s_waitcnt vmcnt(6)" ::: "memory"); }
    else            { asm volatile("s_waitcnt vmcnt(0)" ::: "memory"); }
    __builtin_amdgcn_sched_barrier(0);
    __builtin_amdgcn_s_barrier();
    __builtin_amdgcn_sched_barrier(0);

    const us* sA   = sm3[cb][0];
    const us* sBh_ = sm3[cb][1];
    const us* sBl_ = sm3[cb][2];

    bf16x8 bh[4], bl[4], av[4];
    #pragma unroll
    for (int n = 0; n < 4; ++n) {
      const int rb = (wn * 64 + n * 16 + fr) * 32 + rsw8;
      bh[n] = *(const bf16x8*)&sBh_[rb];
      bl[n] = *(const bf16x8*)&sBl_[rb];
    }
    #pragma unroll
    for (int i = 0; i < 4; ++i)
      av[i] = *(const bf16x8*)&sA[(wm * 64 + i * 16 + fr) * 32 + rsw8];

    const bool pf = (g + 2 < nt);
    const int nb = (g + 2) % 3;

    #pragma unroll
    for (int i = 0; i < 4; ++i) {
      if (pf && i < 3) { stage1(nb, g + 2, 2 * i); stage1(nb, g + 2, 2 * i + 1); }
      if (i == 0) {
        asm volatile("s_waitcnt lgkmcnt(0)" ::: "memory");
        __builtin_amdgcn_sched_barrier(0);
      }
      __builtin_amdgcn_s_setprio(1);
      #pragma unroll
      for (int n = 0; n < 4; ++n) {
        acc[i][n] = __builtin_amdgcn_mfma_f32_16x16x32_bf16(av[i], bh[n], acc[i][n], 0, 0, 0);
        acc[i][n] = __builtin_amdgcn_mfma_f32_16x16x32_bf16(av[i], bl[n], acc[i][n], 0, 0, 0);
      }
      __builtin_amdgcn_s_setprio(0);
    }
  }

  float bcol[4];
  #pragma unroll
  for (int n = 0; n < 4; ++n) bcol[n] = bias[n0 + wn * 64 + n * 16 + fr];

  #pragma unroll
  for (int i = 0; i < 4; ++i) {
    #pragma unroll
    for (int r = 0; r < 4; ++r) {
      const int row = m0 + wm * 64 + i * 16 + fq * 4 + r;
      const size_t ro = (size_t)row * N;
      #pragma unroll
      for (int n = 0; n < 4; ++n) {
        const int col = n0 + wn * 64 + n * 16 + fr;
        float v = acc[i][n][r] + bcol[n];
        if (EPI == 1) Cf[ro + col] = gelu_f(v);
        else          Cf[ro + col] = v + ResF[ro + col];
      }
    }
  }
}

// ---------------------------------------------------------------------------
// 256x256 2-term GEMM, triple-buffered deep pipeline (unchanged from r5,
// except QKV routing writes K hi only).
// EPI: 10 QKV routing | 11 bias+gelu->bf16hi | 12 raw f32 split-K plane
// ---------------------------------------------------------------------------
template<int EPI>
__global__ __launch_bounds__(512, 2)
void gemm256(const us* __restrict__ Ah,
             const us* __restrict__ Bh, const us* __restrict__ Bl,
             const float* __restrict__ bias,
             float* __restrict__ Cf, us* __restrict__ Ch, us* __restrict__ Cl,
             us* __restrict__ Kh2, us* __restrict__ Kl2,
             us* __restrict__ Vh2, us* __restrict__ Vl2,
             int M, int N, int Kfull, int klen) {
  __shared__ us sm3[3][3][8192];   // 144 KB

  const int t = threadIdx.x;
  const int lane = t & 63, wid = t >> 6;
  const int wm = wid >> 2, wn = wid & 3;
  const int fr = lane & 15, fq = lane >> 4;
  const int rsw8 = (fq ^ ((fr >> 1) & 3)) * 8;

  const int nx = N >> 8;
  const int idl = blockIdx.x + blockIdx.y * nx;
  const int xcd = idl & 7, jj = idl >> 3;
  const int band = (M >> 8) >> 3;
  const int m0 = (xcd * band + (jj % band)) << 8;
  const int n0 = (jj / band) << 8;
  const int koff = blockIdx.z * klen;

  const int srow = t >> 2;
  const int gchunk = (t & 3) ^ ((t >> 3) & 3);
  const int dso = srow * 32 + (t & 3) * 8;

  auto stage1 = [&](int buf, int kt, int idx) {
    const int stream = idx >> 1;
    const int half = idx & 1;
    const us* gp = (stream == 0) ? Ah : (stream == 1 ? Bh : Bl);
    const int rbase = ((stream == 0) ? m0 : n0) + half * 128 + srow;
    const size_t g = (size_t)rbase * Kfull + koff + kt * 32 + gchunk * 8;
    glds16(gp + g, &sm3[buf][stream][half * 4096 + dso]);
  };

  f32x4 acc[8][4];
  #pragma unroll
  for (int i = 0; i < 8; ++i)
    #pragma unroll
    for (int n = 0; n < 4; ++n) acc[i][n] = (f32x4){0.f, 0.f, 0.f, 0.f};

  #pragma unroll
  for (int idx = 0; idx < 6; ++idx) stage1(0, 0, idx);
  #pragma unroll
  for (int idx = 0; idx < 6; ++idx) stage1(1, 1, idx);

  const int nt = klen >> 5;
  bf16x8 bhf[4], blf[4];

#define PH_MFMA(qq)                                                              \
  {                                                                              \
    bf16x8 a0 = *(const bf16x8*)&sm3[cb][0][(wm * 128 + (2*qq) * 16 + fr) * 32 + rsw8];   \
    bf16x8 a1 = *(const bf16x8*)&sm3[cb][0][(wm * 128 + (2*qq+1) * 16 + fr) * 32 + rsw8]; \
    asm volatile("s_waitcnt lgkmcnt(0)" ::: "memory");                           \
    __builtin_amdgcn_sched_barrier(0);                                           \
    __builtin_amdgcn_s_setprio(1);                                               \
    _Pragma("unroll")                                                            \
    for (int n = 0; n < 4; ++n) {                                                \
      acc[2*qq][n]   = __builtin_amdgcn_mfma_f32_16x16x32_bf16(a0, bhf[n], acc[2*qq][n], 0,0,0);   \
      acc[2*qq][n]   = __builtin_amdgcn_mfma_f32_16x16x32_bf16(a0, blf[n], acc[2*qq][n], 0,0,0);   \
      acc[2*qq+1][n] = __builtin_amdgcn_mfma_f32_16x16x32_bf16(a1, bhf[n], acc[2*qq+1][n], 0,0,0); \
      acc[2*qq+1][n] = __builtin_amdgcn_mfma_f32_16x16x32_bf16(a1, blf[n], acc[2*qq+1][n], 0,0,0); \
    }                                                                            \
    __builtin_amdgcn_s_setprio(0);                                               \
  }

  for (int g = 0; g < nt; ++g) {
    const int cb = g % 3;
    if (g < nt - 1) { asm volatile("s_waitcnt vmcnt(6)" ::: "memory"); }
    else            { asm volatile("s_waitcnt vmcnt(0)" ::: "memory"); }
    __builtin_amdgcn_sched_barrier(0);
    __builtin_amdgcn_s_barrier();
    __builtin_amdgcn_sched_barrier(0);
    #pragma unroll
    for (int n = 0; n < 4; ++n) {
      const int rb = (wn * 64 + n * 16 + fr) * 32 + rsw8;
      bhf[n] = *(const bf16x8*)&sm3[cb][1][rb];
      blf[n] = *(const bf16x8*)&sm3[cb][2][rb];
    }
    const bool pf = (g + 2 < nt);
    const int nb = (g + 2) % 3;
    if (pf) { stage1(nb, g + 2, 0); stage1(nb, g + 2, 1); }
    PH_MFMA(0)
    if (pf) { stage1(nb, g + 2, 2); stage1(nb, g + 2, 3); }
    PH_MFMA(1)
    if (pf) { stage1(nb, g + 2, 4); stage1(nb, g + 2, 5); }
    PH_MFMA(2)
    PH_MFMA(3)
  }
#undef PH_MFMA

  if (EPI == 12) {
    float* pk = (blockIdx.z == 0) ? Cf :
                (blockIdx.z == 1) ? (float*)Kh2 :
                (blockIdx.z == 2) ? (float*)Kl2 : (float*)Vh2;
    #pragma unroll
    for (int i = 0; i < 8; ++i) {
      #pragma unroll
      for (int r = 0; r < 4; ++r) {
        const int row = m0 + wm * 128 + i * 16 + fq * 4 + r;
        const size_t ro = (size_t)row * N;
        #pragma unroll
        for (int n = 0; n < 4; ++n) {
          const int col = n0 + wn * 64 + n * 16 + fr;
          pk[ro + col] = acc[i][n][r];
        }
      }
    }
    return;
  }

  float bcol[4];
  #pragma unroll
  for (int n = 0; n < 4; ++n) bcol[n] = bias[n0 + wn * 64 + n * 16 + fr];

  if (EPI == 11) {
    #pragma unroll
    for (int i = 0; i < 8; ++i) {
      #pragma unroll
      for (int r = 0; r < 4; ++r) {
        const int row = m0 + wm * 128 + i * 16 + fq * 4 + r;
        const size_t ro = (size_t)row * N;
        #pragma unroll
        for (int n = 0; n < 4; ++n) {
          const int col = n0 + wn * 64 + n * 16 + fr;
          Ch[ro + col] = bf16_of(gelu_f(acc[i][n][r] + bcol[n]));
        }
      }
    }
    return;
  }

  // EPI == 10: QKV routing. Q -> hi/lo, K -> hi only, V -> transposed hi/lo.
  {
    const int sel = n0 >> 10;
    if (sel < 2) {
      us* dh = (sel == 0) ? Ch : Kh2;
      us* dl = Cl;   // only used when sel == 0
      #pragma unroll
      for (int i = 0; i < 8; ++i) {
        #pragma unroll
        for (int r = 0; r < 4; ++r) {
          const int row = m0 + wm * 128 + i * 16 + fq * 4 + r;
          const size_t ro = (size_t)row * 1024;
          #pragma unroll
          for (int n = 0; n < 4; ++n) {
            const int c10 = (n0 & 1023) + wn * 64 + n * 16 + fr;
            float v = acc[i][n][r] + bcol[n];
            if (sel == 0) {
              us h, l; split_hl(v, h, l);
              dh[ro + c10] = h; dl[ro + c10] = l;
            } else {
              dh[ro + c10] = bf16_of(v);
            }
          }
        }
      }
    } else {
      #pragma unroll
      for (int i = 0; i < 8; ++i) {
        #pragma unroll
        for (int n = 0; n < 4; ++n) {
          const int c10 = (n0 & 1023) + wn * 64 + n * 16 + fr;
          const int hh2 = c10 >> 6, dh = c10 & 63;
          const int row0 = m0 + wm * 128 + i * 16 + fq * 4;
          const int bb = row0 >> 10, ltok = row0 & 1023;
          ushort4 h4, l4;
          float v0 = acc[i][n][0] + bcol[n];
          float v1 = acc[i][n][1] + bcol[n];
          float v2 = acc[i][n][2] + bcol[n];
          float v3 = acc[i][n][3] + bcol[n];
          split_hl(v0, h4.x, l4.x); split_hl(v1, h4.y, l4.y);
          split_hl(v2, h4.z, l4.z); split_hl(v3, h4.w, l4.w);
          const size_t off = ((size_t)(bb * 16 + hh2) * 64 + dh) * L_ + ltok;
          *(ushort4*)&Vh2[off] = h4;
          *(ushort4*)&Vl2[off] = l4;
        }
      }
    }
  }
}

// ---------------------------------------------------------------------------
// MFMA flash attention, 2-term split: QK = Kh x (Qh+Ql), PV = (Vh+Vl) x Ph.
// exp2-domain softmax; K LDS chunk-swizzled (2-way, free); 33 KB LDS ->
// 4 blocks/CU; ctx written bf16-hi only (consumer GEMM is 2-term on A).
// ---------------------------------------------------------------------------
__global__ __launch_bounds__(256, 4)
void attn_mfma(const us* __restrict__ Qh, const us* __restrict__ Ql,
               const us* __restrict__ Kh,
               const us* __restrict__ Vth, const us* __restrict__ Vtl,
               us* __restrict__ Oh) {
  const int raw = blockIdx.x + blockIdx.y * 16;
  const int hh = (raw & 7) + 8 * ((raw >> 3) >> 4);
  const int qq = (raw >> 3) & 15;
  const int b = hh >> 4, h = hh & 15;

  const int t = threadIdx.x;
  const int w = t >> 6, lane = t & 63;
  const int fr = lane & 15, g = lane >> 4;

  __shared__ __align__(16) unsigned char smem[33792];
  us* sK  = (us*)(smem);            // [2][64][32] swizzled, 8 KB
  us* sVh = (us*)(smem + 8192);     // [64][64] chunk-swizzled, 8 KB
  us* sVl = (us*)(smem + 16384);
  us* sP  = (us*)(smem + 24576);    // [4][16][72], 9216 B
  float* fb = (float*)smem;         // epilogue reuse

  const size_t base = ((size_t)b * L_) * D_ + (size_t)h * DH_;
  const int tok0 = b * L_ + qq * 64 + w * 16;
  bf16x8 qfh[2], qfl[2];
  #pragma unroll
  for (int ks = 0; ks < 2; ++ks) {
    const size_t qo = (size_t)(tok0 + fr) * D_ + h * 64 + ks * 32 + g * 8;
    qfh[ks] = *(const bf16x8*)&Qh[qo];
    qfl[ks] = *(const bf16x8*)&Ql[qo];
  }

  const float Cc = 0.18033688011112042f;  // 0.125 * log2(e)
  float m = -INFINITY, l = 0.0f;
  f32x4 ctx[4];
  #pragma unroll
  for (int i = 0; i < 4; ++i) ctx[i] = (f32x4){0.f, 0.f, 0.f, 0.f};
  const int rswk = (g ^ ((fr >> 1) & 3)) * 8;

  for (int kt = 0; kt < 16; ++kt) {
    const int k0 = kt * 64;
    __syncthreads();
    #pragma unroll
    for (int p = 0; p < 2; ++p) {
      const int ci = w * 128 + p * 64 + lane;
      const int db = ci * 8;
      {
        const int ks = ci >> 8, rem = ci & 255, key = rem >> 2, sub = rem & 3;
        const int subp = sub ^ ((key >> 1) & 3);
        glds16(Kh + base + (size_t)(k0 + key) * D_ + ks * 32 + subp * 8, sK + db);
      }
      {
        const int d = ci >> 3, c = ci & 7;
        const size_t src = (size_t)(hh * 64 + d) * L_ + k0 + ((c ^ (d & 7)) * 8);
        glds16(Vth + src, sVh + db);
        glds16(Vtl + src, sVl + db);
      }
    }
    __syncthreads();

    f32x4 accS[4];
    #pragma unroll
    for (int i = 0; i < 4; ++i) accS[i] = (f32x4){0.f, 0.f, 0.f, 0.f};
    #pragma unroll
    for (int ks = 0; ks < 2; ++ks) {
      #pragma unroll
      for (int i = 0; i < 4; ++i) {
        const int ra = (ks * 64 + i * 16 + fr) * 32 + rswk;
        bf16x8 a = *(const bf16x8*)&sK[ra];
        accS[i] = __builtin_amdgcn_mfma_f32_16x16x32_bf16(a, qfh[ks], accS[i], 0, 0, 0);
        accS[i] = __builtin_amdgcn_mfma_f32_16x16x32_bf16(a, qfl[ks], accS[i], 0, 0, 0);
      }
    }

    // online softmax, exp2 domain (identical p-ratios to expf form)
    float p4[4][4];
    float mloc = -INFINITY;
    #pragma unroll
    for (int i = 0; i < 4; ++i)
      #pragma unroll
      for (int r = 0; r < 4; ++r) {
        p4[i][r] = accS[i][r] * Cc;
        mloc = fmaxf(mloc, p4[i][r]);
      }
    mloc = fmaxf(mloc, __shfl_xor(mloc, 16));
    mloc = fmaxf(mloc, __shfl_xor(mloc, 32));
    const float mnew = fmaxf(m, mloc);
    const float alpha = exp2f(m - mnew);
    float lt = 0.f;
    #pragma unroll
    for (int i = 0; i < 4; ++i)
      #pragma unroll
      for (int r = 0; r < 4; ++r) {
        p4[i][r] = exp2f(p4[i][r] - mnew);
        lt += p4[i][r];
      }
    lt += __shfl_xor(lt, 16);
    lt += __shfl_xor(lt, 32);
    l = l * alpha + lt;
    m = mnew;
    #pragma unroll
    for (int i = 0; i < 4; ++i) {
      ctx[i][0] *= alpha; ctx[i][1] *= alpha;
      ctx[i][2] *= alpha; ctx[i][3] *= alpha;
    }

    // pack P (hi only) into per-wave LDS
    #pragma unroll
    for (int i = 0; i < 4; ++i) {
      us h0 = bf16_of(p4[i][0]), h1 = bf16_of(p4[i][1]);
      us h2 = bf16_of(p4[i][2]), h3 = bf16_of(p4[i][3]);
      uint2 hv = {(uint32_t)h0 | ((uint32_t)h1 << 16),
                  (uint32_t)h2 | ((uint32_t)h3 << 16)};
      *(uint2*)&sP[(w * 16 + fr) * 72 + i * 16 + g * 4] = hv;
    }

    // PV: ctx += (Vh+Vl) x Ph
    #pragma unroll
    for (int ks = 0; ks < 2; ++ks) {
      const int pb = (w * 16 + fr) * 72 + ks * 32 + g * 8;
      bf16x8 pa = *(const bf16x8*)&sP[pb];
      #pragma unroll
      for (int i = 0; i < 4; ++i) {
        const int d = i * 16 + fr;
        const int pc = (ks * 4 + g) ^ (d & 7);
        bf16x8 vh = *(const bf16x8*)&sVh[d * 64 + pc * 8];
        bf16x8 vl = *(const bf16x8*)&sVl[d * 64 + pc * 8];
        ctx[i] = __builtin_amdgcn_mfma_f32_16x16x32_bf16(vh, pa, ctx[i], 0, 0, 0);
        ctx[i] = __builtin_amdgcn_mfma_f32_16x16x32_bf16(vl, pa, ctx[i], 0, 0, 0);
      }
    }
  }

  // epilogue: normalize, transpose via LDS, write bf16 hi only
  const float invl = 1.0f / l;
  __syncthreads();
  #pragma unroll
  for (int i = 0; i < 4; ++i)
    #pragma unroll
    for (int r = 0; r < 4; ++r)
      fb[(i * 16 + g * 4 + r) * 64 + w * 16 + fr] = ctx[i][r] * invl;
  __syncthreads();

  {
    const int q = t >> 2, dg = t & 3;
    const size_t ob = (size_t)(b * L_ + qq * 64 + q) * D_ + h * 64;
    #pragma unroll
    for (int u = 0; u < 4; ++u) {
      const int d0 = dg * 16 + u * 4;
      ushort4 h4 = {bf16_of(fb[(d0 + 0) * 64 + q]),
                    bf16_of(fb[(d0 + 1) * 64 + q]),
                    bf16_of(fb[(d0 + 2) * 64 + q]),
                    bf16_of(fb[(d0 + 3) * 64 + q])};
      *(ushort4*)&Oh[ob + d0] = h4;
    }
  }
}

// ---------------------------------------------------------------------------
// LayerNorm over D=1024.  MODE 1: bf16 hi/lo out.
// ---------------------------------------------------------------------------
template<int MODE>
__global__ __launch_bounds__(256)
void layernorm_k(const float* __restrict__ X, const float* __restrict__ g,
                 const float* __restrict__ b, float* __restrict__ Yf,
                 us* __restrict__ Yh, us* __restrict__ Yl) {
  const int row = blockIdx.x;
  const int t = threadIdx.x;
  const float* x = X + (size_t)row * D_;

  float4 v = *(const float4*)&x[t * 4];
  float s  = v.x + v.y + v.z + v.w;
  float ss = v.x * v.x + v.y * v.y + v.z * v.z + v.w * v.w;

  #pragma unroll
  for (int off = 1; off < 64; off <<= 1) {
    s  += __shfl_xor(s, off);
    ss += __shfl_xor(ss, off);
  }
  __shared__ float red[4][2];
  const int wid = t >> 6;
  if ((t & 63) == 0) { red[wid][0] = s; red[wid][1] = ss; }
  __syncthreads();
  s  = red[0][0] + red[1][0] + red[2][0] + red[3][0];
  ss = red[0][1] + red[1][1] + red[2][1] + red[3][1];

  const float mean = s * (1.0f / D_);
  const float var  = ss * (1.0f / D_) - mean * mean;
  const float inv  = rsqrtf(var + 1e-5f);

  float4 gv = *(const float4*)&g[t * 4];
  float4 bv = *(const float4*)&b[t * 4];
  float4 o;
  o.x = (v.x - mean) * inv * gv.x + bv.x;
  o.y = (v.y - mean) * inv * gv.y + bv.y;
  o.z = (v.z - mean) * inv * gv.z + bv.z;
  o.w = (v.w - mean) * inv * gv.w + bv.w;
  if (MODE == 0) {
    *(float4*)&Yf[(size_t)row * D_ + t * 4] = o;
  } else {
    ushort4 h, l;
    split_hl(o.x, h.x, l.x); split_hl(o.y, h.y, l.y);
    split_hl(o.z, h.z, l.z); split_hl(o.w, h.w, l.w);
    *(ushort4*)&Yh[(size_t)row * D_ + t * 4] = h;
    *(ushort4*)&Yl[(size_t)row * D_ + t * 4] = l;
  }
}

// ---------------------------------------------------------------------------
// Split-K reduce (4 planes) + bias + residual(hl) + LN -> f32
// ---------------------------------------------------------------------------
__global__ __launch_bounds__(256)
void lnred4(const float* __restrict__ P0, const float* __restrict__ P1,
            const float* __restrict__ P2, const float* __restrict__ P3,
            const float* __restrict__ b2,
            const us* __restrict__ Rh, const us* __restrict__ Rl,
            const float* __restrict__ g, const float* __restrict__ be,
            float* __restrict__ Y) {
  const int row = blockIdx.x;
  const int t = threadIdx.x;
  const size_t o = (size_t)row * D_ + t * 4;

  float4 v0 = *(const float4*)&P0[o];
  float4 v1 = *(const float4*)&P1[o];
  float4 v2 = *(const float4*)&P2[o];
  float4 v3 = *(const float4*)&P3[o];
  float4 bb = *(const float4*)&b2[t * 4];
  ushort4 rh = *(const ushort4*)&Rh[o];
  ushort4 rl = *(const ushort4*)&Rl[o];
  float4 v;
  v.x = v0.x + v1.x + v2.x + v3.x + bb.x + f32_of(rh.x) + f32_of(rl.x);
  v.y = v0.y + v1.y + v2.y + v3.y + bb.y + f32_of(rh.y) + f32_of(rl.y);
  v.z = v0.z + v1.z + v2.z + v3.z + bb.z + f32_of(rh.z) + f32_of(rl.z);
  v.w = v0.w + v1.w + v2.w + v3.w + bb.w + f32_of(rh.w) + f32_of(rl.w);

  float s  = v.x + v.y + v.z + v.w;
  float ss = v.x * v.x + v.y * v.y + v.z * v.z + v.w * v.w;
  #pragma unroll
  for (int off = 1; off < 64; off <<= 1) {
    s  += __shfl_xor(s, off);
    ss += __shfl_xor(ss, off);
  }
  __shared__ float red[4][2];
  const int wid = t >> 6;
  if ((t & 63) == 0) { red[wid][0] = s; red[wid][1] = ss; }
  __syncthreads();
  s  = red[0][0] + red[1][0] + red[2][0] + red[3][0];
  ss = red[0][1] + red[1][1] + red[2][1] + red[3][1];

  const float mean = s * (1.0f / D_);
  const float var  = ss * (1.0f / D_) - mean * mean;
  const float inv  = rsqrtf(var + 1e-5f);

  float4 gv = *(const float4*)&g[t * 4];
  float4 bv = *(const float4*)&be[t * 4];
  float4 y;
  y.x = (v.x - mean) * inv * gv.x + bv.x;
  y.y = (v.y - mean) * inv * gv.y + bv.y;
  y.z = (v.z - mean) * inv * gv.z + bv.z;
  y.w = (v.w - mean) * inv * gv.w + bv.w;
  *(float4*)&Y[o] = y;
}

// ---------------------------------------------------------------------------
// Fused adapter: gate + top-2 + softmax + 2-expert R->D + residual combine.
// ---------------------------------------------------------------------------
__global__ __launch_bounds__(256)
void adapter_combine_hl(const us* __restrict__ Xh, const us* __restrict__ Xl,
                        const float* __restrict__ Hall,
                        const float* __restrict__ Lout,
                        const us* __restrict__ W2b,
                        const float* __restrict__ B2,
                        const float* __restrict__ GW,
                        const float* __restrict__ GB,
                        float* __restrict__ Out) {
  const int tok = blockIdx.x;
  const int t = threadIdx.x;

  __shared__ float xs[D_];
  __shared__ float part[256];
  __shared__ float logit_s[E_];
  __shared__ float hs[2 * R_];
  __shared__ int   e_sh[2];
  __shared__ float g_sh[2];

  {
    ushort4 h = *(const ushort4*)&Xh[(size_t)tok * D_ + t * 4];
    ushort4 l = *(const ushort4*)&Xl[(size_t)tok * D_ + t * 4];
    xs[t * 4 + 0] = f32_of(h.x) + f32_of(l.x);
    xs[t * 4 + 1] = f32_of(h.y) + f32_of(l.y);
    xs[t * 4 + 2] = f32_of(h.z) + f32_of(l.z);
    xs[t * 4 + 3] = f32_of(h.w) + f32_of(l.w);
  }
  __syncthreads();

  {
    const int e = t & 7, seg = t >> 3;
    float p = 0.f;
    #pragma unroll 8
    for (int i = 0; i < 32; ++i) {
      const int d = seg * 32 + i;
      p = fmaf(xs[d], GW[d * E_ + e], p);
    }
    part[t] = p;
  }
  __syncthreads();
  if (t < E_) {
    float s = GB[t];
    for (int sg = 0; sg < 32; ++sg) s += part[sg * 8 + t];
    logit_s[t] = s;
  }
  __syncthreads();
  if (t == 0) {
    int e1 = 0; float v1 = logit_s[0];
    for (int i = 1; i < E_; ++i) if (logit_s[i] > v1) { v1 = logit_s[i]; e1 = i; }
    int e2 = -1; float v2 = -INFINITY;
    for (int i = 0; i < E_; ++i) if (i != e1 && logit_s[i] > v2) { v2 = logit_s[i]; e2 = i; }
    const float ee = expf(v2 - v1);
    const float den = 1.0f + ee;
    g_sh[0] = 1.0f / den; g_sh[1] = ee / den;
    e_sh[0] = e1; e_sh[1] = e2;
  }
  __syncthreads();
  const int e1 = e_sh[0], e2 = e_sh[1];
  const float g1 = g_sh[0], g2 = g_sh[1];

  if (t < 2 * R_) {
    const int ex = (t < R_) ? e1 : e2;
    const int r = t & (R_ - 1);
    hs[t] = Hall[(size_t)tok * (E_ * R_) + ex * R_ + r];
  }
  __syncthreads();

  const int d = t * 4;
  float4 b1v = *(const float4*)&B2[e1 * D_ + d];
  float4 b2v = *(const float4*)&B2[e2 * D_ + d];
  float4 acc;
  acc.x = g1 * b1v.x + g2 * b2v.x;
  acc.y = g1 * b1v.y + g2 * b2v.y;
  acc.z = g1 * b1v.z + g2 * b2v.z;
  acc.w = g1 * b1v.w + g2 * b2v.w;

  #pragma unroll 8
  for (int r = 0; r < R_; ++r) {
    const float f = g1 * hs[r];
    ushort4 w = *(const ushort4*)&W2b[((size_t)e1 * R_ + r) * D_ + d];
    acc.x = fmaf(f, f32_of(w.x), acc.x); acc.y = fmaf(f, f32_of(w.y), acc.y);
    acc.z = fmaf(f, f32_of(w.z), acc.z); acc.w = fmaf(f, f32_of(w.w), acc.w);
  }
  #pragma unroll 8
  for (int r = 0; r < R_; ++r) {
    const float f = g2 * hs[R_ + r];
    ushort4 w = *(const ushort4*)&W2b[((size_t)e2 * R_ + r) * D_ + d];
    acc.x = fmaf(f, f32_of(w.x), acc.x); acc.y = fmaf(f, f32_of(w.y), acc.y);
    acc.z = fmaf(f, f32_of(w.z), acc.z); acc.w = fmaf(f, f32_of(w.w), acc.w);
  }

  float4 lo = *(const float4*)&Lout[(size_t)tok * D_ + d];
  float4 o = {lo.x + 2.0f * acc.x, lo.y + 2.0f * acc.y,
              lo.z + 2.0f * acc.z, lo.w + 2.0f * acc.w};
  *(float4*)&Out[(size_t)tok * D_ + d] = o;
}

// ---------------------------------------------------------------------------
extern "C" void kernel_launch(void* const* d_in, const int* in_sizes, int n_in,
                              void* d_out, int out_size, void* d_ws, size_t ws_size,
                              hipStream_t stream) {
  const float* x     = (const float*)d_in[0];
  const float* wq    = (const float*)d_in[1];
  const float* wk    = (const float*)d_in[2];
  const float* wv    = (const float*)d_in[3];
  const float* wo    = (const float*)d_in[4];
  const float* bq    = (const float*)d_in[5];
  const float* bk    = (const float*)d_in[6];
  const float* bv    = (const float*)d_in[7];
  const float* bo    = (const float*)d_in[8];
  const float* ln1g  = (const float*)d_in[9];
  const float* ln1b  = (const float*)d_in[10];
  const float* w1    = (const float*)d_in[11];
  const float* b1    = (const float*)d_in[12];
  const float* w2    = (const float*)d_in[13];
  const float* b2    = (const float*)d_in[14];
  const float* ln2g  = (const float*)d_in[15];
  const float* ln2b  = (const float*)d_in[16];
  const float* aw1   = (const float*)d_in[17];
  const float* ab1   = (const float*)d_in[18];
  const float* aw2   = (const float*)d_in[19];
  const float* ab2   = (const float*)d_in[20];
  const float* gw    = (const float*)d_in[21];
  const float* gb    = (const float*)d_in[22];
  float* out = (float*)d_out;

  char* base = (char*)d_ws;
  const size_t MB = 1ull << 20;

  // weights (persistent)
  us* qkvTh = (us*)(base + 0 * MB);  us* qkvTl = (us*)(base + 6 * MB);
  us* woTh  = (us*)(base + 12 * MB); us* woTl  = (us*)(base + 14 * MB);
  us* w1Th  = (us*)(base + 16 * MB); us* w1Tl  = (us*)(base + 24 * MB);
  us* w2Th  = (us*)(base + 32 * MB); us* w2Tl  = (us*)(base + 40 * MB);
  us* a1Th  = (us*)(base + 48 * MB); us* a1Tl  = (us*)(base + 49 * MB);
  us* w2b   = (us*)(base + 50 * MB);
  float* bqkv = (float*)(base + 51 * MB);
  // activations
  us* xh   = (us*)(base + 52 * MB);
  us* ctxh = (us*)(base + 52 * MB);
  us* qbh  = (us*)(base + 68 * MB);  us* qbl  = (us*)(base + 76 * MB);
  us* kbh  = (us*)(base + 84 * MB);
  us* vth  = (us*)(base + 100 * MB); us* vtl  = (us*)(base + 108 * MB);
  float* ATTNPRE = (float*)(base + 68 * MB);              // q dead after attn
  us* aoh  = (us*)(base + 84 * MB);  us* aol  = (us*)(base + 92 * MB);
  us* inth = (us*)(base + 116 * MB);                      // 32 MB
  float* P0 = (float*)(base + 52 * MB);
  float* P1 = (float*)(base + 68 * MB);
  float* P2 = (float*)(base + 100 * MB);
  float* P3 = (float*)(base + 148 * MB);
  float* LOUT = P0;
  float* HALL = (float*)(base + 68 * MB);

  const dim3 blk(256);
  const us* nu = nullptr;
  const float* nf = nullptr;

  // --- precompute splits ---
  fhi<<<dim3(NTOK * D_ / 1024), blk, 0, stream>>>(x, xh, NTOK * D_ / 4);
  wsplit_t<<<dim3(16, 16), blk, 0, stream>>>(wq, qkvTh, qkvTl, D_, D_);
  wsplit_t<<<dim3(16, 16), blk, 0, stream>>>(wk, qkvTh + 1024 * 1024, qkvTl + 1024 * 1024, D_, D_);
  wsplit_t<<<dim3(16, 16), blk, 0, stream>>>(wv, qkvTh + 2048 * 1024, qkvTl + 2048 * 1024, D_, D_);
  wsplit_t<<<dim3(16, 16), blk, 0, stream>>>(wo, woTh, woTl, D_, D_);
  wsplit_t<<<dim3(64, 16), blk, 0, stream>>>(w1, w1Th, w1Tl, D_, FF_);
  wsplit_t<<<dim3(16, 64), blk, 0, stream>>>(w2, w2Th, w2Tl, FF_, D_);
  wsplit_t<<<dim3(8, 16),  blk, 0, stream>>>(aw1, a1Th, a1Tl, D_, E_ * R_);
  fhi<<<dim3(E_ * R_ * D_ / 1024), blk, 0, stream>>>(aw2, w2b, E_ * R_ * D_ / 4);
  bconcat<<<dim3(12), blk, 0, stream>>>(bq, bk, bv, bqkv);

  // --- fused QKV projection: Q hl, K h, V transposed hl ---
  gemm256<10><<<dim3(12, 16), dim3(512), 0, stream>>>(
      xh, qkvTh, qkvTl, bqkv, nullptr, qbh, qbl, kbh, nullptr, vth, vtl,
      NTOK, 3072, D_, D_);
  // --- attention (2-term): ctx -> bf16 hi ---
  attn_mfma<<<dim3(16, 64), blk, 0, stream>>>(qbh, qbl, kbh, vth, vtl, ctxh);
  // --- output projection (2-term) + residual(x), LN1 -> AO hi/lo ---
  gemm128<2><<<dim3(8, 32), blk, 0, stream>>>(ctxh, woTh, woTl, bo, x,
                                              ATTNPRE, NTOK, D_, D_);
  layernorm_k<1><<<dim3(NTOK), blk, 0, stream>>>(ATTNPRE, ln1g, ln1b, nullptr, aoh, aol);
  // --- FFN1 (2-term, gelu -> bf16 hi) ---
  gemm256<11><<<dim3(16, 16), dim3(512), 0, stream>>>(
      aoh, w1Th, w1Tl, b1, nullptr, inth, nullptr, nullptr, nullptr, nullptr, nullptr,
      NTOK, FF_, D_, D_);
  // --- FFN2 (split-K=4) + fused reduce+LN2 ---
  gemm256<12><<<dim3(4, 16, 4), dim3(512), 0, stream>>>(
      inth, w2Th, w2Tl, nf, P0, nullptr, nullptr, (us*)P1, (us*)P2, (us*)P3, nullptr,
      NTOK, D_, FF_, 1024);
  lnred4<<<dim3(NTOK), blk, 0, stream>>>(P0, P1, P2, P3, b2, aoh, aol, ln2g, ln2b, LOUT);
  // --- adapter ---
  gemm128<1><<<dim3(4, 32), blk, 0, stream>>>(aoh, a1Th, a1Tl, ab1, nf,
                                              HALL, NTOK, E_ * R_, D_);
  adapter_combine_hl<<<dim3(NTOK), blk, 0, stream>>>(aoh, aol, HALL, LOUT, w2b, ab2, gw, gb, out);
}

// Round 7
// 536.209 us; speedup vs baseline: 4.1617x; 1.0655x over previous
//
#include <hip/hip_runtime.h>
#include <cstddef>
#include <cstdint>

#define B_   4
#define L_   1024
#define D_   1024
#define H_   16
#define DH_  64
#define E_   8
#define R_   64
#define FF_  4096
#define NTOK (B_ * L_)   // 4096
#define KADP 576         // 512 h-cols + 8 gate-cols + 56 zero pad

typedef __attribute__((ext_vector_type(8))) short bf16x8;
typedef __attribute__((ext_vector_type(4))) float f32x4;
typedef unsigned short us;

__device__ __forceinline__ float gelu_f(float x) {
  return 0.5f * x * (1.0f + erff(x * 0.7071067811865476f));
}

__device__ __forceinline__ us bf16_of(float f) {
  union { float f; uint32_t u; } x; x.f = f;
  uint32_t r = x.u + 0x7FFFu + ((x.u >> 16) & 1u);   // RNE
  return (us)(r >> 16);
}
__device__ __forceinline__ float f32_of(us h) {
  union { uint32_t u; float f; } x; x.u = ((uint32_t)h) << 16;
  return x.f;
}
__device__ __forceinline__ void split_hl(float v, us& hi, us& lo) {
  hi = bf16_of(v);
  lo = bf16_of(v - f32_of(hi));
}

__device__ __forceinline__ void glds16(const void* g, const void* l) {
  __builtin_amdgcn_global_load_lds(
      (const __attribute__((address_space(1))) unsigned int*)g,
      (__attribute__((address_space(3))) unsigned int*)l, 16, 0, 0);
}

// ---------------------------------------------------------------------------
// fp32 -> bf16 (hi only)
// ---------------------------------------------------------------------------
__global__ __launch_bounds__(256)
void fhi(const float* __restrict__ X, us* __restrict__ Hh, int n4) {
  int i = blockIdx.x * 256 + threadIdx.x;
  if (i >= n4) return;
  float4 v = ((const float4*)X)[i];
  ushort4 h = {bf16_of(v.x), bf16_of(v.y), bf16_of(v.z), bf16_of(v.w)};
  ((ushort4*)Hh)[i] = h;
}

// concat 3 x [1024] biases -> [3072]
__global__ __launch_bounds__(256)
void bconcat(const float* __restrict__ a, const float* __restrict__ b,
             const float* __restrict__ c, float* __restrict__ o) {
  int i = blockIdx.x * 256 + threadIdx.x;
  if (i >= 3072) return;
  o[i] = (i < 1024) ? a[i] : (i < 2048 ? b[i - 1024] : c[i - 2048]);
}

// build Bflat[576,1024] f32 = [aw2 (512 rows); ab2 (8 rows); zeros (56 rows)]
__global__ __launch_bounds__(256)
void bflat_fill(const float* __restrict__ aw2, const float* __restrict__ ab2,
                float* __restrict__ Bf) {
  int i = blockIdx.x * 256 + threadIdx.x;   // float4 index
  if (i >= KADP * 1024 / 4) return;
  const int row = i >> 8;                   // 256 float4 per row
  float4 v;
  if (row < 512)      v = ((const float4*)aw2)[i];
  else if (row < 520) v = ((const float4*)ab2)[i - 512 * 256];
  else                v = (float4){0.f, 0.f, 0.f, 0.f};
  ((float4*)Bf)[i] = v;
}

// ---------------------------------------------------------------------------
// Weight split+transpose: W[K,N] fp32 -> Th,Tl [N,K] bf16.
// ---------------------------------------------------------------------------
__global__ __launch_bounds__(256)
void wsplit_t(const float* __restrict__ W, us* __restrict__ Th,
              us* __restrict__ Tl, int K, int N) {
  __shared__ float tile[64][65];
  const int k0 = blockIdx.y * 64, n0 = blockIdx.x * 64;
  const int t = threadIdx.x;
  const int r = t >> 4, c4 = (t & 15) * 4;
  #pragma unroll
  for (int p = 0; p < 4; ++p) {
    const int k = r + p * 16;
    *(float4*)&tile[k][c4] = *(const float4*)&W[(size_t)(k0 + k) * N + n0 + c4];
  }
  __syncthreads();
  #pragma unroll
  for (int p = 0; p < 4; ++p) {
    const int n = r + p * 16;
    float v0 = tile[c4 + 0][n], v1 = tile[c4 + 1][n];
    float v2 = tile[c4 + 2][n], v3 = tile[c4 + 3][n];
    ushort4 h, l;
    split_hl(v0, h.x, l.x); split_hl(v1, h.y, l.y);
    split_hl(v2, h.z, l.z); split_hl(v3, h.w, l.w);
    const size_t o = (size_t)(n0 + n) * K + k0 + c4;
    *(ushort4*)&Th[o] = h;
    *(ushort4*)&Tl[o] = l;
  }
}

// ---------------------------------------------------------------------------
// 128x128 2-term GEMM, triple-buffered deep pipeline (counted vmcnt(6)).
// C = epi(A_bf16[M,K] @ (Bh+Bl)^T[N,K] + bias)
// EPI: 1 bias+gelu->f32 | 2 bias+resF->f32 | 3 resF + 2*acc -> f32 (no bias)
// ---------------------------------------------------------------------------
template<int EPI>
__global__ __launch_bounds__(256, 2)
void gemm128(const us* __restrict__ Ah,
             const us* __restrict__ Bh, const us* __restrict__ Bl,
             const float* __restrict__ bias, const float* __restrict__ ResF,
             float* __restrict__ Cf, int M, int N, int K) {
  __shared__ us sm3[3][3][4096];   // [buf][A,Bh,Bl][128*32] 72 KB

  const int t = threadIdx.x;
  const int lane = t & 63, wid = t >> 6;
  const int wm = wid >> 1, wn = wid & 1;
  const int fr = lane & 15, fq = lane >> 4;
  const int rsw8 = (fq ^ ((fr >> 1) & 3)) * 8;

  const int nx = N >> 7;
  const int idl = blockIdx.x + blockIdx.y * nx;
  const int xcd = idl & 7, jj = idl >> 3;
  const int band = (M >> 7) >> 3;
  const int m0 = (xcd * band + (jj % band)) << 7;
  const int n0 = (jj / band) << 7;

  const int srow = t >> 2;          // 0..63
  const int gsub = t & 3;

  auto stage1 = [&](int buf, int kt, int idx) {
    const int stream = idx >> 1;    // 0:A 1:Bh 2:Bl
    const int half = idx & 1;
    const us* gp = (stream == 0) ? Ah : (stream == 1 ? Bh : Bl);
    const int row = half * 64 + srow;
    const int gchunk = gsub ^ ((row >> 1) & 3);
    const int rbase = ((stream == 0) ? m0 : n0) + row;
    const size_t g = (size_t)rbase * K + kt * 32 + gchunk * 8;
    glds16(gp + g, &sm3[buf][stream][row * 32 + gsub * 8]);
  };

  f32x4 acc[4][4];
  #pragma unroll
  for (int i = 0; i < 4; ++i)
    #pragma unroll
    for (int n = 0; n < 4; ++n) acc[i][n] = (f32x4){0.f, 0.f, 0.f, 0.f};

  #pragma unroll
  for (int idx = 0; idx < 6; ++idx) stage1(0, 0, idx);
  #pragma unroll
  for (int idx = 0; idx < 6; ++idx) stage1(1, 1, idx);

  const int nt = K >> 5;
  for (int g = 0; g < nt; ++g) {
    const int cb = g % 3;
    if (g < nt - 1) { asm volatile("s_waitcnt vmcnt(6)" ::: "memory"); }
    else            { asm volatile("s_waitcnt vmcnt(0)" ::: "memory"); }
    __builtin_amdgcn_sched_barrier(0);
    __builtin_amdgcn_s_barrier();
    __builtin_amdgcn_sched_barrier(0);

    const us* sA   = sm3[cb][0];
    const us* sBh_ = sm3[cb][1];
    const us* sBl_ = sm3[cb][2];

    bf16x8 bh[4], bl[4], av[4];
    #pragma unroll
    for (int n = 0; n < 4; ++n) {
      const int rb = (wn * 64 + n * 16 + fr) * 32 + rsw8;
      bh[n] = *(const bf16x8*)&sBh_[rb];
      bl[n] = *(const bf16x8*)&sBl_[rb];
    }
    #pragma unroll
    for (int i = 0; i < 4; ++i)
      av[i] = *(const bf16x8*)&sA[(wm * 64 + i * 16 + fr) * 32 + rsw8];

    const bool pf = (g + 2 < nt);
    const int nb = (g + 2) % 3;

    #pragma unroll
    for (int i = 0; i < 4; ++i) {
      if (pf && i < 3) { stage1(nb, g + 2, 2 * i); stage1(nb, g + 2, 2 * i + 1); }
      if (i == 0) {
        asm volatile("s_waitcnt lgkmcnt(0)" ::: "memory");
        __builtin_amdgcn_sched_barrier(0);
      }
      __builtin_amdgcn_s_setprio(1);
      #pragma unroll
      for (int n = 0; n < 4; ++n) {
        acc[i][n] = __builtin_amdgcn_mfma_f32_16x16x32_bf16(av[i], bh[n], acc[i][n], 0, 0, 0);
        acc[i][n] = __builtin_amdgcn_mfma_f32_16x16x32_bf16(av[i], bl[n], acc[i][n], 0, 0, 0);
      }
      __builtin_amdgcn_s_setprio(0);
    }
  }

  float bcol[4];
  if (EPI != 3) {
    #pragma unroll
    for (int n = 0; n < 4; ++n) bcol[n] = bias[n0 + wn * 64 + n * 16 + fr];
  }

  #pragma unroll
  for (int i = 0; i < 4; ++i) {
    #pragma unroll
    for (int r = 0; r < 4; ++r) {
      const int row = m0 + wm * 64 + i * 16 + fq * 4 + r;
      const size_t ro = (size_t)row * N;
      #pragma unroll
      for (int n = 0; n < 4; ++n) {
        const int col = n0 + wn * 64 + n * 16 + fr;
        if (EPI == 1) {
          Cf[ro + col] = gelu_f(acc[i][n][r] + bcol[n]);
        } else if (EPI == 2) {
          Cf[ro + col] = acc[i][n][r] + bcol[n] + ResF[ro + col];
        } else {  // EPI == 3: adapter combine: out = Lout + 2*acc
          Cf[ro + col] = ResF[ro + col] + 2.0f * acc[i][n][r];
        }
      }
    }
  }
}

// ---------------------------------------------------------------------------
// 256x256 2-term GEMM, triple-buffered deep pipeline.
// EPI: 10 QKV routing | 11 bias+gelu->bf16hi | 12 raw f32 split-K plane
// ---------------------------------------------------------------------------
template<int EPI>
__global__ __launch_bounds__(512, 2)
void gemm256(const us* __restrict__ Ah,
             const us* __restrict__ Bh, const us* __restrict__ Bl,
             const float* __restrict__ bias,
             float* __restrict__ Cf, us* __restrict__ Ch, us* __restrict__ Cl,
             us* __restrict__ Kh2, us* __restrict__ Kl2,
             us* __restrict__ Vh2, us* __restrict__ Vl2,
             int M, int N, int Kfull, int klen) {
  __shared__ us sm3[3][3][8192];   // 144 KB

  const int t = threadIdx.x;
  const int lane = t & 63, wid = t >> 6;
  const int wm = wid >> 2, wn = wid & 3;
  const int fr = lane & 15, fq = lane >> 4;
  const int rsw8 = (fq ^ ((fr >> 1) & 3)) * 8;

  const int nx = N >> 8;
  const int idl = blockIdx.x + blockIdx.y * nx;
  const int xcd = idl & 7, jj = idl >> 3;
  const int band = (M >> 8) >> 3;
  const int m0 = (xcd * band + (jj % band)) << 8;
  const int n0 = (jj / band) << 8;
  const int koff = blockIdx.z * klen;

  const int srow = t >> 2;
  const int gchunk = (t & 3) ^ ((t >> 3) & 3);
  const int dso = srow * 32 + (t & 3) * 8;

  auto stage1 = [&](int buf, int kt, int idx) {
    const int stream = idx >> 1;
    const int half = idx & 1;
    const us* gp = (stream == 0) ? Ah : (stream == 1 ? Bh : Bl);
    const int rbase = ((stream == 0) ? m0 : n0) + half * 128 + srow;
    const size_t g = (size_t)rbase * Kfull + koff + kt * 32 + gchunk * 8;
    glds16(gp + g, &sm3[buf][stream][half * 4096 + dso]);
  };

  f32x4 acc[8][4];
  #pragma unroll
  for (int i = 0; i < 8; ++i)
    #pragma unroll
    for (int n = 0; n < 4; ++n) acc[i][n] = (f32x4){0.f, 0.f, 0.f, 0.f};

  #pragma unroll
  for (int idx = 0; idx < 6; ++idx) stage1(0, 0, idx);
  #pragma unroll
  for (int idx = 0; idx < 6; ++idx) stage1(1, 1, idx);

  const int nt = klen >> 5;
  bf16x8 bhf[4], blf[4];

#define PH_MFMA(qq)                                                              \
  {                                                                              \
    bf16x8 a0 = *(const bf16x8*)&sm3[cb][0][(wm * 128 + (2*qq) * 16 + fr) * 32 + rsw8];   \
    bf16x8 a1 = *(const bf16x8*)&sm3[cb][0][(wm * 128 + (2*qq+1) * 16 + fr) * 32 + rsw8]; \
    asm volatile("s_waitcnt lgkmcnt(0)" ::: "memory");                           \
    __builtin_amdgcn_sched_barrier(0);                                           \
    __builtin_amdgcn_s_setprio(1);                                               \
    _Pragma("unroll")                                                            \
    for (int n = 0; n < 4; ++n) {                                                \
      acc[2*qq][n]   = __builtin_amdgcn_mfma_f32_16x16x32_bf16(a0, bhf[n], acc[2*qq][n], 0,0,0);   \
      acc[2*qq][n]   = __builtin_amdgcn_mfma_f32_16x16x32_bf16(a0, blf[n], acc[2*qq][n], 0,0,0);   \
      acc[2*qq+1][n] = __builtin_amdgcn_mfma_f32_16x16x32_bf16(a1, bhf[n], acc[2*qq+1][n], 0,0,0); \
      acc[2*qq+1][n] = __builtin_amdgcn_mfma_f32_16x16x32_bf16(a1, blf[n], acc[2*qq+1][n], 0,0,0); \
    }                                                                            \
    __builtin_amdgcn_s_setprio(0);                                               \
  }

  for (int g = 0; g < nt; ++g) {
    const int cb = g % 3;
    if (g < nt - 1) { asm volatile("s_waitcnt vmcnt(6)" ::: "memory"); }
    else            { asm volatile("s_waitcnt vmcnt(0)" ::: "memory"); }
    __builtin_amdgcn_sched_barrier(0);
    __builtin_amdgcn_s_barrier();
    __builtin_amdgcn_sched_barrier(0);
    #pragma unroll
    for (int n = 0; n < 4; ++n) {
      const int rb = (wn * 64 + n * 16 + fr) * 32 + rsw8;
      bhf[n] = *(const bf16x8*)&sm3[cb][1][rb];
      blf[n] = *(const bf16x8*)&sm3[cb][2][rb];
    }
    const bool pf = (g + 2 < nt);
    const int nb = (g + 2) % 3;
    if (pf) { stage1(nb, g + 2, 0); stage1(nb, g + 2, 1); }
    PH_MFMA(0)
    if (pf) { stage1(nb, g + 2, 2); stage1(nb, g + 2, 3); }
    PH_MFMA(1)
    if (pf) { stage1(nb, g + 2, 4); stage1(nb, g + 2, 5); }
    PH_MFMA(2)
    PH_MFMA(3)
  }
#undef PH_MFMA

  if (EPI == 12) {
    float* pk = (blockIdx.z == 0) ? Cf :
                (blockIdx.z == 1) ? (float*)Kh2 :
                (blockIdx.z == 2) ? (float*)Kl2 : (float*)Vh2;
    #pragma unroll
    for (int i = 0; i < 8; ++i) {
      #pragma unroll
      for (int r = 0; r < 4; ++r) {
        const int row = m0 + wm * 128 + i * 16 + fq * 4 + r;
        const size_t ro = (size_t)row * N;
        #pragma unroll
        for (int n = 0; n < 4; ++n) {
          const int col = n0 + wn * 64 + n * 16 + fr;
          pk[ro + col] = acc[i][n][r];
        }
      }
    }
    return;
  }

  float bcol[4];
  #pragma unroll
  for (int n = 0; n < 4; ++n) bcol[n] = bias[n0 + wn * 64 + n * 16 + fr];

  if (EPI == 11) {
    #pragma unroll
    for (int i = 0; i < 8; ++i) {
      #pragma unroll
      for (int r = 0; r < 4; ++r) {
        const int row = m0 + wm * 128 + i * 16 + fq * 4 + r;
        const size_t ro = (size_t)row * N;
        #pragma unroll
        for (int n = 0; n < 4; ++n) {
          const int col = n0 + wn * 64 + n * 16 + fr;
          Ch[ro + col] = bf16_of(gelu_f(acc[i][n][r] + bcol[n]));
        }
      }
    }
    return;
  }

  // EPI == 10: QKV routing. Q -> hi/lo, K -> hi only, V -> transposed hi/lo.
  {
    const int sel = n0 >> 10;
    if (sel < 2) {
      us* dh = (sel == 0) ? Ch : Kh2;
      us* dl = Cl;
      #pragma unroll
      for (int i = 0; i < 8; ++i) {
        #pragma unroll
        for (int r = 0; r < 4; ++r) {
          const int row = m0 + wm * 128 + i * 16 + fq * 4 + r;
          const size_t ro = (size_t)row * 1024;
          #pragma unroll
          for (int n = 0; n < 4; ++n) {
            const int c10 = (n0 & 1023) + wn * 64 + n * 16 + fr;
            float v = acc[i][n][r] + bcol[n];
            if (sel == 0) {
              us h, l; split_hl(v, h, l);
              dh[ro + c10] = h; dl[ro + c10] = l;
            } else {
              dh[ro + c10] = bf16_of(v);
            }
          }
        }
      }
    } else {
      #pragma unroll
      for (int i = 0; i < 8; ++i) {
        #pragma unroll
        for (int n = 0; n < 4; ++n) {
          const int c10 = (n0 & 1023) + wn * 64 + n * 16 + fr;
          const int hh2 = c10 >> 6, dh = c10 & 63;
          const int row0 = m0 + wm * 128 + i * 16 + fq * 4;
          const int bb = row0 >> 10, ltok = row0 & 1023;
          ushort4 h4, l4;
          float v0 = acc[i][n][0] + bcol[n];
          float v1 = acc[i][n][1] + bcol[n];
          float v2 = acc[i][n][2] + bcol[n];
          float v3 = acc[i][n][3] + bcol[n];
          split_hl(v0, h4.x, l4.x); split_hl(v1, h4.y, l4.y);
          split_hl(v2, h4.z, l4.z); split_hl(v3, h4.w, l4.w);
          const size_t off = ((size_t)(bb * 16 + hh2) * 64 + dh) * L_ + ltok;
          *(ushort4*)&Vh2[off] = h4;
          *(ushort4*)&Vl2[off] = l4;
        }
      }
    }
  }
}

// ---------------------------------------------------------------------------
// MFMA flash attention (unchanged from round 6, verified)
// ---------------------------------------------------------------------------
__global__ __launch_bounds__(256, 4)
void attn_mfma(const us* __restrict__ Qh, const us* __restrict__ Ql,
               const us* __restrict__ Kh,
               const us* __restrict__ Vth, const us* __restrict__ Vtl,
               us* __restrict__ Oh) {
  const int raw = blockIdx.x + blockIdx.y * 16;
  const int hh = (raw & 7) + 8 * ((raw >> 3) >> 4);
  const int qq = (raw >> 3) & 15;
  const int b = hh >> 4, h = hh & 15;

  const int t = threadIdx.x;
  const int w = t >> 6, lane = t & 63;
  const int fr = lane & 15, g = lane >> 4;

  __shared__ __align__(16) unsigned char smem[33792];
  us* sK  = (us*)(smem);
  us* sVh = (us*)(smem + 8192);
  us* sVl = (us*)(smem + 16384);
  us* sP  = (us*)(smem + 24576);
  float* fb = (float*)smem;

  const size_t base = ((size_t)b * L_) * D_ + (size_t)h * DH_;
  const int tok0 = b * L_ + qq * 64 + w * 16;
  bf16x8 qfh[2], qfl[2];
  #pragma unroll
  for (int ks = 0; ks < 2; ++ks) {
    const size_t qo = (size_t)(tok0 + fr) * D_ + h * 64 + ks * 32 + g * 8;
    qfh[ks] = *(const bf16x8*)&Qh[qo];
    qfl[ks] = *(const bf16x8*)&Ql[qo];
  }

  const float Cc = 0.18033688011112042f;  // 0.125 * log2(e)
  float m = -INFINITY, l = 0.0f;
  f32x4 ctx[4];
  #pragma unroll
  for (int i = 0; i < 4; ++i) ctx[i] = (f32x4){0.f, 0.f, 0.f, 0.f};
  const int rswk = (g ^ ((fr >> 1) & 3)) * 8;

  for (int kt = 0; kt < 16; ++kt) {
    const int k0 = kt * 64;
    __syncthreads();
    #pragma unroll
    for (int p = 0; p < 2; ++p) {
      const int ci = w * 128 + p * 64 + lane;
      const int db = ci * 8;
      {
        const int ks = ci >> 8, rem = ci & 255, key = rem >> 2, sub = rem & 3;
        const int subp = sub ^ ((key >> 1) & 3);
        glds16(Kh + base + (size_t)(k0 + key) * D_ + ks * 32 + subp * 8, sK + db);
      }
      {
        const int d = ci >> 3, c = ci & 7;
        const size_t src = (size_t)(hh * 64 + d) * L_ + k0 + ((c ^ (d & 7)) * 8);
        glds16(Vth + src, sVh + db);
        glds16(Vtl + src, sVl + db);
      }
    }
    __syncthreads();

    f32x4 accS[4];
    #pragma unroll
    for (int i = 0; i < 4; ++i) accS[i] = (f32x4){0.f, 0.f, 0.f, 0.f};
    #pragma unroll
    for (int ks = 0; ks < 2; ++ks) {
      #pragma unroll
      for (int i = 0; i < 4; ++i) {
        const int ra = (ks * 64 + i * 16 + fr) * 32 + rswk;
        bf16x8 a = *(const bf16x8*)&sK[ra];
        accS[i] = __builtin_amdgcn_mfma_f32_16x16x32_bf16(a, qfh[ks], accS[i], 0, 0, 0);
        accS[i] = __builtin_amdgcn_mfma_f32_16x16x32_bf16(a, qfl[ks], accS[i], 0, 0, 0);
      }
    }

    float p4[4][4];
    float mloc = -INFINITY;
    #pragma unroll
    for (int i = 0; i < 4; ++i)
      #pragma unroll
      for (int r = 0; r < 4; ++r) {
        p4[i][r] = accS[i][r] * Cc;
        mloc = fmaxf(mloc, p4[i][r]);
      }
    mloc = fmaxf(mloc, __shfl_xor(mloc, 16));
    mloc = fmaxf(mloc, __shfl_xor(mloc, 32));
    const float mnew = fmaxf(m, mloc);
    const float alpha = exp2f(m - mnew);
    float lt = 0.f;
    #pragma unroll
    for (int i = 0; i < 4; ++i)
      #pragma unroll
      for (int r = 0; r < 4; ++r) {
        p4[i][r] = exp2f(p4[i][r] - mnew);
        lt += p4[i][r];
      }
    lt += __shfl_xor(lt, 16);
    lt += __shfl_xor(lt, 32);
    l = l * alpha + lt;
    m = mnew;
    #pragma unroll
    for (int i = 0; i < 4; ++i) {
      ctx[i][0] *= alpha; ctx[i][1] *= alpha;
      ctx[i][2] *= alpha; ctx[i][3] *= alpha;
    }

    #pragma unroll
    for (int i = 0; i < 4; ++i) {
      us h0 = bf16_of(p4[i][0]), h1 = bf16_of(p4[i][1]);
      us h2 = bf16_of(p4[i][2]), h3 = bf16_of(p4[i][3]);
      uint2 hv = {(uint32_t)h0 | ((uint32_t)h1 << 16),
                  (uint32_t)h2 | ((uint32_t)h3 << 16)};
      *(uint2*)&sP[(w * 16 + fr) * 72 + i * 16 + g * 4] = hv;
    }

    #pragma unroll
    for (int ks = 0; ks < 2; ++ks) {
      const int pb = (w * 16 + fr) * 72 + ks * 32 + g * 8;
      bf16x8 pa = *(const bf16x8*)&sP[pb];
      #pragma unroll
      for (int i = 0; i < 4; ++i) {
        const int d = i * 16 + fr;
        const int pc = (ks * 4 + g) ^ (d & 7);
        bf16x8 vh = *(const bf16x8*)&sVh[d * 64 + pc * 8];
        bf16x8 vl = *(const bf16x8*)&sVl[d * 64 + pc * 8];
        ctx[i] = __builtin_amdgcn_mfma_f32_16x16x32_bf16(vh, pa, ctx[i], 0, 0, 0);
        ctx[i] = __builtin_amdgcn_mfma_f32_16x16x32_bf16(vl, pa, ctx[i], 0, 0, 0);
      }
    }
  }

  const float invl = 1.0f / l;
  __syncthreads();
  #pragma unroll
  for (int i = 0; i < 4; ++i)
    #pragma unroll
    for (int r = 0; r < 4; ++r)
      fb[(i * 16 + g * 4 + r) * 64 + w * 16 + fr] = ctx[i][r] * invl;
  __syncthreads();

  {
    const int q = t >> 2, dg = t & 3;
    const size_t ob = (size_t)(b * L_ + qq * 64 + q) * D_ + h * 64;
    #pragma unroll
    for (int u = 0; u < 4; ++u) {
      const int d0 = dg * 16 + u * 4;
      ushort4 h4 = {bf16_of(fb[(d0 + 0) * 64 + q]),
                    bf16_of(fb[(d0 + 1) * 64 + q]),
                    bf16_of(fb[(d0 + 2) * 64 + q]),
                    bf16_of(fb[(d0 + 3) * 64 + q])};
      *(ushort4*)&Oh[ob + d0] = h4;
    }
  }
}

// ---------------------------------------------------------------------------
// LayerNorm over D=1024 -> bf16 hi/lo out.
// ---------------------------------------------------------------------------
__global__ __launch_bounds__(256)
void layernorm_hl(const float* __restrict__ X, const float* __restrict__ g,
                  const float* __restrict__ b,
                  us* __restrict__ Yh, us* __restrict__ Yl) {
  const int row = blockIdx.x;
  const int t = threadIdx.x;
  const float* x = X + (size_t)row * D_;

  float4 v = *(const float4*)&x[t * 4];
  float s  = v.x + v.y + v.z + v.w;
  float ss = v.x * v.x + v.y * v.y + v.z * v.z + v.w * v.w;

  #pragma unroll
  for (int off = 1; off < 64; off <<= 1) {
    s  += __shfl_xor(s, off);
    ss += __shfl_xor(ss, off);
  }
  __shared__ float red[4][2];
  const int wid = t >> 6;
  if ((t & 63) == 0) { red[wid][0] = s; red[wid][1] = ss; }
  __syncthreads();
  s  = red[0][0] + red[1][0] + red[2][0] + red[3][0];
  ss = red[0][1] + red[1][1] + red[2][1] + red[3][1];

  const float mean = s * (1.0f / D_);
  const float var  = ss * (1.0f / D_) - mean * mean;
  const float inv  = rsqrtf(var + 1e-5f);

  float4 gv = *(const float4*)&g[t * 4];
  float4 bv = *(const float4*)&b[t * 4];
  float4 o;
  o.x = (v.x - mean) * inv * gv.x + bv.x;
  o.y = (v.y - mean) * inv * gv.y + bv.y;
  o.z = (v.z - mean) * inv * gv.z + bv.z;
  o.w = (v.w - mean) * inv * gv.w + bv.w;
  ushort4 h, l;
  split_hl(o.x, h.x, l.x); split_hl(o.y, h.y, l.y);
  split_hl(o.z, h.z, l.z); split_hl(o.w, h.w, l.w);
  *(ushort4*)&Yh[(size_t)row * D_ + t * 4] = h;
  *(ushort4*)&Yl[(size_t)row * D_ + t * 4] = l;
}

// ---------------------------------------------------------------------------
// Split-K reduce (4 planes) + bias + residual(hl) + LN -> f32
// ---------------------------------------------------------------------------
__global__ __launch_bounds__(256)
void lnred4(const float* __restrict__ P0, const float* __restrict__ P1,
            const float* __restrict__ P2, const float* __restrict__ P3,
            const float* __restrict__ b2,
            const us* __restrict__ Rh, const us* __restrict__ Rl,
            const float* __restrict__ g, const float* __restrict__ be,
            float* __restrict__ Y) {
  const int row = blockIdx.x;
  const int t = threadIdx.x;
  const size_t o = (size_t)row * D_ + t * 4;

  float4 v0 = *(const float4*)&P0[o];
  float4 v1 = *(const float4*)&P1[o];
  float4 v2 = *(const float4*)&P2[o];
  float4 v3 = *(const float4*)&P3[o];
  float4 bb = *(const float4*)&b2[t * 4];
  ushort4 rh = *(const ushort4*)&Rh[o];
  ushort4 rl = *(const ushort4*)&Rl[o];
  float4 v;
  v.x = v0.x + v1.x + v2.x + v3.x + bb.x + f32_of(rh.x) + f32_of(rl.x);
  v.y = v0.y + v1.y + v2.y + v3.y + bb.y + f32_of(rh.y) + f32_of(rl.y);
  v.z = v0.z + v1.z + v2.z + v3.z + bb.z + f32_of(rh.z) + f32_of(rl.z);
  v.w = v0.w + v1.w + v2.w + v3.w + bb.w + f32_of(rh.w) + f32_of(rl.w);

  float s  = v.x + v.y + v.z + v.w;
  float ss = v.x * v.x + v.y * v.y + v.z * v.z + v.w * v.w;
  #pragma unroll
  for (int off = 1; off < 64; off <<= 1) {
    s  += __shfl_xor(s, off);
    ss += __shfl_xor(ss, off);
  }
  __shared__ float red[4][2];
  const int wid = t >> 6;
  if ((t & 63) == 0) { red[wid][0] = s; red[wid][1] = ss; }
  __syncthreads();
  s  = red[0][0] + red[1][0] + red[2][0] + red[3][0];
  ss = red[0][1] + red[1][1] + red[2][1] + red[3][1];

  const float mean = s * (1.0f / D_);
  const float var  = ss * (1.0f / D_) - mean * mean;
  const float inv  = rsqrtf(var + 1e-5f);

  float4 gv = *(const float4*)&g[t * 4];
  float4 bv = *(const float4*)&be[t * 4];
  float4 y;
  y.x = (v.x - mean) * inv * gv.x + bv.x;
  y.y = (v.y - mean) * inv * gv.y + bv.y;
  y.z = (v.z - mean) * inv * gv.z + bv.z;
  y.w = (v.w - mean) * inv * gv.w + bv.w;
  *(float4*)&Y[o] = y;
}

// ---------------------------------------------------------------------------
// Gate + top-2 + softmax; scatter gate-scaled h rows into the adapter GEMM
// A-matrix: A[t, e*64+r] = g_e * h[t,e,r] (0 if unselected),
// A[t, 512+e] = g_e, A[t, 520..575] = 0.  bf16 hi only.
// ---------------------------------------------------------------------------
__global__ __launch_bounds__(256)
void gate_scale(const us* __restrict__ Xh, const us* __restrict__ Xl,
                const float* __restrict__ Hall,
                const float* __restrict__ GW, const float* __restrict__ GB,
                us* __restrict__ Aout) {
  const int tok = blockIdx.x;
  const int t = threadIdx.x;

  __shared__ float xs[D_];
  __shared__ float part[256];
  __shared__ float logit_s[E_];
  __shared__ float g_sh[E_];

  {
    ushort4 h = *(const ushort4*)&Xh[(size_t)tok * D_ + t * 4];
    ushort4 l = *(const ushort4*)&Xl[(size_t)tok * D_ + t * 4];
    xs[t * 4 + 0] = f32_of(h.x) + f32_of(l.x);
    xs[t * 4 + 1] = f32_of(h.y) + f32_of(l.y);
    xs[t * 4 + 2] = f32_of(h.z) + f32_of(l.z);
    xs[t * 4 + 3] = f32_of(h.w) + f32_of(l.w);
  }
  __syncthreads();

  {
    const int e = t & 7, seg = t >> 3;
    float p = 0.f;
    #pragma unroll 8
    for (int i = 0; i < 32; ++i) {
      const int d = seg * 32 + i;
      p = fmaf(xs[d], GW[d * E_ + e], p);
    }
    part[t] = p;
  }
  __syncthreads();
  if (t < E_) {
    float s = GB[t];
    for (int sg = 0; sg < 32; ++sg) s += part[sg * 8 + t];
    logit_s[t] = s;
  }
  __syncthreads();
  if (t == 0) {
    int e1 = 0; float v1 = logit_s[0];
    for (int i = 1; i < E_; ++i) if (logit_s[i] > v1) { v1 = logit_s[i]; e1 = i; }
    int e2 = -1; float v2 = -INFINITY;
    for (int i = 0; i < E_; ++i) if (i != e1 && logit_s[i] > v2) { v2 = logit_s[i]; e2 = i; }
    const float ee = expf(v2 - v1);
    const float den = 1.0f + ee;
    #pragma unroll
    for (int i = 0; i < E_; ++i) g_sh[i] = 0.f;
    g_sh[e1] = 1.0f / den;
    g_sh[e2] = ee / den;
  }
  __syncthreads();

  us* arow = Aout + (size_t)tok * KADP;
  // h part: k = t, t+256 (512 cols)
  #pragma unroll
  for (int k = t; k < 512; k += 256) {
    const float gv = g_sh[k >> 6];
    arow[k] = bf16_of(gv * Hall[(size_t)tok * 512 + k]);
  }
  // gate cols + zero pad: k = 512..575 (64 cols)
  if (t < 64) {
    arow[512 + t] = (t < 8) ? bf16_of(g_sh[t]) : (us)0;
  }
}

// ---------------------------------------------------------------------------
extern "C" void kernel_launch(void* const* d_in, const int* in_sizes, int n_in,
                              void* d_out, int out_size, void* d_ws, size_t ws_size,
                              hipStream_t stream) {
  const float* x     = (const float*)d_in[0];
  const float* wq    = (const float*)d_in[1];
  const float* wk    = (const float*)d_in[2];
  const float* wv    = (const float*)d_in[3];
  const float* wo    = (const float*)d_in[4];
  const float* bq    = (const float*)d_in[5];
  const float* bk    = (const float*)d_in[6];
  const float* bv    = (const float*)d_in[7];
  const float* bo    = (const float*)d_in[8];
  const float* ln1g  = (const float*)d_in[9];
  const float* ln1b  = (const float*)d_in[10];
  const float* w1    = (const float*)d_in[11];
  const float* b1    = (const float*)d_in[12];
  const float* w2    = (const float*)d_in[13];
  const float* b2    = (const float*)d_in[14];
  const float* ln2g  = (const float*)d_in[15];
  const float* ln2b  = (const float*)d_in[16];
  const float* aw1   = (const float*)d_in[17];
  const float* ab1   = (const float*)d_in[18];
  const float* aw2   = (const float*)d_in[19];
  const float* ab2   = (const float*)d_in[20];
  const float* gw    = (const float*)d_in[21];
  const float* gb    = (const float*)d_in[22];
  float* out = (float*)d_out;

  char* base = (char*)d_ws;
  const size_t MB = 1ull << 20;

  // weights (persistent)
  us* qkvTh = (us*)(base + 0 * MB);  us* qkvTl = (us*)(base + 6 * MB);
  us* woTh  = (us*)(base + 12 * MB); us* woTl  = (us*)(base + 14 * MB);
  us* w1Th  = (us*)(base + 16 * MB); us* w1Tl  = (us*)(base + 24 * MB);
  us* w2Th  = (us*)(base + 32 * MB); us* w2Tl  = (us*)(base + 40 * MB);
  us* a1Th  = (us*)(base + 48 * MB); us* a1Tl  = (us*)(base + 49 * MB);
  // activations
  us* xh   = (us*)(base + 52 * MB);
  us* ctxh = (us*)(base + 52 * MB);
  us* qbh  = (us*)(base + 68 * MB);  us* qbl  = (us*)(base + 76 * MB);
  us* kbh  = (us*)(base + 84 * MB);
  us* vth  = (us*)(base + 100 * MB); us* vtl  = (us*)(base + 108 * MB);
  float* ATTNPRE = (float*)(base + 68 * MB);
  us* aoh  = (us*)(base + 84 * MB);  us* aol  = (us*)(base + 92 * MB);
  us* inth = (us*)(base + 116 * MB);                      // 32 MB
  float* P0 = (float*)(base + 52 * MB);
  float* P1 = (float*)(base + 68 * MB);
  float* P2 = (float*)(base + 100 * MB);
  float* P3 = (float*)(base + 148 * MB);                  // ..164
  float* LOUT = P0;
  float* HALL = (float*)(base + 68 * MB);                 // 8 MB (P1 dead)
  us* Aarg   = (us*)(base + 76 * MB);                     // [4096,576] bf16 4.5 MB
  // high region (..178 MB proven available)
  us* b2Th   = (us*)(base + 165 * MB);                    // [1024,576] 1.2 MB
  us* b2Tl   = (us*)(base + 167 * MB);
  float* Bflat = (float*)(base + 169 * MB);               // [576,1024] f32 2.25 MB
  float* bqkv  = (float*)(base + 172 * MB);

  const dim3 blk(256);
  const float* nf = nullptr;

  // --- precompute splits ---
  fhi<<<dim3(NTOK * D_ / 1024), blk, 0, stream>>>(x, xh, NTOK * D_ / 4);
  wsplit_t<<<dim3(16, 16), blk, 0, stream>>>(wq, qkvTh, qkvTl, D_, D_);
  wsplit_t<<<dim3(16, 16), blk, 0, stream>>>(wk, qkvTh + 1024 * 1024, qkvTl + 1024 * 1024, D_, D_);
  wsplit_t<<<dim3(16, 16), blk, 0, stream>>>(wv, qkvTh + 2048 * 1024, qkvTl + 2048 * 1024, D_, D_);
  wsplit_t<<<dim3(16, 16), blk, 0, stream>>>(wo, woTh, woTl, D_, D_);
  wsplit_t<<<dim3(64, 16), blk, 0, stream>>>(w1, w1Th, w1Tl, D_, FF_);
  wsplit_t<<<dim3(16, 64), blk, 0, stream>>>(w2, w2Th, w2Tl, FF_, D_);
  wsplit_t<<<dim3(8, 16),  blk, 0, stream>>>(aw1, a1Th, a1Tl, D_, E_ * R_);
  bflat_fill<<<dim3(KADP * 1024 / 1024), blk, 0, stream>>>(aw2, ab2, Bflat);
  wsplit_t<<<dim3(16, KADP / 64), blk, 0, stream>>>(Bflat, b2Th, b2Tl, KADP, D_);
  bconcat<<<dim3(12), blk, 0, stream>>>(bq, bk, bv, bqkv);

  // --- fused QKV projection: Q hl, K h, V transposed hl ---
  gemm256<10><<<dim3(12, 16), dim3(512), 0, stream>>>(
      xh, qkvTh, qkvTl, bqkv, nullptr, qbh, qbl, kbh, nullptr, vth, vtl,
      NTOK, 3072, D_, D_);
  // --- attention (2-term): ctx -> bf16 hi ---
  attn_mfma<<<dim3(16, 64), blk, 0, stream>>>(qbh, qbl, kbh, vth, vtl, ctxh);
  // --- output projection (2-term) + residual(x), LN1 -> AO hi/lo ---
  gemm128<2><<<dim3(8, 32), blk, 0, stream>>>(ctxh, woTh, woTl, bo, x,
                                              ATTNPRE, NTOK, D_, D_);
  layernorm_hl<<<dim3(NTOK), blk, 0, stream>>>(ATTNPRE, ln1g, ln1b, aoh, aol);
  // --- FFN1 (2-term, gelu -> bf16 hi) ---
  gemm256<11><<<dim3(16, 16), dim3(512), 0, stream>>>(
      aoh, w1Th, w1Tl, b1, nullptr, inth, nullptr, nullptr, nullptr, nullptr, nullptr,
      NTOK, FF_, D_, D_);
  // --- FFN2 (split-K=4) + fused reduce+LN2 ---
  gemm256<12><<<dim3(4, 16, 4), dim3(512), 0, stream>>>(
      inth, w2Th, w2Tl, nf, P0, nullptr, nullptr, (us*)P1, (us*)P2, (us*)P3, nullptr,
      NTOK, D_, FF_, 1024);
  lnred4<<<dim3(NTOK), blk, 0, stream>>>(P0, P1, P2, P3, b2, aoh, aol, ln2g, ln2b, LOUT);
  // --- adapter: dense1 -> gate/scale -> combine-GEMM (out = LOUT + 2*A@B2T) ---
  gemm128<1><<<dim3(4, 32), blk, 0, stream>>>(aoh, a1Th, a1Tl, ab1, nf,
                                              HALL, NTOK, E_ * R_, D_);
  gate_scale<<<dim3(NTOK), blk, 0, stream>>>(aoh, aol, HALL, gw, gb, Aarg);
  gemm128<3><<<dim3(8, 32), blk, 0, stream>>>(Aarg, b2Th, b2Tl, nf, LOUT,
                                              out, NTOK, D_, KADP);
}